// Round 10
// baseline (883.831 us; speedup 1.0000x reference)
//
#include <hip/hip_runtime.h>
#include <hip/hip_bf16.h>
#include <hip/hip_fp16.h>

typedef unsigned short u16;
typedef __attribute__((ext_vector_type(8))) short short8;
typedef __attribute__((ext_vector_type(4))) float f32x4;

#define BN_EPS    1e-3f
#define RELAX     1.3f
#define SQRT_HALF 0.7071067811865476f

// packed-weight offsets (ushort units)
#define PK_G0_US     0
#define PK_G1_US     65536
#define PK_DEP_US    98304
#define PK_AT_US     360448
#define PK_WOUT_US   409600
#define PK_WOUTLO_US 413696
// ws byte offsets
#define OFF_SHIFT 835584
#define OFF_SCALE 848896
#define OFF_INSC  862208
#define OFF_INSH  863232

__device__ __forceinline__ u16 f2bf(float x){
  unsigned u = __float_as_uint(x);
  return (u16)((u + 0x7fffu + ((u >> 16) & 1u)) >> 16);
}
__device__ __forceinline__ float bf2f(u16 h){ return __uint_as_float(((unsigned)h) << 16); }
__device__ __forceinline__ float sigm(float x){ return 1.0f / (1.0f + __expf(-x)); }
__device__ __forceinline__ f32x4 splat4(float x){ f32x4 v; v[0]=x; v[1]=x; v[2]=x; v[3]=x; return v; }

// packed pair f32->bf16 (RTNE) -> one u32 (v_cvt_pk_bf16_f32)
__device__ __forceinline__ unsigned pk2(float a, float b){
  float2 t; t.x = a; t.y = b;
  union { __hip_bfloat162 h; unsigned u; } v;
  v.h = __float22bfloat162_rn(t);
  return v.u;
}
// unpack uint2 (4 bf16, pk2 order) -> f32x4
__device__ __forceinline__ f32x4 unpk4(uint2 p){
  f32x4 r;
  r[0] = __uint_as_float(p.x << 16);
  r[1] = __uint_as_float(p.x & 0xffff0000u);
  r[2] = __uint_as_float(p.y << 16);
  r[3] = __uint_as_float(p.y & 0xffff0000u);
  return r;
}

// ---------------- prep: BN scale/shift tables ----------------
__global__ void prep_bn(
  const float* in_g, const float* in_b, const float* in_m, const float* in_v,
  const float* sh_g, const float* sh_b, const float* sh_m, const float* sh_v,
  const float* dep_g, const float* dep_b, const float* dep_m, const float* dep_v,
  const float* at_g, const float* at_b, const float* at_m, const float* at_v,
  float* shiftT, float* scaleT, float* inSc, float* inSh)
{
  int r = blockIdx.x, f = threadIdx.x;
  if (r < 13) {
    const float *g, *bb, *mm, *vv;
    if (r < 2)       { g = sh_g + r*256;        bb = sh_b + r*256;        mm = sh_m + r*256;        vv = sh_v + r*256; }
    else if (r < 10) { int j = r-2;  g = dep_g + j*256; bb = dep_b + j*256; mm = dep_m + j*256; vv = dep_v + j*256; }
    else             { int j = r-10; g = at_g  + j*256; bb = at_b  + j*256; mm = at_m  + j*256; vv = at_v  + j*256; }
    float sc = g[f] * rsqrtf(vv[f] + BN_EPS);
    scaleT[r*256 + f] = sc;
    shiftT[r*256 + f] = bb[f] - mm[f]*sc;
  } else {
    float sc = in_g[f] * rsqrtf(in_v[f] + BN_EPS);
    inSc[f] = sc;
    inSh[f] = in_b[f] - in_m[f]*sc;
  }
}

// ---------------- prep: pack weights into MFMA A-fragment order (BN scale folded) ----------------
__global__ void prep_pack(
  const float* sh_W0, const float* sh_W1, const float* dep_W,
  const float* at_W, const float* Wout, const float* scaleT, u16* pk)
{
  int c = blockIdx.x*256 + threadIdx.x;   // 16B chunk id, 0..52223
  const float* W; int K, Nout, srow, base; bool lo = false;
  if (c < 8192)       { W = sh_W0; K = 256; Nout = 256; srow = 0;  base = 0; }
  else if (c < 12288) { W = sh_W1; K = 128; Nout = 256; srow = 1;  base = 8192; }
  else if (c < 45056) { int j = (c-12288) >> 12; W = dep_W + j*32768; K = 128; Nout = 256; srow = 2+j;  base = 12288 + j*4096; }
  else if (c < 51200) { int j = (c-45056) >> 11; W = at_W  + j*16384; K = 64;  Nout = 256; srow = 10+j; base = 45056 + j*2048; }
  else if (c < 51712) { W = Wout; K = 64; Nout = 64; srow = -1; base = 51200; }
  else                { W = Wout; K = 64; Nout = 64; srow = -1; base = 51712; lo = true; }
  int local = c - base;
  int lane  = local & 63;
  int t     = local >> 6;
  int KS    = K >> 5;
  int lsh   = (K == 256) ? 3 : (K == 128) ? 2 : 1;
  int ks    = t & (KS - 1);
  int mf    = t >> lsh;
  int feat  = mf*16 + (lane & 15);
  int k0    = ks*32 + ((lane >> 4) << 3);
  float scl = (srow < 0) ? 1.0f : scaleT[srow*256 + feat];
  u16 v[8];
  #pragma unroll
  for (int j = 0; j < 8; ++j) {
    float x = W[(size_t)(k0 + j)*Nout + feat] * scl;
    u16 h = f2bf(x);
    if (lo) h = f2bf(x - bf2f(h));
    v[j] = h;
  }
  ushort4* d4 = (ushort4*)(pk + (size_t)c*8);
  ushort4 p0; p0.x=v[0]; p0.y=v[1]; p0.z=v[2]; p0.w=v[3];
  ushort4 p1; p1.x=v[4]; p1.y=v[5]; p1.z=v[6]; p1.w=v[7];
  d4[0] = p0; d4[1] = p1;
}

// ---------------- main fused kernel helpers (4 waves, 4 m-frags/wave, 2 n-frags) ----------------
// A-staging split 2+2 to keep peak live regs under the 85-VGPR cap (3 waves/SIMD).
template<int KS, int LDB, int KOFF>
__device__ __forceinline__ void gemm4(const u16* __restrict__ pk, const u16* bufB,
                                      int w, int l15, int lg, int swzv, f32x4 acc[4][2])
{
  const int lane = lg*16 + l15;
  #pragma unroll 1
  for (int ks = 0; ks < KS; ++ks) {
    short8 b[2];
    #pragma unroll
    for (int nf = 0; nf < 2; ++nf) {
      int idx = (nf*16 + l15)*LDB + KOFF + ks*32 + lg*8;
      b[nf] = *(const short8*)(bufB + (idx ^ swzv));
    }
    #pragma unroll
    for (int half = 0; half < 2; ++half) {
      short8 a0 = *(const short8*)(pk + (size_t)(((w + 4*(2*half  ))*KS + ks)*64 + lane)*8);
      short8 a1 = *(const short8*)(pk + (size_t)(((w + 4*(2*half+1))*KS + ks)*64 + lane)*8);
      acc[2*half  ][0] = __builtin_amdgcn_mfma_f32_16x16x32_bf16(a0, b[0], acc[2*half  ][0], 0, 0, 0);
      acc[2*half  ][1] = __builtin_amdgcn_mfma_f32_16x16x32_bf16(a0, b[1], acc[2*half  ][1], 0, 0, 0);
      acc[2*half+1][0] = __builtin_amdgcn_mfma_f32_16x16x32_bf16(a1, b[0], acc[2*half+1][0], 0, 0, 0);
      acc[2*half+1][1] = __builtin_amdgcn_mfma_f32_16x16x32_bf16(a1, b[1], acc[2*half+1][1], 0, 0, 0);
    }
  }
}

__device__ __forceinline__ void zero4(f32x4 acc[4][2]){
  #pragma unroll
  for (int mi = 0; mi < 4; ++mi)
    #pragma unroll
    for (int nf = 0; nf < 2; ++nf)
      acc[mi][nf] = splat4(0.0f);
}

// GLU epilogue: h[mi][nf], mi in {0,1} -> features (w+4*mi)*16 + lg*4
__device__ __forceinline__ void glu_epi4(const f32x4 acc[4][2], const float* __restrict__ shrow,
                                         int w, int lg, f32x4 h[2][2])
{
  #pragma unroll
  for (int mi = 0; mi < 2; ++mi) {
    const int f0 = (w + 4*mi)*16 + lg*4;
    const f32x4 bh = *(const f32x4*)(shrow + f0);
    const f32x4 bg = *(const f32x4*)(shrow + f0 + 128);
    #pragma unroll
    for (int nf = 0; nf < 2; ++nf)
      #pragma unroll
      for (int c = 0; c < 4; ++c) {
        float v = acc[mi][nf][c] + bh[c];
        float g = acc[mi+2][nf][c] + bg[c];
        h[mi][nf][c] = v * sigm(g);
      }
  }
}

// write this wave's 32 features of a 128-wide activation [32][128] bf16 (swizzled)
__device__ __forceinline__ void write_half(u16* dst, const f32x4 v[2][2], int w, int l15, int lg, int swzv)
{
  #pragma unroll
  for (int mi = 0; mi < 2; ++mi) {
    const int f0 = (w + 4*mi)*16 + lg*4;
    #pragma unroll
    for (int nf = 0; nf < 2; ++nf) {
      const int s = nf*16 + l15;
      uint2 p;
      p.x = pk2(v[mi][nf][0], v[mi][nf][1]);
      p.y = pk2(v[mi][nf][2], v[mi][nf][3]);
      *(uint2*)(dst + ((s*128 + f0) ^ swzv)) = p;
    }
  }
}

// shared_block + dep_block. h lives in hbuf (8 KB); x ping-pongs between big
// halves [0:4096] and [4096:8192]; x_final lands at big[0:4096].
// NO f32 register copy of h or x is kept across gemms (re-read bf16 from LDS).
// Barriers: 4 per call (was 6).
__device__ __forceinline__ void shared_dep(const u16* __restrict__ pk, const float* __restrict__ shiftT,
                                           const u16* binput, u16* big, u16* hbuf, int inv,
                                           int w, int l15, int lg, int swzv)
{
  f32x4 acc[4][2];
  zero4(acc);
  gemm4<8, 256, 0>(pk + PK_G0_US, binput, w, l15, lg, swzv, acc);
  {
    f32x4 h[2][2];
    glu_epi4(acc, shiftT + 0, w, lg, h);
    write_half(hbuf, h, w, l15, lg, swzv);   // hbuf disjoint from binput: no pre-barrier
  }
  __syncthreads();                           // B1: h visible; all G0 reads done

  zero4(acc);
  gemm4<4, 128, 0>(pk + PK_G1_US, hbuf, w, l15, lg, swzv, acc);
  {
    f32x4 h2[2][2];
    glu_epi4(acc, shiftT + 256, w, lg, h2);
    f32x4 xv[2][2];
    #pragma unroll
    for (int mi = 0; mi < 2; ++mi) {
      const int f0 = (w + 4*mi)*16 + lg*4;
      #pragma unroll
      for (int nf = 0; nf < 2; ++nf) {
        const int s = nf*16 + l15;
        uint2 hp = *(const uint2*)(hbuf + ((s*128 + f0) ^ swzv));
        f32x4 hv = unpk4(hp);
        xv[mi][nf] = (hv + h2[mi][nf]) * SQRT_HALF;
      }
    }
    write_half(big, xv, w, l15, lg, swzv);   // x -> big[0:4096]; safe post-B1
  }
  __syncthreads();                           // B2: x visible

  const u16* xin = big;
  u16* xout = big + 4096;
  #pragma unroll
  for (int i = 0; i < 2; ++i) {
    zero4(acc);
    gemm4<4, 128, 0>(pk + PK_DEP_US + (inv*2 + i)*32768, xin, w, l15, lg, swzv, acc);
    f32x4 hd[2][2];
    glu_epi4(acc, shiftT + (2 + inv*2 + i)*256, w, lg, hd);
    #pragma unroll
    for (int mi = 0; mi < 2; ++mi) {
      const int f0 = (w + 4*mi)*16 + lg*4;
      #pragma unroll
      for (int nf = 0; nf < 2; ++nf) {
        const int s = nf*16 + l15;
        uint2 xp = *(const uint2*)(xin + ((s*128 + f0) ^ swzv));
        f32x4 xo = unpk4(xp);
        hd[mi][nf] = (xo + hd[mi][nf]) * SQRT_HALF;
      }
    }
    write_half(xout, hd, w, l15, lg, swzv);  // xout disjoint from xin: safe while others read xin
    __syncthreads();                         // B3/B4: x' visible
    const u16* t = xin; xin = xout; xout = (u16*)t;
  }
  // x_final at big[0:4096]
}

// ---------------- main fused kernel ----------------
// 32 samples/block, 4 waves (256 thr). LDS = 40 KiB -> 3 blocks/CU fits 120 KiB.
// __launch_bounds__(256,3): empirical VGPR cap = 256/3 = 85 -> 3 waves/SIMD (12 waves/CU).
__global__ void __launch_bounds__(256, 3)
tabnet_main(const float* __restrict__ inp, const u16* __restrict__ pk,
            const float* __restrict__ shiftT, const float* __restrict__ inSc,
            const float* __restrict__ inSh, float* __restrict__ out)
{
  __shared__ __align__(16) u16 feat[32*256];   // 16 KB, persistent features
  __shared__ __align__(16) u16 big[32*256];    // 16 KB, masked / x ping-pong
  __shared__ __align__(16) u16 hbuf[32*128];   // 8 KB, h; sparsemax red2 aliases here
  float2* red2 = (float2*)hbuf;                // [buf*288 + si*9 + w]

  const int tid  = threadIdx.x;
  const int w    = tid >> 6;        // 0..3
  const int lane = tid & 63;
  const int l15  = lane & 15, lg = lane >> 4;
  const int swzv = (l15 & 7) << 3;
  const long long row0 = (long long)blockIdx.x * 32;

  // stage 0: features = BN(inputs) -> feat (bf16, swizzled [sample][256])
  {
    const int f = lane*4;
    const f32x4 sc = *(const f32x4*)(inSc + f);
    const f32x4 sh = *(const f32x4*)(inSh + f);
    #pragma unroll
    for (int j = 0; j < 8; ++j) {
      const int s = j*4 + w;
      f32x4 v = *(const f32x4*)(inp + (row0 + s)*256 + f);
      uint2 p;
      p.x = pk2(v[0]*sc[0] + sh[0], v[1]*sc[1] + sh[1]);
      p.y = pk2(v[2]*sc[2] + sh[2], v[3]*sc[3] + sh[3]);
      *(uint2*)(feat + ((s*256 + f) ^ ((s & 7) << 3))) = p;
    }
  }
  __syncthreads();

  shared_dep(pk, shiftT, feat, big, hbuf, 0, w, l15, lg, swzv);

  __half2 priorH[4][2][2];       // prior packed f16 (pairs over c)
  f32x4 outAg[2];
  {
    const __half2 one2 = __float2half2_rn(1.0f);
    #pragma unroll
    for (int mi = 0; mi < 4; ++mi)
      #pragma unroll
      for (int nf = 0; nf < 2; ++nf) {
        priorH[mi][nf][0] = one2; priorH[mi][nf][1] = one2;
      }
    outAg[0] = splat4(0.0f); outAg[1] = splat4(0.0f);
  }

  #pragma unroll 1
  for (int st = 0; st < 3; ++st) {
    // attention: logits = BN(a @ at_W[st]) * prior, a = x[:,64:128] (x at big[0:4096], KOFF=64)
    f32x4 z[4][2];
    zero4(z);
    gemm4<2, 128, 64>(pk + PK_AT_US + st*16384, big, w, l15, lg, swzv, z);
    #pragma unroll
    for (int mi = 0; mi < 4; ++mi) {
      const f32x4 bz = *(const f32x4*)(shiftT + (10 + st)*256 + (w + 4*mi)*16 + lg*4);
      #pragma unroll
      for (int nf = 0; nf < 2; ++nf) {
        float2 p0 = __half22float2(priorH[mi][nf][0]);
        float2 p1 = __half22float2(priorH[mi][nf][1]);
        z[mi][nf][0] = (z[mi][nf][0] + bz[0]) * p0.x;
        z[mi][nf][1] = (z[mi][nf][1] + bz[1]) * p0.y;
        z[mi][nf][2] = (z[mi][nf][2] + bz[2]) * p1.x;
        z[mi][nf][3] = (z[mi][nf][3] + bz[3]) * p1.y;
      }
    }

    // ---- rowmax -> tau0 = max - 1 (red2 in hbuf; h is dead here)
    float tau[2];
    {
      #pragma unroll
      for (int nf = 0; nf < 2; ++nf) {
        float m = -1e30f;
        #pragma unroll
        for (int mi = 0; mi < 4; ++mi)
          #pragma unroll
          for (int c = 0; c < 4; ++c) m = fmaxf(m, z[mi][nf][c]);
        m = fmaxf(m, __shfl_xor(m, 16, 64));
        m = fmaxf(m, __shfl_xor(m, 32, 64));
        if (lg == 0) { int si = nf*16 + l15; red2[si*9 + w].x = m; }
      }
      __syncthreads();
      #pragma unroll
      for (int nf = 0; nf < 2; ++nf) {
        const int si = nf*16 + l15;
        float m = fmaxf(fmaxf(red2[si*9+0].x, red2[si*9+1].x),
                        fmaxf(red2[si*9+2].x, red2[si*9+3].x));
        tau[nf] = m - 1.0f;
      }
    }

    // ---- Newton iterations, 1 barrier each, uniform early exit
    int buf = 0;
    #pragma unroll 1
    for (int it = 0; it < 12; ++it) {
      buf ^= 1;
      float S[2], C[2];
      #pragma unroll
      for (int nf = 0; nf < 2; ++nf) {
        f32x4 s4 = splat4(0.0f), c4 = splat4(0.0f);
        #pragma unroll
        for (int mi = 0; mi < 4; ++mi)
          #pragma unroll
          for (int c = 0; c < 4; ++c) {
            float d = z[mi][nf][c] - tau[nf];
            s4[c] += fmaxf(d, 0.0f);
            c4[c] += (d > 0.0f) ? 1.0f : 0.0f;
          }
        float S_ = (s4[0] + s4[1]) + (s4[2] + s4[3]);
        float C_ = (c4[0] + c4[1]) + (c4[2] + c4[3]);
        S_ += __shfl_xor(S_, 16, 64); S_ += __shfl_xor(S_, 32, 64);
        C_ += __shfl_xor(C_, 16, 64); C_ += __shfl_xor(C_, 32, 64);
        S[nf] = S_; C[nf] = C_;
      }
      if (lg == 0) {
        #pragma unroll
        for (int nf = 0; nf < 2; ++nf) {
          int si = nf*16 + l15;
          float2 p; p.x = S[nf]; p.y = C[nf];
          red2[buf*288 + si*9 + w] = p;
        }
      }
      __syncthreads();
      bool ok = true;
      float tauN[2];
      #pragma unroll
      for (int nf = 0; nf < 2; ++nf) {
        const int si = nf*16 + l15;
        float Ss = 0.0f, Cs = 0.0f;
        #pragma unroll
        for (int i = 0; i < 4; ++i) { float2 p = red2[buf*288 + si*9 + i]; Ss += p.x; Cs += p.y; }
        ok = ok && (fabsf(Ss - 1.0f) < 1e-5f);
        tauN[nf] = tau[nf] + (Ss - 1.0f) / Cs;
      }
      if (__all(ok)) break;
      #pragma unroll
      for (int nf = 0; nf < 2; ++nf) tau[nf] = tauN[nf];
    }
    // no barrier needed: mask writes big, red2 lives in hbuf (disjoint)

    // mask, prior update, masked = mask * features -> big (full [32][256])
    #pragma unroll
    for (int mi = 0; mi < 4; ++mi) {
      const int f0 = (w + 4*mi)*16 + lg*4;
      #pragma unroll
      for (int nf = 0; nf < 2; ++nf) {
        const int si = nf*16 + l15;
        ushort4 fv = *(const ushort4*)(feat + ((si*256 + f0) ^ swzv));
        float m0 = fmaxf(z[mi][nf][0] - tau[nf], 0.0f);
        float m1 = fmaxf(z[mi][nf][1] - tau[nf], 0.0f);
        float m2 = fmaxf(z[mi][nf][2] - tau[nf], 0.0f);
        float m3 = fmaxf(z[mi][nf][3] - tau[nf], 0.0f);
        float2 p0 = __half22float2(priorH[mi][nf][0]);
        float2 p1 = __half22float2(priorH[mi][nf][1]);
        p0.x *= (RELAX - m0); p0.y *= (RELAX - m1);
        p1.x *= (RELAX - m2); p1.y *= (RELAX - m3);
        priorH[mi][nf][0] = __floats2half2_rn(p0.x, p0.y);
        priorH[mi][nf][1] = __floats2half2_rn(p1.x, p1.y);
        uint2 p;
        p.x = pk2(bf2f(fv.x) * m0, bf2f(fv.y) * m1);
        p.y = pk2(bf2f(fv.z) * m2, bf2f(fv.w) * m3);
        *(uint2*)(big + ((si*256 + f0) ^ swzv)) = p;
      }
    }
    __syncthreads();   // masked visible before G0 reads

    shared_dep(pk, shiftT, big, big, hbuf, st + 1, w, l15, lg, swzv);

    // out_agg += relu(x[:, :64]); x_final at big[0:4096] (visible after B4)
    #pragma unroll
    for (int nf = 0; nf < 2; ++nf) {
      const int si = nf*16 + l15;
      const int f0 = w*16 + lg*4;
      uint2 xp = *(const uint2*)(big + ((si*128 + f0) ^ swzv));
      f32x4 xv = unpk4(xp);
      #pragma unroll
      for (int c = 0; c < 4; ++c)
        outAg[nf][c] += fmaxf(xv[c], 0.0f);
    }
  }

  // final: out = out_agg @ Wout, split-bf16 (hi/lo) for precision
  __syncthreads();   // all outAg reads of big done before restaging
  {
    #pragma unroll
    for (int nf = 0; nf < 2; ++nf) {
      const int si = nf*16 + l15;
      const int f0 = w*16 + lg*4;
      ushort4 hi, lo;
      u16 h0 = f2bf(outAg[nf][0]); hi.x = h0; lo.x = f2bf(outAg[nf][0] - bf2f(h0));
      u16 h1 = f2bf(outAg[nf][1]); hi.y = h1; lo.y = f2bf(outAg[nf][1] - bf2f(h1));
      u16 h2v = f2bf(outAg[nf][2]); hi.z = h2v; lo.z = f2bf(outAg[nf][2] - bf2f(h2v));
      u16 h3 = f2bf(outAg[nf][3]); hi.w = h3; lo.w = f2bf(outAg[nf][3] - bf2f(h3));
      *(ushort4*)(big + ((si*64 + f0) ^ swzv)) = hi;
      *(ushort4*)(big + 2048 + ((si*64 + f0) ^ swzv)) = lo;
    }
  }
  __syncthreads();

  // 64x64x(32 samples) GEMM: wave w -> out m-frag w, both sample n-frags
  {
    const int lane64 = lg*16 + l15;
    f32x4 facc[2];
    facc[0] = splat4(0.0f); facc[1] = splat4(0.0f);
    #pragma unroll
    for (int ks = 0; ks < 2; ++ks) {
      short8 aHi = *(const short8*)(pk + PK_WOUT_US   + (size_t)((w*2 + ks)*64 + lane64)*8);
      short8 aLo = *(const short8*)(pk + PK_WOUTLO_US + (size_t)((w*2 + ks)*64 + lane64)*8);
      #pragma unroll
      for (int j = 0; j < 2; ++j) {
        const int si = j*16 + l15;
        short8 bHi = *(const short8*)(big + ((si*64 + ks*32 + lg*8) ^ swzv));
        short8 bLo = *(const short8*)(big + 2048 + ((si*64 + ks*32 + lg*8) ^ swzv));
        facc[j] = __builtin_amdgcn_mfma_f32_16x16x32_bf16(aHi, bHi, facc[j], 0, 0, 0);
        facc[j] = __builtin_amdgcn_mfma_f32_16x16x32_bf16(aHi, bLo, facc[j], 0, 0, 0);
        facc[j] = __builtin_amdgcn_mfma_f32_16x16x32_bf16(aLo, bHi, facc[j], 0, 0, 0);
      }
    }
    #pragma unroll
    for (int j = 0; j < 2; ++j) {
      const int si = j*16 + l15;
      *(f32x4*)(out + (row0 + si)*64 + w*16 + lg*4) = facc[j];
    }
  }
}

// ---------------- launch ----------------
extern "C" void kernel_launch(void* const* d_in, const int* in_sizes, int n_in,
                              void* d_out, int out_size, void* d_ws, size_t ws_size,
                              hipStream_t stream)
{
  const float* inp   = (const float*)d_in[0];
  const float* in_g  = (const float*)d_in[1];
  const float* in_b  = (const float*)d_in[2];
  const float* in_m  = (const float*)d_in[3];
  const float* in_v  = (const float*)d_in[4];
  const float* sh_W0 = (const float*)d_in[5];
  const float* sh_W1 = (const float*)d_in[6];
  const float* sh_g  = (const float*)d_in[7];
  const float* sh_b  = (const float*)d_in[8];
  const float* sh_m  = (const float*)d_in[9];
  const float* sh_v  = (const float*)d_in[10];
  const float* dep_W = (const float*)d_in[11];
  const float* dep_g = (const float*)d_in[12];
  const float* dep_b = (const float*)d_in[13];
  const float* dep_m = (const float*)d_in[14];
  const float* dep_v = (const float*)d_in[15];
  const float* at_W  = (const float*)d_in[16];
  const float* at_g  = (const float*)d_in[17];
  const float* at_b  = (const float*)d_in[18];
  const float* at_m  = (const float*)d_in[19];
  const float* at_v  = (const float*)d_in[20];
  const float* Wout  = (const float*)d_in[21];

  unsigned char* ws = (unsigned char*)d_ws;
  u16*   pk     = (u16*)ws;
  float* shiftT = (float*)(ws + OFF_SHIFT);
  float* scaleT = (float*)(ws + OFF_SCALE);
  float* inSc   = (float*)(ws + OFF_INSC);
  float* inSh   = (float*)(ws + OFF_INSH);

  hipLaunchKernelGGL(prep_bn, dim3(14), dim3(256), 0, stream,
                     in_g, in_b, in_m, in_v, sh_g, sh_b, sh_m, sh_v,
                     dep_g, dep_b, dep_m, dep_v, at_g, at_b, at_m, at_v,
                     shiftT, scaleT, inSc, inSh);
  hipLaunchKernelGGL(prep_pack, dim3(204), dim3(256), 0, stream,
                     sh_W0, sh_W1, dep_W, at_W, Wout, scaleT, pk);
  hipLaunchKernelGGL(tabnet_main, dim3(4096), dim3(256), 0, stream,
                     inp, pk, shiftT, inSc, inSh, (float*)d_out);
}

// Round 11
// 533.219 us; speedup vs baseline: 1.6575x; 1.6575x over previous
//
#include <hip/hip_runtime.h>
#include <hip/hip_bf16.h>
#include <hip/hip_fp16.h>

typedef unsigned short u16;
typedef __attribute__((ext_vector_type(8))) short short8;
typedef __attribute__((ext_vector_type(4))) float f32x4;

#define BN_EPS    1e-3f
#define RELAX     1.3f
#define SQRT_HALF 0.7071067811865476f

// packed-weight offsets (ushort units)
#define PK_G0_US     0
#define PK_G1_US     65536
#define PK_DEP_US    98304
#define PK_AT_US     360448
#define PK_WOUT_US   409600
#define PK_WOUTLO_US 413696
// ws byte offsets
#define OFF_SHIFT 835584
#define OFF_SCALE 848896
#define OFF_INSC  862208
#define OFF_INSH  863232

__device__ __forceinline__ u16 f2bf(float x){
  unsigned u = __float_as_uint(x);
  return (u16)((u + 0x7fffu + ((u >> 16) & 1u)) >> 16);
}
__device__ __forceinline__ float bf2f(u16 h){ return __uint_as_float(((unsigned)h) << 16); }
__device__ __forceinline__ float sigm(float x){ return 1.0f / (1.0f + __expf(-x)); }
__device__ __forceinline__ f32x4 splat4(float x){ f32x4 v; v[0]=x; v[1]=x; v[2]=x; v[3]=x; return v; }

__device__ __forceinline__ unsigned pk2(float a, float b){
  float2 t; t.x = a; t.y = b;
  union { __hip_bfloat162 h; unsigned u; } v;
  v.h = __float22bfloat162_rn(t);
  return v.u;
}
__device__ __forceinline__ f32x4 unpk4(uint2 p){
  f32x4 r;
  r[0] = __uint_as_float(p.x << 16);
  r[1] = __uint_as_float(p.x & 0xffff0000u);
  r[2] = __uint_as_float(p.y << 16);
  r[3] = __uint_as_float(p.y & 0xffff0000u);
  return r;
}
__device__ __forceinline__ float2 h2f2(unsigned u){
  union { unsigned u; __half2 h; } v; v.u = u;
  return __half22float2(v.h);
}
__device__ __forceinline__ unsigned f22h2(float a, float b){
  union { __half2 h; unsigned u; } v; v.h = __floats2half2_rn(a, b);
  return v.u;
}

// ---------------- prep: BN scale/shift tables ----------------
__global__ void prep_bn(
  const float* in_g, const float* in_b, const float* in_m, const float* in_v,
  const float* sh_g, const float* sh_b, const float* sh_m, const float* sh_v,
  const float* dep_g, const float* dep_b, const float* dep_m, const float* dep_v,
  const float* at_g, const float* at_b, const float* at_m, const float* at_v,
  float* shiftT, float* scaleT, float* inSc, float* inSh)
{
  int r = blockIdx.x, f = threadIdx.x;
  if (r < 13) {
    const float *g, *bb, *mm, *vv;
    if (r < 2)       { g = sh_g + r*256;        bb = sh_b + r*256;        mm = sh_m + r*256;        vv = sh_v + r*256; }
    else if (r < 10) { int j = r-2;  g = dep_g + j*256; bb = dep_b + j*256; mm = dep_m + j*256; vv = dep_v + j*256; }
    else             { int j = r-10; g = at_g  + j*256; bb = at_b  + j*256; mm = at_m  + j*256; vv = at_v  + j*256; }
    float sc = g[f] * rsqrtf(vv[f] + BN_EPS);
    scaleT[r*256 + f] = sc;
    shiftT[r*256 + f] = bb[f] - mm[f]*sc;
  } else {
    float sc = in_g[f] * rsqrtf(in_v[f] + BN_EPS);
    inSc[f] = sc;
    inSh[f] = in_b[f] - in_m[f]*sc;
  }
}

// ---------------- prep: pack weights into MFMA A-fragment order (BN scale folded) ----------------
__global__ void prep_pack(
  const float* sh_W0, const float* sh_W1, const float* dep_W,
  const float* at_W, const float* Wout, const float* scaleT, u16* pk)
{
  int c = blockIdx.x*256 + threadIdx.x;   // 16B chunk id, 0..52223
  const float* W; int K, Nout, srow, base; bool lo = false;
  if (c < 8192)       { W = sh_W0; K = 256; Nout = 256; srow = 0;  base = 0; }
  else if (c < 12288) { W = sh_W1; K = 128; Nout = 256; srow = 1;  base = 8192; }
  else if (c < 45056) { int j = (c-12288) >> 12; W = dep_W + j*32768; K = 128; Nout = 256; srow = 2+j;  base = 12288 + j*4096; }
  else if (c < 51200) { int j = (c-45056) >> 11; W = at_W  + j*16384; K = 64;  Nout = 256; srow = 10+j; base = 45056 + j*2048; }
  else if (c < 51712) { W = Wout; K = 64; Nout = 64; srow = -1; base = 51200; }
  else                { W = Wout; K = 64; Nout = 64; srow = -1; base = 51712; lo = true; }
  int local = c - base;
  int lane  = local & 63;
  int t     = local >> 6;
  int KS    = K >> 5;
  int lsh   = (K == 256) ? 3 : (K == 128) ? 2 : 1;
  int ks    = t & (KS - 1);
  int mf    = t >> lsh;
  int feat  = mf*16 + (lane & 15);
  int k0    = ks*32 + ((lane >> 4) << 3);
  float scl = (srow < 0) ? 1.0f : scaleT[srow*256 + feat];
  u16 v[8];
  #pragma unroll
  for (int j = 0; j < 8; ++j) {
    float x = W[(size_t)(k0 + j)*Nout + feat] * scl;
    u16 h = f2bf(x);
    if (lo) h = f2bf(x - bf2f(h));
    v[j] = h;
  }
  ushort4* d4 = (ushort4*)(pk + (size_t)c*8);
  ushort4 p0; p0.x=v[0]; p0.y=v[1]; p0.z=v[2]; p0.w=v[3];
  ushort4 p1; p1.x=v[4]; p1.y=v[5]; p1.z=v[6]; p1.w=v[7];
  d4[0] = p0; d4[1] = p1;
}

// ---------------- gemm: 4 m-frags x 2 n-frags, manual even/odd double-buffer ----------------
// Prefetch ks+1 operands while MFMAing ks: hides L2/LDS latency at 2 waves/SIMD.
// Live regs: acc 32 + ae16+be8+ao16+bo8 = 80 (+ compiler overhead); prior/outAg
// are in LDS during gemms, freeing 24 regs vs r8's spilling variant.
template<int KS, int LDB, int KOFF>
__device__ __forceinline__ void gemm4(const u16* __restrict__ pk, const u16* bufB,
                                      int w, int l15, int lg, int swzv, f32x4 acc[4][2])
{
  const int lane = lg*16 + l15;
  short8 ae[4], be[2], ao[4], bo[2];
  #pragma unroll
  for (int nf = 0; nf < 2; ++nf) {
    int idx = (nf*16 + l15)*LDB + KOFF + lg*8;
    be[nf] = *(const short8*)(bufB + (idx ^ swzv));
  }
  #pragma unroll
  for (int mi = 0; mi < 4; ++mi)
    ae[mi] = *(const short8*)(pk + (size_t)(((w + 4*mi)*KS)*64 + lane)*8);

  #pragma unroll 1
  for (int ks = 0; ks < KS; ks += 2) {
    #pragma unroll
    for (int nf = 0; nf < 2; ++nf) {
      int idx = (nf*16 + l15)*LDB + KOFF + (ks+1)*32 + lg*8;
      bo[nf] = *(const short8*)(bufB + (idx ^ swzv));
    }
    #pragma unroll
    for (int mi = 0; mi < 4; ++mi)
      ao[mi] = *(const short8*)(pk + (size_t)(((w + 4*mi)*KS + ks + 1)*64 + lane)*8);
    #pragma unroll
    for (int mi = 0; mi < 4; ++mi) {
      acc[mi][0] = __builtin_amdgcn_mfma_f32_16x16x32_bf16(ae[mi], be[0], acc[mi][0], 0, 0, 0);
      acc[mi][1] = __builtin_amdgcn_mfma_f32_16x16x32_bf16(ae[mi], be[1], acc[mi][1], 0, 0, 0);
    }
    if (ks + 2 < KS) {
      #pragma unroll
      for (int nf = 0; nf < 2; ++nf) {
        int idx = (nf*16 + l15)*LDB + KOFF + (ks+2)*32 + lg*8;
        be[nf] = *(const short8*)(bufB + (idx ^ swzv));
      }
      #pragma unroll
      for (int mi = 0; mi < 4; ++mi)
        ae[mi] = *(const short8*)(pk + (size_t)(((w + 4*mi)*KS + ks + 2)*64 + lane)*8);
    }
    #pragma unroll
    for (int mi = 0; mi < 4; ++mi) {
      acc[mi][0] = __builtin_amdgcn_mfma_f32_16x16x32_bf16(ao[mi], bo[0], acc[mi][0], 0, 0, 0);
      acc[mi][1] = __builtin_amdgcn_mfma_f32_16x16x32_bf16(ao[mi], bo[1], acc[mi][1], 0, 0, 0);
    }
  }
}

__device__ __forceinline__ void zero4(f32x4 acc[4][2]){
  #pragma unroll
  for (int mi = 0; mi < 4; ++mi)
    #pragma unroll
    for (int nf = 0; nf < 2; ++nf)
      acc[mi][nf] = splat4(0.0f);
}

// GLU epilogue: h[mi][nf], mi in {0,1} -> features (w+4*mi)*16 + lg*4
__device__ __forceinline__ void glu_epi4(const f32x4 acc[4][2], const float* __restrict__ shrow,
                                         int w, int lg, f32x4 h[2][2])
{
  #pragma unroll
  for (int mi = 0; mi < 2; ++mi) {
    const int f0 = (w + 4*mi)*16 + lg*4;
    const f32x4 bh = *(const f32x4*)(shrow + f0);
    const f32x4 bg = *(const f32x4*)(shrow + f0 + 128);
    #pragma unroll
    for (int nf = 0; nf < 2; ++nf)
      #pragma unroll
      for (int c = 0; c < 4; ++c) {
        float v = acc[mi][nf][c] + bh[c];
        float g = acc[mi+2][nf][c] + bg[c];
        h[mi][nf][c] = v * sigm(g);
      }
  }
}

// write this wave's 32 features of a 128-wide activation [32][128] bf16 (swizzled)
__device__ __forceinline__ void write_half(u16* dst, const f32x4 v[2][2], int w, int l15, int lg, int swzv)
{
  #pragma unroll
  for (int mi = 0; mi < 2; ++mi) {
    const int f0 = (w + 4*mi)*16 + lg*4;
    #pragma unroll
    for (int nf = 0; nf < 2; ++nf) {
      const int s = nf*16 + l15;
      uint2 p;
      p.x = pk2(v[mi][nf][0], v[mi][nf][1]);
      p.y = pk2(v[mi][nf][2], v[mi][nf][3]);
      *(uint2*)(dst + ((s*128 + f0) ^ swzv)) = p;
    }
  }
}

// shared_block + dep_block. h in hbuf (8 KB); x ping-pongs between big halves;
// x_final lands at big[0:4096]. No f32 copies of h/x kept across gemms.
__device__ __forceinline__ void shared_dep(const u16* __restrict__ pk, const float* __restrict__ shiftT,
                                           const u16* binput, u16* big, u16* hbuf, int inv,
                                           int w, int l15, int lg, int swzv)
{
  f32x4 acc[4][2];
  zero4(acc);
  gemm4<8, 256, 0>(pk + PK_G0_US, binput, w, l15, lg, swzv, acc);
  {
    f32x4 h[2][2];
    glu_epi4(acc, shiftT + 0, w, lg, h);
    write_half(hbuf, h, w, l15, lg, swzv);   // hbuf disjoint from binput: no pre-barrier
  }
  __syncthreads();                           // B1: h visible; all G0 reads done

  zero4(acc);
  gemm4<4, 128, 0>(pk + PK_G1_US, hbuf, w, l15, lg, swzv, acc);
  {
    f32x4 h2[2][2];
    glu_epi4(acc, shiftT + 256, w, lg, h2);
    f32x4 xv[2][2];
    #pragma unroll
    for (int mi = 0; mi < 2; ++mi) {
      const int f0 = (w + 4*mi)*16 + lg*4;
      #pragma unroll
      for (int nf = 0; nf < 2; ++nf) {
        const int s = nf*16 + l15;
        uint2 hp = *(const uint2*)(hbuf + ((s*128 + f0) ^ swzv));
        f32x4 hv = unpk4(hp);
        xv[mi][nf] = (hv + h2[mi][nf]) * SQRT_HALF;
      }
    }
    write_half(big, xv, w, l15, lg, swzv);   // x -> big[0:4096]; safe post-B1
  }
  __syncthreads();                           // B2: x visible

  const u16* xin = big;
  u16* xout = big + 4096;
  #pragma unroll
  for (int i = 0; i < 2; ++i) {
    zero4(acc);
    gemm4<4, 128, 0>(pk + PK_DEP_US + (inv*2 + i)*32768, xin, w, l15, lg, swzv, acc);
    f32x4 hd[2][2];
    glu_epi4(acc, shiftT + (2 + inv*2 + i)*256, w, lg, hd);
    #pragma unroll
    for (int mi = 0; mi < 2; ++mi) {
      const int f0 = (w + 4*mi)*16 + lg*4;
      #pragma unroll
      for (int nf = 0; nf < 2; ++nf) {
        const int s = nf*16 + l15;
        uint2 xp = *(const uint2*)(xin + ((s*128 + f0) ^ swzv));
        f32x4 xo = unpk4(xp);
        hd[mi][nf] = (xo + hd[mi][nf]) * SQRT_HALF;
      }
    }
    write_half(xout, hd, w, l15, lg, swzv);  // xout disjoint from xin
    __syncthreads();                         // B3/B4: x' visible
    const u16* t = xin; xin = xout; xout = (u16*)t;
  }
  // x_final at big[0:4096]
}

// ---------------- main fused kernel ----------------
// 32 samples/block, 4 waves (256 thr). LDS = 64 KiB -> 2 blocks/CU (128 KiB).
// prior/outAg live in per-thread-private LDS columns (no barriers needed for
// them), freeing 24 VGPRs so the double-buffered gemm fits the 128-reg cap.
__global__ void __launch_bounds__(256, 2)
tabnet_main(const float* __restrict__ inp, const u16* __restrict__ pk,
            const float* __restrict__ shiftT, const float* __restrict__ inSc,
            const float* __restrict__ inSh, float* __restrict__ out)
{
  __shared__ __align__(16) u16 feat[32*256];     // 16 KB
  __shared__ __align__(16) u16 big[32*256];      // 16 KB
  __shared__ __align__(16) u16 hbuf[32*128];     // 8 KB (h + sparsemax red2 alias)
  __shared__ unsigned priorS[16*256];            // 16 KB: prior as __half2, [j][tid]
  __shared__ float    aggS[8*256];               // 8 KB: out_agg f32, [j][tid]
  float2* red2 = (float2*)hbuf;                  // [buf*288 + si*9 + w]

  const int tid  = threadIdx.x;
  const int w    = tid >> 6;        // 0..3
  const int lane = tid & 63;
  const int l15  = lane & 15, lg = lane >> 4;
  const int swzv = (l15 & 7) << 3;
  const long long row0 = (long long)blockIdx.x * 32;

  // stage 0: features = BN(inputs) -> feat (bf16, swizzled [sample][256])
  {
    const int f = lane*4;
    const f32x4 sc = *(const f32x4*)(inSc + f);
    const f32x4 sh = *(const f32x4*)(inSh + f);
    #pragma unroll
    for (int j = 0; j < 8; ++j) {
      const int s = j*4 + w;
      f32x4 v = *(const f32x4*)(inp + (row0 + s)*256 + f);
      uint2 p;
      p.x = pk2(v[0]*sc[0] + sh[0], v[1]*sc[1] + sh[1]);
      p.y = pk2(v[2]*sc[2] + sh[2], v[3]*sc[3] + sh[3]);
      *(uint2*)(feat + ((s*256 + f) ^ ((s & 7) << 3))) = p;
    }
  }
  // init prior=1, agg=0 (per-thread-private columns, no barrier needed)
  {
    const unsigned one2 = 0x3c003c00u;  // __half2(1.0, 1.0)
    #pragma unroll
    for (int j = 0; j < 16; ++j) priorS[j*256 + tid] = one2;
    #pragma unroll
    for (int j = 0; j < 8; ++j) aggS[j*256 + tid] = 0.0f;
  }
  __syncthreads();

  shared_dep(pk, shiftT, feat, big, hbuf, 0, w, l15, lg, swzv);

  #pragma unroll 1
  for (int st = 0; st < 3; ++st) {
    // attention: logits = BN(a @ at_W[st]) * prior, a = x[:,64:128] (x at big[0:4096])
    f32x4 z[4][2];
    zero4(z);
    gemm4<2, 128, 64>(pk + PK_AT_US + st*16384, big, w, l15, lg, swzv, z);
    #pragma unroll
    for (int mi = 0; mi < 4; ++mi) {
      const f32x4 bz = *(const f32x4*)(shiftT + (10 + st)*256 + (w + 4*mi)*16 + lg*4);
      #pragma unroll
      for (int nf = 0; nf < 2; ++nf) {
        float2 p0 = h2f2(priorS[((mi<<2)|(nf<<1)|0)*256 + tid]);
        float2 p1 = h2f2(priorS[((mi<<2)|(nf<<1)|1)*256 + tid]);
        z[mi][nf][0] = (z[mi][nf][0] + bz[0]) * p0.x;
        z[mi][nf][1] = (z[mi][nf][1] + bz[1]) * p0.y;
        z[mi][nf][2] = (z[mi][nf][2] + bz[2]) * p1.x;
        z[mi][nf][3] = (z[mi][nf][3] + bz[3]) * p1.y;
      }
    }

    // ---- rowmax -> tau0 = max - 1 (red2 in hbuf; h is dead here)
    float tau[2];
    {
      #pragma unroll
      for (int nf = 0; nf < 2; ++nf) {
        float m = -1e30f;
        #pragma unroll
        for (int mi = 0; mi < 4; ++mi)
          #pragma unroll
          for (int c = 0; c < 4; ++c) m = fmaxf(m, z[mi][nf][c]);
        m = fmaxf(m, __shfl_xor(m, 16, 64));
        m = fmaxf(m, __shfl_xor(m, 32, 64));
        if (lg == 0) { int si = nf*16 + l15; red2[si*9 + w].x = m; }
      }
      __syncthreads();
      #pragma unroll
      for (int nf = 0; nf < 2; ++nf) {
        const int si = nf*16 + l15;
        float m = fmaxf(fmaxf(red2[si*9+0].x, red2[si*9+1].x),
                        fmaxf(red2[si*9+2].x, red2[si*9+3].x));
        tau[nf] = m - 1.0f;
      }
    }

    // ---- Newton iterations, 1 barrier each, uniform early exit
    int buf = 0;
    #pragma unroll 1
    for (int it = 0; it < 12; ++it) {
      buf ^= 1;
      float S[2], C[2];
      #pragma unroll
      for (int nf = 0; nf < 2; ++nf) {
        f32x4 s4 = splat4(0.0f), c4 = splat4(0.0f);
        #pragma unroll
        for (int mi = 0; mi < 4; ++mi)
          #pragma unroll
          for (int c = 0; c < 4; ++c) {
            float d = z[mi][nf][c] - tau[nf];
            s4[c] += fmaxf(d, 0.0f);
            c4[c] += (d > 0.0f) ? 1.0f : 0.0f;
          }
        float S_ = (s4[0] + s4[1]) + (s4[2] + s4[3]);
        float C_ = (c4[0] + c4[1]) + (c4[2] + c4[3]);
        S_ += __shfl_xor(S_, 16, 64); S_ += __shfl_xor(S_, 32, 64);
        C_ += __shfl_xor(C_, 16, 64); C_ += __shfl_xor(C_, 32, 64);
        S[nf] = S_; C[nf] = C_;
      }
      if (lg == 0) {
        #pragma unroll
        for (int nf = 0; nf < 2; ++nf) {
          int si = nf*16 + l15;
          float2 p; p.x = S[nf]; p.y = C[nf];
          red2[buf*288 + si*9 + w] = p;
        }
      }
      __syncthreads();
      bool ok = true;
      float tauN[2];
      #pragma unroll
      for (int nf = 0; nf < 2; ++nf) {
        const int si = nf*16 + l15;
        float Ss = 0.0f, Cs = 0.0f;
        #pragma unroll
        for (int i = 0; i < 4; ++i) { float2 p = red2[buf*288 + si*9 + i]; Ss += p.x; Cs += p.y; }
        ok = ok && (fabsf(Ss - 1.0f) < 1e-5f);
        tauN[nf] = tau[nf] + (Ss - 1.0f) / Cs;
      }
      if (__all(ok)) break;
      #pragma unroll
      for (int nf = 0; nf < 2; ++nf) tau[nf] = tauN[nf];
    }
    // no barrier needed: mask writes big, red2 lives in hbuf (disjoint)

    // mask, prior update (LDS), masked = mask * features -> big (full [32][256])
    #pragma unroll
    for (int mi = 0; mi < 4; ++mi) {
      const int f0 = (w + 4*mi)*16 + lg*4;
      #pragma unroll
      for (int nf = 0; nf < 2; ++nf) {
        const int si = nf*16 + l15;
        ushort4 fv = *(const ushort4*)(feat + ((si*256 + f0) ^ swzv));
        float m0 = fmaxf(z[mi][nf][0] - tau[nf], 0.0f);
        float m1 = fmaxf(z[mi][nf][1] - tau[nf], 0.0f);
        float m2 = fmaxf(z[mi][nf][2] - tau[nf], 0.0f);
        float m3 = fmaxf(z[mi][nf][3] - tau[nf], 0.0f);
        const int j0 = ((mi<<2)|(nf<<1)|0)*256 + tid;
        const int j1 = ((mi<<2)|(nf<<1)|1)*256 + tid;
        float2 p0 = h2f2(priorS[j0]);
        float2 p1 = h2f2(priorS[j1]);
        priorS[j0] = f22h2(p0.x * (RELAX - m0), p0.y * (RELAX - m1));
        priorS[j1] = f22h2(p1.x * (RELAX - m2), p1.y * (RELAX - m3));
        uint2 p;
        p.x = pk2(bf2f(fv.x) * m0, bf2f(fv.y) * m1);
        p.y = pk2(bf2f(fv.z) * m2, bf2f(fv.w) * m3);
        *(uint2*)(big + ((si*256 + f0) ^ swzv)) = p;
      }
    }
    __syncthreads();   // masked visible before G0 reads

    shared_dep(pk, shiftT, big, big, hbuf, st + 1, w, l15, lg, swzv);

    // out_agg += relu(x[:, :64]); x_final at big[0:4096]
    #pragma unroll
    for (int nf = 0; nf < 2; ++nf) {
      const int si = nf*16 + l15;
      const int f0 = w*16 + lg*4;
      uint2 xp = *(const uint2*)(big + ((si*128 + f0) ^ swzv));
      f32x4 xv = unpk4(xp);
      #pragma unroll
      for (int c = 0; c < 4; ++c)
        aggS[(nf*4 + c)*256 + tid] += fmaxf(xv[c], 0.0f);
    }
  }

  // final: out = out_agg @ Wout, split-bf16 (hi/lo) for precision
  __syncthreads();   // all agg reads of big done before restaging
  {
    #pragma unroll
    for (int nf = 0; nf < 2; ++nf) {
      const int si = nf*16 + l15;
      const int f0 = w*16 + lg*4;
      float a0 = aggS[(nf*4+0)*256 + tid];
      float a1 = aggS[(nf*4+1)*256 + tid];
      float a2 = aggS[(nf*4+2)*256 + tid];
      float a3 = aggS[(nf*4+3)*256 + tid];
      ushort4 hi, lo;
      u16 h0 = f2bf(a0); hi.x = h0; lo.x = f2bf(a0 - bf2f(h0));
      u16 h1 = f2bf(a1); hi.y = h1; lo.y = f2bf(a1 - bf2f(h1));
      u16 h2v = f2bf(a2); hi.z = h2v; lo.z = f2bf(a2 - bf2f(h2v));
      u16 h3 = f2bf(a3); hi.w = h3; lo.w = f2bf(a3 - bf2f(h3));
      *(ushort4*)(big + ((si*64 + f0) ^ swzv)) = hi;
      *(ushort4*)(big + 2048 + ((si*64 + f0) ^ swzv)) = lo;
    }
  }
  __syncthreads();

  // 64x64x(32 samples) GEMM: wave w -> out m-frag w, both sample n-frags
  {
    const int lane64 = lg*16 + l15;
    f32x4 facc[2];
    facc[0] = splat4(0.0f); facc[1] = splat4(0.0f);
    #pragma unroll
    for (int ks = 0; ks < 2; ++ks) {
      short8 aHi = *(const short8*)(pk + PK_WOUT_US   + (size_t)((w*2 + ks)*64 + lane64)*8);
      short8 aLo = *(const short8*)(pk + PK_WOUTLO_US + (size_t)((w*2 + ks)*64 + lane64)*8);
      #pragma unroll
      for (int j = 0; j < 2; ++j) {
        const int si = j*16 + l15;
        short8 bHi = *(const short8*)(big + ((si*64 + ks*32 + lg*8) ^ swzv));
        short8 bLo = *(const short8*)(big + 2048 + ((si*64 + ks*32 + lg*8) ^ swzv));
        facc[j] = __builtin_amdgcn_mfma_f32_16x16x32_bf16(aHi, bHi, facc[j], 0, 0, 0);
        facc[j] = __builtin_amdgcn_mfma_f32_16x16x32_bf16(aHi, bLo, facc[j], 0, 0, 0);
        facc[j] = __builtin_amdgcn_mfma_f32_16x16x32_bf16(aLo, bHi, facc[j], 0, 0, 0);
      }
    }
    #pragma unroll
    for (int j = 0; j < 2; ++j) {
      const int si = j*16 + l15;
      *(f32x4*)(out + (row0 + si)*64 + w*16 + lg*4) = facc[j];
    }
  }
}

// ---------------- launch ----------------
extern "C" void kernel_launch(void* const* d_in, const int* in_sizes, int n_in,
                              void* d_out, int out_size, void* d_ws, size_t ws_size,
                              hipStream_t stream)
{
  const float* inp   = (const float*)d_in[0];
  const float* in_g  = (const float*)d_in[1];
  const float* in_b  = (const float*)d_in[2];
  const float* in_m  = (const float*)d_in[3];
  const float* in_v  = (const float*)d_in[4];
  const float* sh_W0 = (const float*)d_in[5];
  const float* sh_W1 = (const float*)d_in[6];
  const float* sh_g  = (const float*)d_in[7];
  const float* sh_b  = (const float*)d_in[8];
  const float* sh_m  = (const float*)d_in[9];
  const float* sh_v  = (const float*)d_in[10];
  const float* dep_W = (const float*)d_in[11];
  const float* dep_g = (const float*)d_in[12];
  const float* dep_b = (const float*)d_in[13];
  const float* dep_m = (const float*)d_in[14];
  const float* dep_v = (const float*)d_in[15];
  const float* at_W  = (const float*)d_in[16];
  const float* at_g  = (const float*)d_in[17];
  const float* at_b  = (const float*)d_in[18];
  const float* at_m  = (const float*)d_in[19];
  const float* at_v  = (const float*)d_in[20];
  const float* Wout  = (const float*)d_in[21];

  unsigned char* ws = (unsigned char*)d_ws;
  u16*   pk     = (u16*)ws;
  float* shiftT = (float*)(ws + OFF_SHIFT);
  float* scaleT = (float*)(ws + OFF_SCALE);
  float* inSc   = (float*)(ws + OFF_INSC);
  float* inSh   = (float*)(ws + OFF_INSH);

  hipLaunchKernelGGL(prep_bn, dim3(14), dim3(256), 0, stream,
                     in_g, in_b, in_m, in_v, sh_g, sh_b, sh_m, sh_v,
                     dep_g, dep_b, dep_m, dep_v, at_g, at_b, at_m, at_v,
                     shiftT, scaleT, inSc, inSh);
  hipLaunchKernelGGL(prep_pack, dim3(204), dim3(256), 0, stream,
                     sh_W0, sh_W1, dep_W, at_W, Wout, scaleT, pk);
  hipLaunchKernelGGL(tabnet_main, dim3(4096), dim3(256), 0, stream,
                     inp, pk, shiftT, inSc, inSh, (float*)d_out);
}

// Round 12
// 508.276 us; speedup vs baseline: 1.7389x; 1.0491x over previous
//
#include <hip/hip_runtime.h>
#include <hip/hip_bf16.h>
#include <hip/hip_fp16.h>

typedef unsigned short u16;
typedef __attribute__((ext_vector_type(8))) short short8;
typedef __attribute__((ext_vector_type(4))) float f32x4;

#define BN_EPS    1e-3f
#define RELAX     1.3f
#define SQRT_HALF 0.7071067811865476f

// packed-weight offsets (ushort units)
#define PK_G0_US     0
#define PK_G1_US     65536
#define PK_DEP_US    98304
#define PK_AT_US     360448
#define PK_WOUT_US   409600
#define PK_WOUTLO_US 413696
// ws byte offsets
#define OFF_SHIFT 835584
#define OFF_SCALE 848896
#define OFF_INSC  862208
#define OFF_INSH  863232

__device__ __forceinline__ u16 f2bf(float x){
  unsigned u = __float_as_uint(x);
  return (u16)((u + 0x7fffu + ((u >> 16) & 1u)) >> 16);
}
__device__ __forceinline__ float bf2f(u16 h){ return __uint_as_float(((unsigned)h) << 16); }
__device__ __forceinline__ float sigm(float x){ return 1.0f / (1.0f + __expf(-x)); }
__device__ __forceinline__ f32x4 splat4(float x){ f32x4 v; v[0]=x; v[1]=x; v[2]=x; v[3]=x; return v; }

__device__ __forceinline__ unsigned pk2(float a, float b){
  float2 t; t.x = a; t.y = b;
  union { __hip_bfloat162 h; unsigned u; } v;
  v.h = __float22bfloat162_rn(t);
  return v.u;
}
__device__ __forceinline__ f32x4 unpk4(uint2 p){
  f32x4 r;
  r[0] = __uint_as_float(p.x << 16);
  r[1] = __uint_as_float(p.x & 0xffff0000u);
  r[2] = __uint_as_float(p.y << 16);
  r[3] = __uint_as_float(p.y & 0xffff0000u);
  return r;
}
__device__ __forceinline__ float2 h2f2(unsigned u){
  union { unsigned u; __half2 h; } v; v.u = u;
  return __half22float2(v.h);
}
__device__ __forceinline__ unsigned f22h2(float a, float b){
  union { __half2 h; unsigned u; } v; v.h = __floats2half2_rn(a, b);
  return v.u;
}

// ---------------- prep: BN scale/shift tables ----------------
__global__ void prep_bn(
  const float* in_g, const float* in_b, const float* in_m, const float* in_v,
  const float* sh_g, const float* sh_b, const float* sh_m, const float* sh_v,
  const float* dep_g, const float* dep_b, const float* dep_m, const float* dep_v,
  const float* at_g, const float* at_b, const float* at_m, const float* at_v,
  float* shiftT, float* scaleT, float* inSc, float* inSh)
{
  int r = blockIdx.x, f = threadIdx.x;
  if (r < 13) {
    const float *g, *bb, *mm, *vv;
    if (r < 2)       { g = sh_g + r*256;        bb = sh_b + r*256;        mm = sh_m + r*256;        vv = sh_v + r*256; }
    else if (r < 10) { int j = r-2;  g = dep_g + j*256; bb = dep_b + j*256; mm = dep_m + j*256; vv = dep_v + j*256; }
    else             { int j = r-10; g = at_g  + j*256; bb = at_b  + j*256; mm = at_m  + j*256; vv = at_v  + j*256; }
    float sc = g[f] * rsqrtf(vv[f] + BN_EPS);
    scaleT[r*256 + f] = sc;
    shiftT[r*256 + f] = bb[f] - mm[f]*sc;
  } else {
    float sc = in_g[f] * rsqrtf(in_v[f] + BN_EPS);
    inSc[f] = sc;
    inSh[f] = in_b[f] - in_m[f]*sc;
  }
}

// ---------------- prep: pack weights into MFMA A-fragment order (BN scale folded) ----------------
__global__ void prep_pack(
  const float* sh_W0, const float* sh_W1, const float* dep_W,
  const float* at_W, const float* Wout, const float* scaleT, u16* pk)
{
  int c = blockIdx.x*256 + threadIdx.x;   // 16B chunk id, 0..52223
  const float* W; int K, Nout, srow, base; bool lo = false;
  if (c < 8192)       { W = sh_W0; K = 256; Nout = 256; srow = 0;  base = 0; }
  else if (c < 12288) { W = sh_W1; K = 128; Nout = 256; srow = 1;  base = 8192; }
  else if (c < 45056) { int j = (c-12288) >> 12; W = dep_W + j*32768; K = 128; Nout = 256; srow = 2+j;  base = 12288 + j*4096; }
  else if (c < 51200) { int j = (c-45056) >> 11; W = at_W  + j*16384; K = 64;  Nout = 256; srow = 10+j; base = 45056 + j*2048; }
  else if (c < 51712) { W = Wout; K = 64; Nout = 64; srow = -1; base = 51200; }
  else                { W = Wout; K = 64; Nout = 64; srow = -1; base = 51712; lo = true; }
  int local = c - base;
  int lane  = local & 63;
  int t     = local >> 6;
  int KS    = K >> 5;
  int lsh   = (K == 256) ? 3 : (K == 128) ? 2 : 1;
  int ks    = t & (KS - 1);
  int mf    = t >> lsh;
  int feat  = mf*16 + (lane & 15);
  int k0    = ks*32 + ((lane >> 4) << 3);
  float scl = (srow < 0) ? 1.0f : scaleT[srow*256 + feat];
  u16 v[8];
  #pragma unroll
  for (int j = 0; j < 8; ++j) {
    float x = W[(size_t)(k0 + j)*Nout + feat] * scl;
    u16 h = f2bf(x);
    if (lo) h = f2bf(x - bf2f(h));
    v[j] = h;
  }
  ushort4* d4 = (ushort4*)(pk + (size_t)c*8);
  ushort4 p0; p0.x=v[0]; p0.y=v[1]; p0.z=v[2]; p0.w=v[3];
  ushort4 p1; p1.x=v[4]; p1.y=v[5]; p1.z=v[6]; p1.w=v[7];
  d4[0] = p0; d4[1] = p1;
}

// ---------------- gemm: 4 m-frags x 2 n-frags, manual even/odd double-buffer ----------------
template<int KS, int LDB, int KOFF>
__device__ __forceinline__ void gemm4(const u16* __restrict__ pk, const u16* bufB,
                                      int w, int l15, int lg, int swzv, f32x4 acc[4][2])
{
  const int lane = lg*16 + l15;
  short8 ae[4], be[2], ao[4], bo[2];
  #pragma unroll
  for (int nf = 0; nf < 2; ++nf) {
    int idx = (nf*16 + l15)*LDB + KOFF + lg*8;
    be[nf] = *(const short8*)(bufB + (idx ^ swzv));
  }
  #pragma unroll
  for (int mi = 0; mi < 4; ++mi)
    ae[mi] = *(const short8*)(pk + (size_t)(((w + 4*mi)*KS)*64 + lane)*8);

  #pragma unroll 1
  for (int ks = 0; ks < KS; ks += 2) {
    #pragma unroll
    for (int nf = 0; nf < 2; ++nf) {
      int idx = (nf*16 + l15)*LDB + KOFF + (ks+1)*32 + lg*8;
      bo[nf] = *(const short8*)(bufB + (idx ^ swzv));
    }
    #pragma unroll
    for (int mi = 0; mi < 4; ++mi)
      ao[mi] = *(const short8*)(pk + (size_t)(((w + 4*mi)*KS + ks + 1)*64 + lane)*8);
    #pragma unroll
    for (int mi = 0; mi < 4; ++mi) {
      acc[mi][0] = __builtin_amdgcn_mfma_f32_16x16x32_bf16(ae[mi], be[0], acc[mi][0], 0, 0, 0);
      acc[mi][1] = __builtin_amdgcn_mfma_f32_16x16x32_bf16(ae[mi], be[1], acc[mi][1], 0, 0, 0);
    }
    if (ks + 2 < KS) {
      #pragma unroll
      for (int nf = 0; nf < 2; ++nf) {
        int idx = (nf*16 + l15)*LDB + KOFF + (ks+2)*32 + lg*8;
        be[nf] = *(const short8*)(bufB + (idx ^ swzv));
      }
      #pragma unroll
      for (int mi = 0; mi < 4; ++mi)
        ae[mi] = *(const short8*)(pk + (size_t)(((w + 4*mi)*KS + ks + 2)*64 + lane)*8);
    }
    #pragma unroll
    for (int mi = 0; mi < 4; ++mi) {
      acc[mi][0] = __builtin_amdgcn_mfma_f32_16x16x32_bf16(ao[mi], bo[0], acc[mi][0], 0, 0, 0);
      acc[mi][1] = __builtin_amdgcn_mfma_f32_16x16x32_bf16(ao[mi], bo[1], acc[mi][1], 0, 0, 0);
    }
  }
}

__device__ __forceinline__ void zero4(f32x4 acc[4][2]){
  #pragma unroll
  for (int mi = 0; mi < 4; ++mi)
    #pragma unroll
    for (int nf = 0; nf < 2; ++nf)
      acc[mi][nf] = splat4(0.0f);
}

// GLU epilogue: h[mi][nf], mi in {0,1} -> features (w+4*mi)*16 + lg*4
__device__ __forceinline__ void glu_epi4(const f32x4 acc[4][2], const float* __restrict__ shrow,
                                         int w, int lg, f32x4 h[2][2])
{
  #pragma unroll
  for (int mi = 0; mi < 2; ++mi) {
    const int f0 = (w + 4*mi)*16 + lg*4;
    const f32x4 bh = *(const f32x4*)(shrow + f0);
    const f32x4 bg = *(const f32x4*)(shrow + f0 + 128);
    #pragma unroll
    for (int nf = 0; nf < 2; ++nf)
      #pragma unroll
      for (int c = 0; c < 4; ++c) {
        float v = acc[mi][nf][c] + bh[c];
        float g = acc[mi+2][nf][c] + bg[c];
        h[mi][nf][c] = v * sigm(g);
      }
  }
}

// write this wave's 32 features of a 128-wide activation [32][128] bf16 (swizzled)
__device__ __forceinline__ void write_half(u16* dst, const f32x4 v[2][2], int w, int l15, int lg, int swzv)
{
  #pragma unroll
  for (int mi = 0; mi < 2; ++mi) {
    const int f0 = (w + 4*mi)*16 + lg*4;
    #pragma unroll
    for (int nf = 0; nf < 2; ++nf) {
      const int s = nf*16 + l15;
      uint2 p;
      p.x = pk2(v[mi][nf][0], v[mi][nf][1]);
      p.y = pk2(v[mi][nf][2], v[mi][nf][3]);
      *(uint2*)(dst + ((s*128 + f0) ^ swzv)) = p;
    }
  }
}

// shared_block + dep_block. h in hbuf; x ping-pongs between big halves;
// x_final at big[0:4096]. bf16 h/x re-read from LDS (no f32 copies across gemms).
__device__ __forceinline__ void shared_dep(const u16* __restrict__ pk, const float* __restrict__ shiftT,
                                           const u16* binput, u16* big, u16* hbuf, int inv,
                                           int w, int l15, int lg, int swzv)
{
  f32x4 acc[4][2];
  zero4(acc);
  gemm4<8, 256, 0>(pk + PK_G0_US, binput, w, l15, lg, swzv, acc);
  {
    f32x4 h[2][2];
    glu_epi4(acc, shiftT + 0, w, lg, h);
    write_half(hbuf, h, w, l15, lg, swzv);   // hbuf disjoint from binput
  }
  __syncthreads();                           // B1: h visible; all G0 reads done

  zero4(acc);
  gemm4<4, 128, 0>(pk + PK_G1_US, hbuf, w, l15, lg, swzv, acc);
  {
    f32x4 h2[2][2];
    glu_epi4(acc, shiftT + 256, w, lg, h2);
    f32x4 xv[2][2];
    #pragma unroll
    for (int mi = 0; mi < 2; ++mi) {
      const int f0 = (w + 4*mi)*16 + lg*4;
      #pragma unroll
      for (int nf = 0; nf < 2; ++nf) {
        const int s = nf*16 + l15;
        uint2 hp = *(const uint2*)(hbuf + ((s*128 + f0) ^ swzv));
        f32x4 hv = unpk4(hp);
        xv[mi][nf] = (hv + h2[mi][nf]) * SQRT_HALF;
      }
    }
    write_half(big, xv, w, l15, lg, swzv);   // x -> big[0:4096]
  }
  __syncthreads();                           // B2: x visible

  const u16* xin = big;
  u16* xout = big + 4096;
  #pragma unroll
  for (int i = 0; i < 2; ++i) {
    zero4(acc);
    gemm4<4, 128, 0>(pk + PK_DEP_US + (inv*2 + i)*32768, xin, w, l15, lg, swzv, acc);
    f32x4 hd[2][2];
    glu_epi4(acc, shiftT + (2 + inv*2 + i)*256, w, lg, hd);
    #pragma unroll
    for (int mi = 0; mi < 2; ++mi) {
      const int f0 = (w + 4*mi)*16 + lg*4;
      #pragma unroll
      for (int nf = 0; nf < 2; ++nf) {
        const int s = nf*16 + l15;
        uint2 xp = *(const uint2*)(xin + ((s*128 + f0) ^ swzv));
        f32x4 xo = unpk4(xp);
        hd[mi][nf] = (xo + hd[mi][nf]) * SQRT_HALF;
      }
    }
    write_half(xout, hd, w, l15, lg, swzv);  // xout disjoint from xin
    __syncthreads();                         // B3/B4: x' visible
    const u16* t = xin; xin = xout; xout = (u16*)t;
  }
  // x_final at big[0:4096]
}

// ---------------- main fused kernel ----------------
// 32 samples/block, 4 waves. LDS 73 KiB -> 2 blocks/CU (149.5 <= 160 KiB).
// Sparsemax is WAVE-LOCAL: z transposed once through LDS (zbuf aliases the
// dead big/hbuf region); each lane owns one sample (s = w*8 + lane>>3) and
// 32 features in 8 XOR-interleaved chunks -> Newton needs 0 barriers.
__global__ void __launch_bounds__(256, 2)
tabnet_main(const float* __restrict__ inp, const u16* __restrict__ pk,
            const float* __restrict__ shiftT, const float* __restrict__ inSc,
            const float* __restrict__ inSh, float* __restrict__ out)
{
  __shared__ __align__(16) u16 feat[32*256];     // 16 KB
  __shared__ __align__(16) u16 uni[16640];       // 33,280 B: zbuf f32[32][260] | big(16K)+hbuf(8K)
  __shared__ unsigned priorT[32*132];            // 16,896 B: prior half2 pairs, padded stride
  __shared__ float    aggS[8*256];               // 8 KB: out_agg f32, [j][tid]
  u16*   big  = uni;
  u16*   hbuf = uni + 8192;
  float* zbuf = (float*)uni;

  const int tid  = threadIdx.x;
  const int w    = tid >> 6;        // 0..3
  const int lane = tid & 63;
  const int l15  = lane & 15, lg = lane >> 4;
  const int swzv = (l15 & 7) << 3;
  const int a    = lane >> 3;       // sample offset within wave (0..7)
  const int b    = lane & 7;        // feature-chunk class (0..7)
  const int s_own = w*8 + a;        // owned sample (s_own & 7 == a)
  const long long row0 = (long long)blockIdx.x * 32;

  // stage 0: features = BN(inputs) -> feat (bf16, swizzled [sample][256])
  {
    const int f = lane*4;
    const f32x4 sc = *(const f32x4*)(inSc + f);
    const f32x4 sh = *(const f32x4*)(inSh + f);
    #pragma unroll
    for (int j = 0; j < 8; ++j) {
      const int s = j*4 + w;
      f32x4 v = *(const f32x4*)(inp + (row0 + s)*256 + f);
      uint2 p;
      p.x = pk2(v[0]*sc[0] + sh[0], v[1]*sc[1] + sh[1]);
      p.y = pk2(v[2]*sc[2] + sh[2], v[3]*sc[3] + sh[3]);
      *(uint2*)(feat + ((s*256 + f) ^ ((s & 7) << 3))) = p;
    }
  }
  // init prior=1 (own transposed slots), agg=0 (own columns)
  {
    #pragma unroll
    for (int j = 0; j < 8; ++j) {
      const int c = (b ^ a) + 8*j;
      uint2 one; one.x = 0x3c003c00u; one.y = 0x3c003c00u;
      *(uint2*)(priorT + s_own*132 + 2*c) = one;
    }
    #pragma unroll
    for (int j = 0; j < 8; ++j) aggS[j*256 + tid] = 0.0f;
  }
  __syncthreads();

  shared_dep(pk, shiftT, feat, big, hbuf, 0, w, l15, lg, swzv);

  #pragma unroll 1
  for (int st = 0; st < 3; ++st) {
    // attention: raw logits = a @ at_W[st], a = x[:,64:128] (x at big[0:4096])
    f32x4 z[4][2];
    zero4(z);
    gemm4<2, 128, 64>(pk + PK_AT_US + st*16384, big, w, l15, lg, swzv, z);
    __syncthreads();   // B_a: all waves done reading big (x) before z-write clobbers

    // spill raw z to zbuf f32[32][260] (aliases big/hbuf; both dead now)
    #pragma unroll
    for (int mi = 0; mi < 4; ++mi) {
      const int F0 = (w + 4*mi)*16 + lg*4;
      #pragma unroll
      for (int nf = 0; nf < 2; ++nf) {
        const int s = nf*16 + l15;
        *(f32x4*)(zbuf + s*260 + F0) = z[mi][nf];
      }
    }
    __syncthreads();   // B_t: z visible

    // transposed assemble: zT = (z + bias) * prior; rowmax via 3 shuffles
    f32x4 zT[8];
    float tau;
    {
      const float* bias = shiftT + (10 + st)*256;
      float mx = -1e30f;
      #pragma unroll
      for (int j = 0; j < 8; ++j) {
        const int c = (b ^ a) + 8*j;
        const int f = 4*c;
        f32x4 zv = *(const f32x4*)(zbuf + s_own*260 + f);
        const f32x4 bz = *(const f32x4*)(bias + f);
        uint2 pr = *(const uint2*)(priorT + s_own*132 + 2*c);
        float2 p0 = h2f2(pr.x), p1 = h2f2(pr.y);
        zv[0] = (zv[0] + bz[0]) * p0.x;
        zv[1] = (zv[1] + bz[1]) * p0.y;
        zv[2] = (zv[2] + bz[2]) * p1.x;
        zv[3] = (zv[3] + bz[3]) * p1.y;
        zT[j] = zv;
        mx = fmaxf(mx, fmaxf(fmaxf(zv[0], zv[1]), fmaxf(zv[2], zv[3])));
      }
      mx = fmaxf(mx, __shfl_xor(mx, 1, 64));
      mx = fmaxf(mx, __shfl_xor(mx, 2, 64));
      mx = fmaxf(mx, __shfl_xor(mx, 4, 64));
      tau = mx - 1.0f;
    }

    // Newton: wave-local (8 samples/wave), zero barriers, per-wave early exit
    #pragma unroll 1
    for (int it = 0; it < 12; ++it) {
      float S = 0.0f, C = 0.0f;
      #pragma unroll
      for (int j = 0; j < 8; ++j)
        #pragma unroll
        for (int c4 = 0; c4 < 4; ++c4) {
          float d = zT[j][c4] - tau;
          S += fmaxf(d, 0.0f);
          C += (d > 0.0f) ? 1.0f : 0.0f;
        }
      S += __shfl_xor(S, 1, 64); C += __shfl_xor(C, 1, 64);
      S += __shfl_xor(S, 2, 64); C += __shfl_xor(C, 2, 64);
      S += __shfl_xor(S, 4, 64); C += __shfl_xor(C, 4, 64);
      if (__all(fabsf(S - 1.0f) < 1e-5f)) break;
      tau += (S - 1.0f) / C;
    }

    __syncthreads();   // B_m: all waves done reading zbuf before mask overwrites big

    // mask + prior update + masked = mask * features -> big ([32][256] bf16 swizzled)
    #pragma unroll
    for (int j = 0; j < 8; ++j) {
      const int c = (b ^ a) + 8*j;
      const int f = 4*c;
      float m0 = fmaxf(zT[j][0] - tau, 0.0f);
      float m1 = fmaxf(zT[j][1] - tau, 0.0f);
      float m2 = fmaxf(zT[j][2] - tau, 0.0f);
      float m3 = fmaxf(zT[j][3] - tau, 0.0f);
      uint2 pr = *(const uint2*)(priorT + s_own*132 + 2*c);
      float2 p0 = h2f2(pr.x), p1 = h2f2(pr.y);
      pr.x = f22h2(p0.x*(RELAX - m0), p0.y*(RELAX - m1));
      pr.y = f22h2(p1.x*(RELAX - m2), p1.y*(RELAX - m3));
      *(uint2*)(priorT + s_own*132 + 2*c) = pr;
      const int idx = (s_own*256 + f) ^ (a << 3);
      ushort4 fv = *(const ushort4*)(feat + idx);
      uint2 o;
      o.x = pk2(bf2f(fv.x)*m0, bf2f(fv.y)*m1);
      o.y = pk2(bf2f(fv.z)*m2, bf2f(fv.w)*m3);
      *(uint2*)(big + idx) = o;
    }
    __syncthreads();   // B_g0: masked visible before G0 reads

    shared_dep(pk, shiftT, big, big, hbuf, st + 1, w, l15, lg, swzv);

    // out_agg += relu(x[:, :64]); x_final at big[0:4096]
    #pragma unroll
    for (int nf = 0; nf < 2; ++nf) {
      const int si = nf*16 + l15;
      const int f0 = w*16 + lg*4;
      uint2 xp = *(const uint2*)(big + ((si*128 + f0) ^ swzv));
      f32x4 xv = unpk4(xp);
      #pragma unroll
      for (int c = 0; c < 4; ++c)
        aggS[(nf*4 + c)*256 + tid] += fmaxf(xv[c], 0.0f);
    }
  }

  // final: out = out_agg @ Wout, split-bf16 (hi/lo) for precision
  __syncthreads();   // all agg reads of big done before restaging
  {
    #pragma unroll
    for (int nf = 0; nf < 2; ++nf) {
      const int si = nf*16 + l15;
      const int f0 = w*16 + lg*4;
      float a0 = aggS[(nf*4+0)*256 + tid];
      float a1 = aggS[(nf*4+1)*256 + tid];
      float a2 = aggS[(nf*4+2)*256 + tid];
      float a3 = aggS[(nf*4+3)*256 + tid];
      ushort4 hi, lo;
      u16 h0 = f2bf(a0); hi.x = h0; lo.x = f2bf(a0 - bf2f(h0));
      u16 h1 = f2bf(a1); hi.y = h1; lo.y = f2bf(a1 - bf2f(h1));
      u16 h2v = f2bf(a2); hi.z = h2v; lo.z = f2bf(a2 - bf2f(h2v));
      u16 h3 = f2bf(a3); hi.w = h3; lo.w = f2bf(a3 - bf2f(h3));
      *(ushort4*)(big + ((si*64 + f0) ^ swzv)) = hi;
      *(ushort4*)(big + 2048 + ((si*64 + f0) ^ swzv)) = lo;
    }
  }
  __syncthreads();

  // 64x64x(32 samples) GEMM: wave w -> out m-frag w, both sample n-frags
  {
    const int lane64 = lg*16 + l15;
    f32x4 facc[2];
    facc[0] = splat4(0.0f); facc[1] = splat4(0.0f);
    #pragma unroll
    for (int ks = 0; ks < 2; ++ks) {
      short8 aHi = *(const short8*)(pk + PK_WOUT_US   + (size_t)((w*2 + ks)*64 + lane64)*8);
      short8 aLo = *(const short8*)(pk + PK_WOUTLO_US + (size_t)((w*2 + ks)*64 + lane64)*8);
      #pragma unroll
      for (int j = 0; j < 2; ++j) {
        const int si = j*16 + l15;
        short8 bHi = *(const short8*)(big + ((si*64 + ks*32 + lg*8) ^ swzv));
        short8 bLo = *(const short8*)(big + 2048 + ((si*64 + ks*32 + lg*8) ^ swzv));
        facc[j] = __builtin_amdgcn_mfma_f32_16x16x32_bf16(aHi, bHi, facc[j], 0, 0, 0);
        facc[j] = __builtin_amdgcn_mfma_f32_16x16x32_bf16(aHi, bLo, facc[j], 0, 0, 0);
        facc[j] = __builtin_amdgcn_mfma_f32_16x16x32_bf16(aLo, bHi, facc[j], 0, 0, 0);
      }
    }
    #pragma unroll
    for (int j = 0; j < 2; ++j) {
      const int si = j*16 + l15;
      *(f32x4*)(out + (row0 + si)*64 + w*16 + lg*4) = facc[j];
    }
  }
}

// ---------------- launch ----------------
extern "C" void kernel_launch(void* const* d_in, const int* in_sizes, int n_in,
                              void* d_out, int out_size, void* d_ws, size_t ws_size,
                              hipStream_t stream)
{
  const float* inp   = (const float*)d_in[0];
  const float* in_g  = (const float*)d_in[1];
  const float* in_b  = (const float*)d_in[2];
  const float* in_m  = (const float*)d_in[3];
  const float* in_v  = (const float*)d_in[4];
  const float* sh_W0 = (const float*)d_in[5];
  const float* sh_W1 = (const float*)d_in[6];
  const float* sh_g  = (const float*)d_in[7];
  const float* sh_b  = (const float*)d_in[8];
  const float* sh_m  = (const float*)d_in[9];
  const float* sh_v  = (const float*)d_in[10];
  const float* dep_W = (const float*)d_in[11];
  const float* dep_g = (const float*)d_in[12];
  const float* dep_b = (const float*)d_in[13];
  const float* dep_m = (const float*)d_in[14];
  const float* dep_v = (const float*)d_in[15];
  const float* at_W  = (const float*)d_in[16];
  const float* at_g  = (const float*)d_in[17];
  const float* at_b  = (const float*)d_in[18];
  const float* at_m  = (const float*)d_in[19];
  const float* at_v  = (const float*)d_in[20];
  const float* Wout  = (const float*)d_in[21];

  unsigned char* ws = (unsigned char*)d_ws;
  u16*   pk     = (u16*)ws;
  float* shiftT = (float*)(ws + OFF_SHIFT);
  float* scaleT = (float*)(ws + OFF_SCALE);
  float* inSc   = (float*)(ws + OFF_INSC);
  float* inSh   = (float*)(ws + OFF_INSH);

  hipLaunchKernelGGL(prep_bn, dim3(14), dim3(256), 0, stream,
                     in_g, in_b, in_m, in_v, sh_g, sh_b, sh_m, sh_v,
                     dep_g, dep_b, dep_m, dep_v, at_g, at_b, at_m, at_v,
                     shiftT, scaleT, inSc, inSh);
  hipLaunchKernelGGL(prep_pack, dim3(204), dim3(256), 0, stream,
                     sh_W0, sh_W1, dep_W, at_W, Wout, scaleT, pk);
  hipLaunchKernelGGL(tabnet_main, dim3(4096), dim3(256), 0, stream,
                     inp, pk, shiftT, inSc, inSh, (float*)d_out);
}

// Round 13
// 493.494 us; speedup vs baseline: 1.7910x; 1.0300x over previous
//
#include <hip/hip_runtime.h>
#include <hip/hip_bf16.h>
#include <hip/hip_fp16.h>

typedef unsigned short u16;
typedef __attribute__((ext_vector_type(8))) short short8;
typedef __attribute__((ext_vector_type(4))) float f32x4;

#define BN_EPS    1e-3f
#define RELAX     1.3f
#define SQRT_HALF 0.7071067811865476f

// packed-weight offsets (ushort units)
#define PK_G0_US     0
#define PK_G1_US     65536
#define PK_DEP_US    98304
#define PK_AT_US     360448
#define PK_WOUT_US   409600
#define PK_WOUTLO_US 413696
// ws byte offsets
#define OFF_SHIFT 835584
#define OFF_SCALE 848896
#define OFF_INSC  862208
#define OFF_INSH  863232

__device__ __forceinline__ u16 f2bf(float x){
  unsigned u = __float_as_uint(x);
  return (u16)((u + 0x7fffu + ((u >> 16) & 1u)) >> 16);
}
__device__ __forceinline__ float bf2f(u16 h){ return __uint_as_float(((unsigned)h) << 16); }
__device__ __forceinline__ float sigm(float x){ return 1.0f / (1.0f + __expf(-x)); }
__device__ __forceinline__ f32x4 splat4(float x){ f32x4 v; v[0]=x; v[1]=x; v[2]=x; v[3]=x; return v; }

__device__ __forceinline__ unsigned pk2(float a, float b){
  float2 t; t.x = a; t.y = b;
  union { __hip_bfloat162 h; unsigned u; } v;
  v.h = __float22bfloat162_rn(t);
  return v.u;
}
__device__ __forceinline__ f32x4 unpk4(uint2 p){
  f32x4 r;
  r[0] = __uint_as_float(p.x << 16);
  r[1] = __uint_as_float(p.x & 0xffff0000u);
  r[2] = __uint_as_float(p.y << 16);
  r[3] = __uint_as_float(p.y & 0xffff0000u);
  return r;
}
__device__ __forceinline__ float2 h2f2(unsigned u){
  union { unsigned u; __half2 h; } v; v.u = u;
  return __half22float2(v.h);
}
__device__ __forceinline__ unsigned f22h2(float a, float b){
  union { __half2 h; unsigned u; } v; v.h = __floats2half2_rn(a, b);
  return v.u;
}

// ---------------- prep: BN scale/shift tables ----------------
__global__ void prep_bn(
  const float* in_g, const float* in_b, const float* in_m, const float* in_v,
  const float* sh_g, const float* sh_b, const float* sh_m, const float* sh_v,
  const float* dep_g, const float* dep_b, const float* dep_m, const float* dep_v,
  const float* at_g, const float* at_b, const float* at_m, const float* at_v,
  float* shiftT, float* scaleT, float* inSc, float* inSh)
{
  int r = blockIdx.x, f = threadIdx.x;
  if (r < 13) {
    const float *g, *bb, *mm, *vv;
    if (r < 2)       { g = sh_g + r*256;        bb = sh_b + r*256;        mm = sh_m + r*256;        vv = sh_v + r*256; }
    else if (r < 10) { int j = r-2;  g = dep_g + j*256; bb = dep_b + j*256; mm = dep_m + j*256; vv = dep_v + j*256; }
    else             { int j = r-10; g = at_g  + j*256; bb = at_b  + j*256; mm = at_m  + j*256; vv = at_v  + j*256; }
    float sc = g[f] * rsqrtf(vv[f] + BN_EPS);
    scaleT[r*256 + f] = sc;
    shiftT[r*256 + f] = bb[f] - mm[f]*sc;
  } else {
    float sc = in_g[f] * rsqrtf(in_v[f] + BN_EPS);
    inSc[f] = sc;
    inSh[f] = in_b[f] - in_m[f]*sc;
  }
}

// ---------------- prep: pack weights into MFMA A-fragment order (BN scale folded) ----------------
__global__ void prep_pack(
  const float* sh_W0, const float* sh_W1, const float* dep_W,
  const float* at_W, const float* Wout, const float* scaleT, u16* pk)
{
  int c = blockIdx.x*256 + threadIdx.x;   // 16B chunk id, 0..52223
  const float* W; int K, Nout, srow, base; bool lo = false;
  if (c < 8192)       { W = sh_W0; K = 256; Nout = 256; srow = 0;  base = 0; }
  else if (c < 12288) { W = sh_W1; K = 128; Nout = 256; srow = 1;  base = 8192; }
  else if (c < 45056) { int j = (c-12288) >> 12; W = dep_W + j*32768; K = 128; Nout = 256; srow = 2+j;  base = 12288 + j*4096; }
  else if (c < 51200) { int j = (c-45056) >> 11; W = at_W  + j*16384; K = 64;  Nout = 256; srow = 10+j; base = 45056 + j*2048; }
  else if (c < 51712) { W = Wout; K = 64; Nout = 64; srow = -1; base = 51200; }
  else                { W = Wout; K = 64; Nout = 64; srow = -1; base = 51712; lo = true; }
  int local = c - base;
  int lane  = local & 63;
  int t     = local >> 6;
  int KS    = K >> 5;
  int lsh   = (K == 256) ? 3 : (K == 128) ? 2 : 1;
  int ks    = t & (KS - 1);
  int mf    = t >> lsh;
  int feat  = mf*16 + (lane & 15);
  int k0    = ks*32 + ((lane >> 4) << 3);
  float scl = (srow < 0) ? 1.0f : scaleT[srow*256 + feat];
  u16 v[8];
  #pragma unroll
  for (int j = 0; j < 8; ++j) {
    float x = W[(size_t)(k0 + j)*Nout + feat] * scl;
    u16 h = f2bf(x);
    if (lo) h = f2bf(x - bf2f(h));
    v[j] = h;
  }
  ushort4* d4 = (ushort4*)(pk + (size_t)c*8);
  ushort4 p0; p0.x=v[0]; p0.y=v[1]; p0.z=v[2]; p0.w=v[3];
  ushort4 p1; p1.x=v[4]; p1.y=v[5]; p1.z=v[6]; p1.w=v[7];
  d4[0] = p0; d4[1] = p1;
}

// ---------------- gemm: 4 m-frags x 2 n-frags, manual even/odd double-buffer ----------------
template<int KS, int LDB, int KOFF>
__device__ __forceinline__ void gemm4(const u16* __restrict__ pk, const u16* bufB,
                                      int w, int l15, int lg, int swzv, f32x4 acc[4][2])
{
  const int lane = lg*16 + l15;
  short8 ae[4], be[2], ao[4], bo[2];
  #pragma unroll
  for (int nf = 0; nf < 2; ++nf) {
    int idx = (nf*16 + l15)*LDB + KOFF + lg*8;
    be[nf] = *(const short8*)(bufB + (idx ^ swzv));
  }
  #pragma unroll
  for (int mi = 0; mi < 4; ++mi)
    ae[mi] = *(const short8*)(pk + (size_t)(((w + 4*mi)*KS)*64 + lane)*8);

  #pragma unroll 1
  for (int ks = 0; ks < KS; ks += 2) {
    #pragma unroll
    for (int nf = 0; nf < 2; ++nf) {
      int idx = (nf*16 + l15)*LDB + KOFF + (ks+1)*32 + lg*8;
      bo[nf] = *(const short8*)(bufB + (idx ^ swzv));
    }
    #pragma unroll
    for (int mi = 0; mi < 4; ++mi)
      ao[mi] = *(const short8*)(pk + (size_t)(((w + 4*mi)*KS + ks + 1)*64 + lane)*8);
    #pragma unroll
    for (int mi = 0; mi < 4; ++mi) {
      acc[mi][0] = __builtin_amdgcn_mfma_f32_16x16x32_bf16(ae[mi], be[0], acc[mi][0], 0, 0, 0);
      acc[mi][1] = __builtin_amdgcn_mfma_f32_16x16x32_bf16(ae[mi], be[1], acc[mi][1], 0, 0, 0);
    }
    if (ks + 2 < KS) {
      #pragma unroll
      for (int nf = 0; nf < 2; ++nf) {
        int idx = (nf*16 + l15)*LDB + KOFF + (ks+2)*32 + lg*8;
        be[nf] = *(const short8*)(bufB + (idx ^ swzv));
      }
      #pragma unroll
      for (int mi = 0; mi < 4; ++mi)
        ae[mi] = *(const short8*)(pk + (size_t)(((w + 4*mi)*KS + ks + 2)*64 + lane)*8);
    }
    #pragma unroll
    for (int mi = 0; mi < 4; ++mi) {
      acc[mi][0] = __builtin_amdgcn_mfma_f32_16x16x32_bf16(ao[mi], bo[0], acc[mi][0], 0, 0, 0);
      acc[mi][1] = __builtin_amdgcn_mfma_f32_16x16x32_bf16(ao[mi], bo[1], acc[mi][1], 0, 0, 0);
    }
  }
}

// init acc with BN bias (C-in of first MFMA); exact same f32 math as epilogue add
__device__ __forceinline__ void init4(f32x4 acc[4][2], const float* __restrict__ shrow,
                                      int w, int lg)
{
  #pragma unroll
  for (int mi = 0; mi < 4; ++mi) {
    const f32x4 bv = *(const f32x4*)(shrow + (w + 4*mi)*16 + lg*4);
    acc[mi][0] = bv;
    acc[mi][1] = bv;
  }
}

// GLU epilogue (bias pre-folded into acc): h = v * sigmoid(g)
__device__ __forceinline__ void glu_epi4(const f32x4 acc[4][2], f32x4 h[2][2])
{
  #pragma unroll
  for (int mi = 0; mi < 2; ++mi)
    #pragma unroll
    for (int nf = 0; nf < 2; ++nf)
      #pragma unroll
      for (int c = 0; c < 4; ++c)
        h[mi][nf][c] = acc[mi][nf][c] * sigm(acc[mi+2][nf][c]);
}

// write this wave's 32 features of a 128-wide activation [32][128] bf16 (swizzled)
__device__ __forceinline__ void write_half(u16* dst, const f32x4 v[2][2], int w, int l15, int lg, int swzv)
{
  #pragma unroll
  for (int mi = 0; mi < 2; ++mi) {
    const int f0 = (w + 4*mi)*16 + lg*4;
    #pragma unroll
    for (int nf = 0; nf < 2; ++nf) {
      const int s = nf*16 + l15;
      uint2 p;
      p.x = pk2(v[mi][nf][0], v[mi][nf][1]);
      p.y = pk2(v[mi][nf][2], v[mi][nf][3]);
      *(uint2*)(dst + ((s*128 + f0) ^ swzv)) = p;
    }
  }
}

// shared_block + dep_block. h in hbuf; x ping-pongs between big halves;
// x_final at big[0:4096]. bf16 h/x re-read from LDS (no f32 copies across gemms).
__device__ __forceinline__ void shared_dep(const u16* __restrict__ pk, const float* __restrict__ shiftT,
                                           const u16* binput, u16* big, u16* hbuf, int inv,
                                           int w, int l15, int lg, int swzv)
{
  f32x4 acc[4][2];
  init4(acc, shiftT + 0, w, lg);
  gemm4<8, 256, 0>(pk + PK_G0_US, binput, w, l15, lg, swzv, acc);
  {
    f32x4 h[2][2];
    glu_epi4(acc, h);
    write_half(hbuf, h, w, l15, lg, swzv);   // hbuf disjoint from binput
  }
  __syncthreads();                           // B1: h visible; all G0 reads done

  init4(acc, shiftT + 256, w, lg);
  gemm4<4, 128, 0>(pk + PK_G1_US, hbuf, w, l15, lg, swzv, acc);
  {
    f32x4 h2[2][2];
    glu_epi4(acc, h2);
    f32x4 xv[2][2];
    #pragma unroll
    for (int mi = 0; mi < 2; ++mi) {
      const int f0 = (w + 4*mi)*16 + lg*4;
      #pragma unroll
      for (int nf = 0; nf < 2; ++nf) {
        const int s = nf*16 + l15;
        uint2 hp = *(const uint2*)(hbuf + ((s*128 + f0) ^ swzv));
        f32x4 hv = unpk4(hp);
        xv[mi][nf] = (hv + h2[mi][nf]) * SQRT_HALF;
      }
    }
    write_half(big, xv, w, l15, lg, swzv);   // x -> big[0:4096]
  }
  __syncthreads();                           // B2: x visible

  const u16* xin = big;
  u16* xout = big + 4096;
  #pragma unroll
  for (int i = 0; i < 2; ++i) {
    init4(acc, shiftT + (2 + inv*2 + i)*256, w, lg);
    gemm4<4, 128, 0>(pk + PK_DEP_US + (inv*2 + i)*32768, xin, w, l15, lg, swzv, acc);
    f32x4 hd[2][2];
    glu_epi4(acc, hd);
    #pragma unroll
    for (int mi = 0; mi < 2; ++mi) {
      const int f0 = (w + 4*mi)*16 + lg*4;
      #pragma unroll
      for (int nf = 0; nf < 2; ++nf) {
        const int s = nf*16 + l15;
        uint2 xp = *(const uint2*)(xin + ((s*128 + f0) ^ swzv));
        f32x4 xo = unpk4(xp);
        hd[mi][nf] = (xo + hd[mi][nf]) * SQRT_HALF;
      }
    }
    write_half(xout, hd, w, l15, lg, swzv);  // xout disjoint from xin
    __syncthreads();                         // B3/B4: x' visible
    const u16* t = xin; xin = xout; xout = (u16*)t;
  }
  // x_final at big[0:4096]
}

// ---------------- main fused kernel ----------------
// 32 samples/block, 4 waves. LDS 73 KiB -> 2 blocks/CU (149.5 <= 160 KiB).
// Sparsemax WAVE-LOCAL via one LDS transpose (zbuf aliases dead big/hbuf);
// each lane owns one sample. Attn bias folded into the MFMA acc init, so the
// spilled z already includes BN shift.
__global__ void __launch_bounds__(256, 2)
tabnet_main(const float* __restrict__ inp, const u16* __restrict__ pk,
            const float* __restrict__ shiftT, const float* __restrict__ inSc,
            const float* __restrict__ inSh, float* __restrict__ out)
{
  __shared__ __align__(16) u16 feat[32*256];     // 16 KB
  __shared__ __align__(16) u16 uni[16640];       // 33,280 B: zbuf f32[32][260] | big(16K)+hbuf(8K)
  __shared__ unsigned priorT[32*132];            // 16,896 B: prior half2 pairs, padded stride
  __shared__ float    aggS[8*256];               // 8 KB: out_agg f32, [j][tid]
  u16*   big  = uni;
  u16*   hbuf = uni + 8192;
  float* zbuf = (float*)uni;

  const int tid  = threadIdx.x;
  const int w    = tid >> 6;        // 0..3
  const int lane = tid & 63;
  const int l15  = lane & 15, lg = lane >> 4;
  const int swzv = (l15 & 7) << 3;
  const int a    = lane >> 3;       // sample offset within wave (0..7)
  const int b    = lane & 7;        // feature-chunk class (0..7)
  const int s_own = w*8 + a;        // owned sample (s_own & 7 == a)
  const long long row0 = (long long)blockIdx.x * 32;

  // stage 0: features = BN(inputs) -> feat (bf16, swizzled [sample][256])
  {
    const int f = lane*4;
    const f32x4 sc = *(const f32x4*)(inSc + f);
    const f32x4 sh = *(const f32x4*)(inSh + f);
    #pragma unroll
    for (int j = 0; j < 8; ++j) {
      const int s = j*4 + w;
      f32x4 v = *(const f32x4*)(inp + (row0 + s)*256 + f);
      uint2 p;
      p.x = pk2(v[0]*sc[0] + sh[0], v[1]*sc[1] + sh[1]);
      p.y = pk2(v[2]*sc[2] + sh[2], v[3]*sc[3] + sh[3]);
      *(uint2*)(feat + ((s*256 + f) ^ ((s & 7) << 3))) = p;
    }
  }
  // init prior=1 (own transposed slots), agg=0 (own columns)
  {
    #pragma unroll
    for (int j = 0; j < 8; ++j) {
      const int c = (b ^ a) + 8*j;
      uint2 one; one.x = 0x3c003c00u; one.y = 0x3c003c00u;
      *(uint2*)(priorT + s_own*132 + 2*c) = one;
    }
    #pragma unroll
    for (int j = 0; j < 8; ++j) aggS[j*256 + tid] = 0.0f;
  }
  __syncthreads();

  shared_dep(pk, shiftT, feat, big, hbuf, 0, w, l15, lg, swzv);

  #pragma unroll 1
  for (int st = 0; st < 3; ++st) {
    // attention: z = a @ at_W[st] + bias  (bias via acc init), a = x[:,64:128]
    f32x4 z[4][2];
    init4(z, shiftT + (10 + st)*256, w, lg);
    gemm4<2, 128, 64>(pk + PK_AT_US + st*16384, big, w, l15, lg, swzv, z);
    __syncthreads();   // B_a: all waves done reading big (x) before z-write clobbers

    // spill z (bias included) to zbuf f32[32][260] (aliases big/hbuf; both dead)
    #pragma unroll
    for (int mi = 0; mi < 4; ++mi) {
      const int F0 = (w + 4*mi)*16 + lg*4;
      #pragma unroll
      for (int nf = 0; nf < 2; ++nf) {
        const int s = nf*16 + l15;
        *(f32x4*)(zbuf + s*260 + F0) = z[mi][nf];
      }
    }
    __syncthreads();   // B_t: z visible

    // transposed assemble: zT = z * prior; rowmax via 3 shuffles
    f32x4 zT[8];
    float tau;
    {
      float mx = -1e30f;
      #pragma unroll
      for (int j = 0; j < 8; ++j) {
        const int c = (b ^ a) + 8*j;
        const int f = 4*c;
        f32x4 zv = *(const f32x4*)(zbuf + s_own*260 + f);
        uint2 pr = *(const uint2*)(priorT + s_own*132 + 2*c);
        float2 p0 = h2f2(pr.x), p1 = h2f2(pr.y);
        zv[0] *= p0.x;
        zv[1] *= p0.y;
        zv[2] *= p1.x;
        zv[3] *= p1.y;
        zT[j] = zv;
        mx = fmaxf(mx, fmaxf(fmaxf(zv[0], zv[1]), fmaxf(zv[2], zv[3])));
      }
      mx = fmaxf(mx, __shfl_xor(mx, 1, 64));
      mx = fmaxf(mx, __shfl_xor(mx, 2, 64));
      mx = fmaxf(mx, __shfl_xor(mx, 4, 64));
      tau = mx - 1.0f;
    }

    // Newton: wave-local, zero barriers, per-wave early exit (tol 1e-4)
    #pragma unroll 1
    for (int it = 0; it < 10; ++it) {
      float S = 0.0f, C = 0.0f;
      #pragma unroll
      for (int j = 0; j < 8; ++j)
        #pragma unroll
        for (int c4 = 0; c4 < 4; ++c4) {
          float d = zT[j][c4] - tau;
          S += fmaxf(d, 0.0f);
          C += (d > 0.0f) ? 1.0f : 0.0f;
        }
      S += __shfl_xor(S, 1, 64); C += __shfl_xor(C, 1, 64);
      S += __shfl_xor(S, 2, 64); C += __shfl_xor(C, 2, 64);
      S += __shfl_xor(S, 4, 64); C += __shfl_xor(C, 4, 64);
      if (__all(fabsf(S - 1.0f) < 1e-4f)) break;
      tau += (S - 1.0f) / C;
    }

    __syncthreads();   // B_m: all waves done reading zbuf before mask overwrites big

    // mask + prior update + masked = mask * features -> big ([32][256] bf16 swizzled)
    #pragma unroll
    for (int j = 0; j < 8; ++j) {
      const int c = (b ^ a) + 8*j;
      const int f = 4*c;
      float m0 = fmaxf(zT[j][0] - tau, 0.0f);
      float m1 = fmaxf(zT[j][1] - tau, 0.0f);
      float m2 = fmaxf(zT[j][2] - tau, 0.0f);
      float m3 = fmaxf(zT[j][3] - tau, 0.0f);
      uint2 pr = *(const uint2*)(priorT + s_own*132 + 2*c);
      float2 p0 = h2f2(pr.x), p1 = h2f2(pr.y);
      pr.x = f22h2(p0.x*(RELAX - m0), p0.y*(RELAX - m1));
      pr.y = f22h2(p1.x*(RELAX - m2), p1.y*(RELAX - m3));
      *(uint2*)(priorT + s_own*132 + 2*c) = pr;
      const int idx = (s_own*256 + f) ^ (a << 3);
      ushort4 fv = *(const ushort4*)(feat + idx);
      uint2 o;
      o.x = pk2(bf2f(fv.x)*m0, bf2f(fv.y)*m1);
      o.y = pk2(bf2f(fv.z)*m2, bf2f(fv.w)*m3);
      *(uint2*)(big + idx) = o;
    }
    __syncthreads();   // B_g0: masked visible before G0 reads

    shared_dep(pk, shiftT, big, big, hbuf, st + 1, w, l15, lg, swzv);

    // out_agg += relu(x[:, :64]); x_final at big[0:4096]
    #pragma unroll
    for (int nf = 0; nf < 2; ++nf) {
      const int si = nf*16 + l15;
      const int f0 = w*16 + lg*4;
      uint2 xp = *(const uint2*)(big + ((si*128 + f0) ^ swzv));
      f32x4 xv = unpk4(xp);
      #pragma unroll
      for (int c = 0; c < 4; ++c)
        aggS[(nf*4 + c)*256 + tid] += fmaxf(xv[c], 0.0f);
    }
  }

  // final: out = out_agg @ Wout, split-bf16 (hi/lo) for precision
  __syncthreads();   // all agg reads of big done before restaging
  {
    #pragma unroll
    for (int nf = 0; nf < 2; ++nf) {
      const int si = nf*16 + l15;
      const int f0 = w*16 + lg*4;
      float a0 = aggS[(nf*4+0)*256 + tid];
      float a1 = aggS[(nf*4+1)*256 + tid];
      float a2 = aggS[(nf*4+2)*256 + tid];
      float a3 = aggS[(nf*4+3)*256 + tid];
      ushort4 hi, lo;
      u16 h0 = f2bf(a0); hi.x = h0; lo.x = f2bf(a0 - bf2f(h0));
      u16 h1 = f2bf(a1); hi.y = h1; lo.y = f2bf(a1 - bf2f(h1));
      u16 h2v = f2bf(a2); hi.z = h2v; lo.z = f2bf(a2 - bf2f(h2v));
      u16 h3 = f2bf(a3); hi.w = h3; lo.w = f2bf(a3 - bf2f(h3));
      *(ushort4*)(big + ((si*64 + f0) ^ swzv)) = hi;
      *(ushort4*)(big + 2048 + ((si*64 + f0) ^ swzv)) = lo;
    }
  }
  __syncthreads();

  // 64x64x(32 samples) GEMM: wave w -> out m-frag w, both sample n-frags
  {
    const int lane64 = lg*16 + l15;
    f32x4 facc[2];
    facc[0] = splat4(0.0f); facc[1] = splat4(0.0f);
    #pragma unroll
    for (int ks = 0; ks < 2; ++ks) {
      short8 aHi = *(const short8*)(pk + PK_WOUT_US   + (size_t)((w*2 + ks)*64 + lane64)*8);
      short8 aLo = *(const short8*)(pk + PK_WOUTLO_US + (size_t)((w*2 + ks)*64 + lane64)*8);
      #pragma unroll
      for (int j = 0; j < 2; ++j) {
        const int si = j*16 + l15;
        short8 bHi = *(const short8*)(big + ((si*64 + ks*32 + lg*8) ^ swzv));
        short8 bLo = *(const short8*)(big + 2048 + ((si*64 + ks*32 + lg*8) ^ swzv));
        facc[j] = __builtin_amdgcn_mfma_f32_16x16x32_bf16(aHi, bHi, facc[j], 0, 0, 0);
        facc[j] = __builtin_amdgcn_mfma_f32_16x16x32_bf16(aHi, bLo, facc[j], 0, 0, 0);
        facc[j] = __builtin_amdgcn_mfma_f32_16x16x32_bf16(aLo, bHi, facc[j], 0, 0, 0);
      }
    }
    #pragma unroll
    for (int j = 0; j < 2; ++j) {
      const int si = j*16 + l15;
      *(f32x4*)(out + (row0 + si)*64 + w*16 + lg*4) = facc[j];
    }
  }
}

// ---------------- launch ----------------
extern "C" void kernel_launch(void* const* d_in, const int* in_sizes, int n_in,
                              void* d_out, int out_size, void* d_ws, size_t ws_size,
                              hipStream_t stream)
{
  const float* inp   = (const float*)d_in[0];
  const float* in_g  = (const float*)d_in[1];
  const float* in_b  = (const float*)d_in[2];
  const float* in_m  = (const float*)d_in[3];
  const float* in_v  = (const float*)d_in[4];
  const float* sh_W0 = (const float*)d_in[5];
  const float* sh_W1 = (const float*)d_in[6];
  const float* sh_g  = (const float*)d_in[7];
  const float* sh_b  = (const float*)d_in[8];
  const float* sh_m  = (const float*)d_in[9];
  const float* sh_v  = (const float*)d_in[10];
  const float* dep_W = (const float*)d_in[11];
  const float* dep_g = (const float*)d_in[12];
  const float* dep_b = (const float*)d_in[13];
  const float* dep_m = (const float*)d_in[14];
  const float* dep_v = (const float*)d_in[15];
  const float* at_W  = (const float*)d_in[16];
  const float* at_g  = (const float*)d_in[17];
  const float* at_b  = (const float*)d_in[18];
  const float* at_m  = (const float*)d_in[19];
  const float* at_v  = (const float*)d_in[20];
  const float* Wout  = (const float*)d_in[21];

  unsigned char* ws = (unsigned char*)d_ws;
  u16*   pk     = (u16*)ws;
  float* shiftT = (float*)(ws + OFF_SHIFT);
  float* scaleT = (float*)(ws + OFF_SCALE);
  float* inSc   = (float*)(ws + OFF_INSC);
  float* inSh   = (float*)(ws + OFF_INSH);

  hipLaunchKernelGGL(prep_bn, dim3(14), dim3(256), 0, stream,
                     in_g, in_b, in_m, in_v, sh_g, sh_b, sh_m, sh_v,
                     dep_g, dep_b, dep_m, dep_v, at_g, at_b, at_m, at_v,
                     shiftT, scaleT, inSc, inSh);
  hipLaunchKernelGGL(prep_pack, dim3(204), dim3(256), 0, stream,
                     sh_W0, sh_W1, dep_W, at_W, Wout, scaleT, pk);
  hipLaunchKernelGGL(tabnet_main, dim3(4096), dim3(256), 0, stream,
                     inp, pk, shiftT, inSc, inSh, (float*)d_out);
}

// Round 14
// 444.586 us; speedup vs baseline: 1.9880x; 1.1100x over previous
//
#include <hip/hip_runtime.h>
#include <hip/hip_bf16.h>
#include <hip/hip_fp16.h>

typedef unsigned short u16;
typedef __attribute__((ext_vector_type(8))) short short8;
typedef __attribute__((ext_vector_type(4))) float f32x4;

#define BN_EPS    1e-3f
#define RELAX     1.3f
#define SQRT_HALF 0.7071067811865476f
#define ZSTRIDE   272   // f32 units; 272 % 32 == 16 -> 4-aligned bank starts, uniform groups

// packed-weight offsets (ushort units)
#define PK_G0_US     0
#define PK_G1_US     65536
#define PK_DEP_US    98304
#define PK_AT_US     360448
#define PK_WOUT_US   409600
#define PK_WOUTLO_US 413696
// ws byte offsets
#define OFF_SHIFT 835584
#define OFF_SCALE 848896
#define OFF_INSC  862208
#define OFF_INSH  863232

__device__ __forceinline__ u16 f2bf(float x){
  unsigned u = __float_as_uint(x);
  return (u16)((u + 0x7fffu + ((u >> 16) & 1u)) >> 16);
}
__device__ __forceinline__ float bf2f(u16 h){ return __uint_as_float(((unsigned)h) << 16); }
// v_rcp_f32-based sigmoid (rel err ~2^-22, far below bf16 noise; avoids div chain)
__device__ __forceinline__ float sigm(float x){ return __builtin_amdgcn_rcpf(1.0f + __expf(-x)); }
__device__ __forceinline__ f32x4 splat4(float x){ f32x4 v; v[0]=x; v[1]=x; v[2]=x; v[3]=x; return v; }

__device__ __forceinline__ unsigned pk2(float a, float b){
  float2 t; t.x = a; t.y = b;
  union { __hip_bfloat162 h; unsigned u; } v;
  v.h = __float22bfloat162_rn(t);
  return v.u;
}
__device__ __forceinline__ f32x4 unpk4(uint2 p){
  f32x4 r;
  r[0] = __uint_as_float(p.x << 16);
  r[1] = __uint_as_float(p.x & 0xffff0000u);
  r[2] = __uint_as_float(p.y << 16);
  r[3] = __uint_as_float(p.y & 0xffff0000u);
  return r;
}
__device__ __forceinline__ float2 h2f2(unsigned u){
  union { unsigned u; __half2 h; } v; v.u = u;
  return __half22float2(v.h);
}
__device__ __forceinline__ unsigned f22h2(float a, float b){
  union { __half2 h; unsigned u; } v; v.h = __floats2half2_rn(a, b);
  return v.u;
}

// ---------------- prep: BN scale/shift tables ----------------
__global__ void prep_bn(
  const float* in_g, const float* in_b, const float* in_m, const float* in_v,
  const float* sh_g, const float* sh_b, const float* sh_m, const float* sh_v,
  const float* dep_g, const float* dep_b, const float* dep_m, const float* dep_v,
  const float* at_g, const float* at_b, const float* at_m, const float* at_v,
  float* shiftT, float* scaleT, float* inSc, float* inSh)
{
  int r = blockIdx.x, f = threadIdx.x;
  if (r < 13) {
    const float *g, *bb, *mm, *vv;
    if (r < 2)       { g = sh_g + r*256;        bb = sh_b + r*256;        mm = sh_m + r*256;        vv = sh_v + r*256; }
    else if (r < 10) { int j = r-2;  g = dep_g + j*256; bb = dep_b + j*256; mm = dep_m + j*256; vv = dep_v + j*256; }
    else             { int j = r-10; g = at_g  + j*256; bb = at_b  + j*256; mm = at_m  + j*256; vv = at_v  + j*256; }
    float sc = g[f] * rsqrtf(vv[f] + BN_EPS);
    scaleT[r*256 + f] = sc;
    shiftT[r*256 + f] = bb[f] - mm[f]*sc;
  } else {
    float sc = in_g[f] * rsqrtf(in_v[f] + BN_EPS);
    inSc[f] = sc;
    inSh[f] = in_b[f] - in_m[f]*sc;
  }
}

// ---------------- prep: pack weights into MFMA A-fragment order (BN scale folded) ----------------
__global__ void prep_pack(
  const float* sh_W0, const float* sh_W1, const float* dep_W,
  const float* at_W, const float* Wout, const float* scaleT, u16* pk)
{
  int c = blockIdx.x*256 + threadIdx.x;   // 16B chunk id, 0..52223
  const float* W; int K, Nout, srow, base; bool lo = false;
  if (c < 8192)       { W = sh_W0; K = 256; Nout = 256; srow = 0;  base = 0; }
  else if (c < 12288) { W = sh_W1; K = 128; Nout = 256; srow = 1;  base = 8192; }
  else if (c < 45056) { int j = (c-12288) >> 12; W = dep_W + j*32768; K = 128; Nout = 256; srow = 2+j;  base = 12288 + j*4096; }
  else if (c < 51200) { int j = (c-45056) >> 11; W = at_W  + j*16384; K = 64;  Nout = 256; srow = 10+j; base = 45056 + j*2048; }
  else if (c < 51712) { W = Wout; K = 64; Nout = 64; srow = -1; base = 51200; }
  else                { W = Wout; K = 64; Nout = 64; srow = -1; base = 51712; lo = true; }
  int local = c - base;
  int lane  = local & 63;
  int t     = local >> 6;
  int KS    = K >> 5;
  int lsh   = (K == 256) ? 3 : (K == 128) ? 2 : 1;
  int ks    = t & (KS - 1);
  int mf    = t >> lsh;
  int feat  = mf*16 + (lane & 15);
  int k0    = ks*32 + ((lane >> 4) << 3);
  float scl = (srow < 0) ? 1.0f : scaleT[srow*256 + feat];
  u16 v[8];
  #pragma unroll
  for (int j = 0; j < 8; ++j) {
    float x = W[(size_t)(k0 + j)*Nout + feat] * scl;
    u16 h = f2bf(x);
    if (lo) h = f2bf(x - bf2f(h));
    v[j] = h;
  }
  ushort4* d4 = (ushort4*)(pk + (size_t)c*8);
  ushort4 p0; p0.x=v[0]; p0.y=v[1]; p0.z=v[2]; p0.w=v[3];
  ushort4 p1; p1.x=v[4]; p1.y=v[5]; p1.z=v[6]; p1.w=v[7];
  d4[0] = p0; d4[1] = p1;
}

// ---------------- gemm: 4 m-frags x 2 n-frags, manual even/odd double-buffer ----------------
template<int KS, int LDB, int KOFF>
__device__ __forceinline__ void gemm4(const u16* __restrict__ pk, const u16* bufB,
                                      int w, int l15, int lg, int swzv, f32x4 acc[4][2])
{
  const int lane = lg*16 + l15;
  short8 ae[4], be[2], ao[4], bo[2];
  #pragma unroll
  for (int nf = 0; nf < 2; ++nf) {
    int idx = (nf*16 + l15)*LDB + KOFF + lg*8;
    be[nf] = *(const short8*)(bufB + (idx ^ swzv));
  }
  #pragma unroll
  for (int mi = 0; mi < 4; ++mi)
    ae[mi] = *(const short8*)(pk + (size_t)(((w + 4*mi)*KS)*64 + lane)*8);

  #pragma unroll 1
  for (int ks = 0; ks < KS; ks += 2) {
    #pragma unroll
    for (int nf = 0; nf < 2; ++nf) {
      int idx = (nf*16 + l15)*LDB + KOFF + (ks+1)*32 + lg*8;
      bo[nf] = *(const short8*)(bufB + (idx ^ swzv));
    }
    #pragma unroll
    for (int mi = 0; mi < 4; ++mi)
      ao[mi] = *(const short8*)(pk + (size_t)(((w + 4*mi)*KS + ks + 1)*64 + lane)*8);
    #pragma unroll
    for (int mi = 0; mi < 4; ++mi) {
      acc[mi][0] = __builtin_amdgcn_mfma_f32_16x16x32_bf16(ae[mi], be[0], acc[mi][0], 0, 0, 0);
      acc[mi][1] = __builtin_amdgcn_mfma_f32_16x16x32_bf16(ae[mi], be[1], acc[mi][1], 0, 0, 0);
    }
    if (ks + 2 < KS) {
      #pragma unroll
      for (int nf = 0; nf < 2; ++nf) {
        int idx = (nf*16 + l15)*LDB + KOFF + (ks+2)*32 + lg*8;
        be[nf] = *(const short8*)(bufB + (idx ^ swzv));
      }
      #pragma unroll
      for (int mi = 0; mi < 4; ++mi)
        ae[mi] = *(const short8*)(pk + (size_t)(((w + 4*mi)*KS + ks + 2)*64 + lane)*8);
    }
    #pragma unroll
    for (int mi = 0; mi < 4; ++mi) {
      acc[mi][0] = __builtin_amdgcn_mfma_f32_16x16x32_bf16(ao[mi], bo[0], acc[mi][0], 0, 0, 0);
      acc[mi][1] = __builtin_amdgcn_mfma_f32_16x16x32_bf16(ao[mi], bo[1], acc[mi][1], 0, 0, 0);
    }
  }
}

// init acc with BN bias (C-in of first MFMA); exact same f32 math as epilogue add
__device__ __forceinline__ void init4(f32x4 acc[4][2], const float* __restrict__ shrow,
                                      int w, int lg)
{
  #pragma unroll
  for (int mi = 0; mi < 4; ++mi) {
    const f32x4 bv = *(const f32x4*)(shrow + (w + 4*mi)*16 + lg*4);
    acc[mi][0] = bv;
    acc[mi][1] = bv;
  }
}

// GLU epilogue (bias pre-folded into acc): h = v * sigmoid(g)
__device__ __forceinline__ void glu_epi4(const f32x4 acc[4][2], f32x4 h[2][2])
{
  #pragma unroll
  for (int mi = 0; mi < 2; ++mi)
    #pragma unroll
    for (int nf = 0; nf < 2; ++nf)
      #pragma unroll
      for (int c = 0; c < 4; ++c)
        h[mi][nf][c] = acc[mi][nf][c] * sigm(acc[mi+2][nf][c]);
}

// write this wave's 32 features of a 128-wide activation [32][128] bf16 (swizzled)
__device__ __forceinline__ void write_half(u16* dst, const f32x4 v[2][2], int w, int l15, int lg, int swzv)
{
  #pragma unroll
  for (int mi = 0; mi < 2; ++mi) {
    const int f0 = (w + 4*mi)*16 + lg*4;
    #pragma unroll
    for (int nf = 0; nf < 2; ++nf) {
      const int s = nf*16 + l15;
      uint2 p;
      p.x = pk2(v[mi][nf][0], v[mi][nf][1]);
      p.y = pk2(v[mi][nf][2], v[mi][nf][3]);
      *(uint2*)(dst + ((s*128 + f0) ^ swzv)) = p;
    }
  }
}

// shared_block + dep_block. h in hbuf; x ping-pongs between big halves;
// x_final at big[0:4096]. bf16 h/x re-read from LDS (no f32 copies across gemms).
__device__ __forceinline__ void shared_dep(const u16* __restrict__ pk, const float* __restrict__ shiftT,
                                           const u16* binput, u16* big, u16* hbuf, int inv,
                                           int w, int l15, int lg, int swzv)
{
  f32x4 acc[4][2];
  init4(acc, shiftT + 0, w, lg);
  gemm4<8, 256, 0>(pk + PK_G0_US, binput, w, l15, lg, swzv, acc);
  {
    f32x4 h[2][2];
    glu_epi4(acc, h);
    write_half(hbuf, h, w, l15, lg, swzv);   // hbuf disjoint from binput
  }
  __syncthreads();                           // B1: h visible; all G0 reads done

  init4(acc, shiftT + 256, w, lg);
  gemm4<4, 128, 0>(pk + PK_G1_US, hbuf, w, l15, lg, swzv, acc);
  {
    f32x4 h2[2][2];
    glu_epi4(acc, h2);
    f32x4 xv[2][2];
    #pragma unroll
    for (int mi = 0; mi < 2; ++mi) {
      const int f0 = (w + 4*mi)*16 + lg*4;
      #pragma unroll
      for (int nf = 0; nf < 2; ++nf) {
        const int s = nf*16 + l15;
        uint2 hp = *(const uint2*)(hbuf + ((s*128 + f0) ^ swzv));
        f32x4 hv = unpk4(hp);
        xv[mi][nf] = (hv + h2[mi][nf]) * SQRT_HALF;
      }
    }
    write_half(big, xv, w, l15, lg, swzv);   // x -> big[0:4096]
  }
  __syncthreads();                           // B2: x visible

  const u16* xin = big;
  u16* xout = big + 4096;
  #pragma unroll
  for (int i = 0; i < 2; ++i) {
    init4(acc, shiftT + (2 + inv*2 + i)*256, w, lg);
    gemm4<4, 128, 0>(pk + PK_DEP_US + (inv*2 + i)*32768, xin, w, l15, lg, swzv, acc);
    f32x4 hd[2][2];
    glu_epi4(acc, hd);
    #pragma unroll
    for (int mi = 0; mi < 2; ++mi) {
      const int f0 = (w + 4*mi)*16 + lg*4;
      #pragma unroll
      for (int nf = 0; nf < 2; ++nf) {
        const int s = nf*16 + l15;
        uint2 xp = *(const uint2*)(xin + ((s*128 + f0) ^ swzv));
        f32x4 xo = unpk4(xp);
        hd[mi][nf] = (xo + hd[mi][nf]) * SQRT_HALF;
      }
    }
    write_half(xout, hd, w, l15, lg, swzv);  // xout disjoint from xin
    __syncthreads();                         // B3/B4: x' visible
    const u16* t = xin; xin = xout; xout = (u16*)t;
  }
  // x_final at big[0:4096]
}

// ---------------- main fused kernel ----------------
// 32 samples/block, 4 waves. LDS 76,288 B -> 2 blocks/CU (152.6 <= 160 KiB).
// Sparsemax WAVE-LOCAL via one LDS transpose; zbuf stride = 272 f32 so both
// the spill-write and the transposed read have 4-aligned, uniformly-spread
// bank-group starts (conflict-free at the 1024B/8-cycle floor).
__global__ void __launch_bounds__(256, 2)
tabnet_main(const float* __restrict__ inp, const u16* __restrict__ pk,
            const float* __restrict__ shiftT, const float* __restrict__ inSc,
            const float* __restrict__ inSh, float* __restrict__ out)
{
  __shared__ __align__(16) u16 feat[32*256];     // 16 KB
  __shared__ __align__(16) u16 uni[17408];       // 34,816 B: zbuf f32[32][272] | big(16K)+hbuf(8K)
  __shared__ unsigned priorT[32*132];            // 16,896 B: prior half2 pairs
  __shared__ float    aggS[8*256];               // 8 KB: out_agg f32, [j][tid]
  u16*   big  = uni;
  u16*   hbuf = uni + 8192;
  float* zbuf = (float*)uni;

  const int tid  = threadIdx.x;
  const int w    = tid >> 6;        // 0..3
  const int lane = tid & 63;
  const int l15  = lane & 15, lg = lane >> 4;
  const int swzv = (l15 & 7) << 3;
  const int a    = lane >> 3;       // sample offset within wave (0..7)
  const int b    = lane & 7;        // feature-chunk class (0..7)
  const int s_own = w*8 + a;        // owned sample
  const long long row0 = (long long)blockIdx.x * 32;

  // stage 0: features = BN(inputs) -> feat (bf16, swizzled [sample][256])
  {
    const int f = lane*4;
    const f32x4 sc = *(const f32x4*)(inSc + f);
    const f32x4 sh = *(const f32x4*)(inSh + f);
    #pragma unroll
    for (int j = 0; j < 8; ++j) {
      const int s = j*4 + w;
      f32x4 v = *(const f32x4*)(inp + (row0 + s)*256 + f);
      uint2 p;
      p.x = pk2(v[0]*sc[0] + sh[0], v[1]*sc[1] + sh[1]);
      p.y = pk2(v[2]*sc[2] + sh[2], v[3]*sc[3] + sh[3]);
      *(uint2*)(feat + ((s*256 + f) ^ ((s & 7) << 3))) = p;
    }
  }
  // init prior=1 (own transposed slots), agg=0 (own columns)
  {
    #pragma unroll
    for (int j = 0; j < 8; ++j) {
      const int c = (b ^ a) + 8*j;
      uint2 one; one.x = 0x3c003c00u; one.y = 0x3c003c00u;
      *(uint2*)(priorT + s_own*132 + 2*c) = one;
    }
    #pragma unroll
    for (int j = 0; j < 8; ++j) aggS[j*256 + tid] = 0.0f;
  }
  __syncthreads();

  shared_dep(pk, shiftT, feat, big, hbuf, 0, w, l15, lg, swzv);

  #pragma unroll 1
  for (int st = 0; st < 3; ++st) {
    // attention: z = a @ at_W[st] + bias  (bias via acc init), a = x[:,64:128]
    f32x4 z[4][2];
    init4(z, shiftT + (10 + st)*256, w, lg);
    gemm4<2, 128, 64>(pk + PK_AT_US + st*16384, big, w, l15, lg, swzv, z);
    __syncthreads();   // B_a: all waves done reading big (x) before z-write clobbers

    // spill z (bias included) to zbuf f32[32][ZSTRIDE] (aliases big/hbuf; both dead)
    #pragma unroll
    for (int mi = 0; mi < 4; ++mi) {
      const int F0 = (w + 4*mi)*16 + lg*4;
      #pragma unroll
      for (int nf = 0; nf < 2; ++nf) {
        const int s = nf*16 + l15;
        *(f32x4*)(zbuf + s*ZSTRIDE + F0) = z[mi][nf];
      }
    }
    __syncthreads();   // B_t: z visible

    // transposed assemble: zT = z * prior; rowmax via 3 shuffles
    f32x4 zT[8];
    float tau;
    {
      float mx = -1e30f;
      #pragma unroll
      for (int j = 0; j < 8; ++j) {
        const int c = (b ^ a) + 8*j;
        const int f = 4*c;
        f32x4 zv = *(const f32x4*)(zbuf + s_own*ZSTRIDE + f);
        uint2 pr = *(const uint2*)(priorT + s_own*132 + 2*c);
        float2 p0 = h2f2(pr.x), p1 = h2f2(pr.y);
        zv[0] *= p0.x;
        zv[1] *= p0.y;
        zv[2] *= p1.x;
        zv[3] *= p1.y;
        zT[j] = zv;
        mx = fmaxf(mx, fmaxf(fmaxf(zv[0], zv[1]), fmaxf(zv[2], zv[3])));
      }
      mx = fmaxf(mx, __shfl_xor(mx, 1, 64));
      mx = fmaxf(mx, __shfl_xor(mx, 2, 64));
      mx = fmaxf(mx, __shfl_xor(mx, 4, 64));
      tau = mx - 1.0f;
    }

    // Newton: wave-local, zero barriers, per-wave early exit (tol 1e-4)
    #pragma unroll 1
    for (int it = 0; it < 10; ++it) {
      float S = 0.0f, C = 0.0f;
      #pragma unroll
      for (int j = 0; j < 8; ++j)
        #pragma unroll
        for (int c4 = 0; c4 < 4; ++c4) {
          float d = zT[j][c4] - tau;
          S += fmaxf(d, 0.0f);
          C += (d > 0.0f) ? 1.0f : 0.0f;
        }
      S += __shfl_xor(S, 1, 64); C += __shfl_xor(C, 1, 64);
      S += __shfl_xor(S, 2, 64); C += __shfl_xor(C, 2, 64);
      S += __shfl_xor(S, 4, 64); C += __shfl_xor(C, 4, 64);
      if (__all(fabsf(S - 1.0f) < 1e-4f)) break;
      tau += (S - 1.0f) * __builtin_amdgcn_rcpf(C);
    }

    __syncthreads();   // B_m: all waves done reading zbuf before mask overwrites big

    // mask + prior update + masked = mask * features -> big ([32][256] bf16 swizzled)
    #pragma unroll
    for (int j = 0; j < 8; ++j) {
      const int c = (b ^ a) + 8*j;
      const int f = 4*c;
      float m0 = fmaxf(zT[j][0] - tau, 0.0f);
      float m1 = fmaxf(zT[j][1] - tau, 0.0f);
      float m2 = fmaxf(zT[j][2] - tau, 0.0f);
      float m3 = fmaxf(zT[j][3] - tau, 0.0f);
      uint2 pr = *(const uint2*)(priorT + s_own*132 + 2*c);
      float2 p0 = h2f2(pr.x), p1 = h2f2(pr.y);
      pr.x = f22h2(p0.x*(RELAX - m0), p0.y*(RELAX - m1));
      pr.y = f22h2(p1.x*(RELAX - m2), p1.y*(RELAX - m3));
      *(uint2*)(priorT + s_own*132 + 2*c) = pr;
      const int idx = (s_own*256 + f) ^ (a << 3);
      ushort4 fv = *(const ushort4*)(feat + idx);
      uint2 o;
      o.x = pk2(bf2f(fv.x)*m0, bf2f(fv.y)*m1);
      o.y = pk2(bf2f(fv.z)*m2, bf2f(fv.w)*m3);
      *(uint2*)(big + idx) = o;
    }
    __syncthreads();   // B_g0: masked visible before G0 reads

    shared_dep(pk, shiftT, big, big, hbuf, st + 1, w, l15, lg, swzv);

    // out_agg += relu(x[:, :64]); x_final at big[0:4096]
    #pragma unroll
    for (int nf = 0; nf < 2; ++nf) {
      const int si = nf*16 + l15;
      const int f0 = w*16 + lg*4;
      uint2 xp = *(const uint2*)(big + ((si*128 + f0) ^ swzv));
      f32x4 xv = unpk4(xp);
      #pragma unroll
      for (int c = 0; c < 4; ++c)
        aggS[(nf*4 + c)*256 + tid] += fmaxf(xv[c], 0.0f);
    }
  }

  // final: out = out_agg @ Wout, split-bf16 (hi/lo) for precision
  __syncthreads();   // all agg reads of big done before restaging
  {
    #pragma unroll
    for (int nf = 0; nf < 2; ++nf) {
      const int si = nf*16 + l15;
      const int f0 = w*16 + lg*4;
      float a0 = aggS[(nf*4+0)*256 + tid];
      float a1 = aggS[(nf*4+1)*256 + tid];
      float a2 = aggS[(nf*4+2)*256 + tid];
      float a3 = aggS[(nf*4+3)*256 + tid];
      ushort4 hi, lo;
      u16 h0 = f2bf(a0); hi.x = h0; lo.x = f2bf(a0 - bf2f(h0));
      u16 h1 = f2bf(a1); hi.y = h1; lo.y = f2bf(a1 - bf2f(h1));
      u16 h2v = f2bf(a2); hi.z = h2v; lo.z = f2bf(a2 - bf2f(h2v));
      u16 h3 = f2bf(a3); hi.w = h3; lo.w = f2bf(a3 - bf2f(h3));
      *(ushort4*)(big + ((si*64 + f0) ^ swzv)) = hi;
      *(ushort4*)(big + 2048 + ((si*64 + f0) ^ swzv)) = lo;
    }
  }
  __syncthreads();

  // 64x64x(32 samples) GEMM: wave w -> out m-frag w, both sample n-frags
  {
    const int lane64 = lg*16 + l15;
    f32x4 facc[2];
    facc[0] = splat4(0.0f); facc[1] = splat4(0.0f);
    #pragma unroll
    for (int ks = 0; ks < 2; ++ks) {
      short8 aHi = *(const short8*)(pk + PK_WOUT_US   + (size_t)((w*2 + ks)*64 + lane64)*8);
      short8 aLo = *(const short8*)(pk + PK_WOUTLO_US + (size_t)((w*2 + ks)*64 + lane64)*8);
      #pragma unroll
      for (int j = 0; j < 2; ++j) {
        const int si = j*16 + l15;
        short8 bHi = *(const short8*)(big + ((si*64 + ks*32 + lg*8) ^ swzv));
        short8 bLo = *(const short8*)(big + 2048 + ((si*64 + ks*32 + lg*8) ^ swzv));
        facc[j] = __builtin_amdgcn_mfma_f32_16x16x32_bf16(aHi, bHi, facc[j], 0, 0, 0);
        facc[j] = __builtin_amdgcn_mfma_f32_16x16x32_bf16(aHi, bLo, facc[j], 0, 0, 0);
        facc[j] = __builtin_amdgcn_mfma_f32_16x16x32_bf16(aLo, bHi, facc[j], 0, 0, 0);
      }
    }
    #pragma unroll
    for (int j = 0; j < 2; ++j) {
      const int si = j*16 + l15;
      *(f32x4*)(out + (row0 + si)*64 + w*16 + lg*4) = facc[j];
    }
  }
}

// ---------------- launch ----------------
extern "C" void kernel_launch(void* const* d_in, const int* in_sizes, int n_in,
                              void* d_out, int out_size, void* d_ws, size_t ws_size,
                              hipStream_t stream)
{
  const float* inp   = (const float*)d_in[0];
  const float* in_g  = (const float*)d_in[1];
  const float* in_b  = (const float*)d_in[2];
  const float* in_m  = (const float*)d_in[3];
  const float* in_v  = (const float*)d_in[4];
  const float* sh_W0 = (const float*)d_in[5];
  const float* sh_W1 = (const float*)d_in[6];
  const float* sh_g  = (const float*)d_in[7];
  const float* sh_b  = (const float*)d_in[8];
  const float* sh_m  = (const float*)d_in[9];
  const float* sh_v  = (const float*)d_in[10];
  const float* dep_W = (const float*)d_in[11];
  const float* dep_g = (const float*)d_in[12];
  const float* dep_b = (const float*)d_in[13];
  const float* dep_m = (const float*)d_in[14];
  const float* dep_v = (const float*)d_in[15];
  const float* at_W  = (const float*)d_in[16];
  const float* at_g  = (const float*)d_in[17];
  const float* at_b  = (const float*)d_in[18];
  const float* at_m  = (const float*)d_in[19];
  const float* at_v  = (const float*)d_in[20];
  const float* Wout  = (const float*)d_in[21];

  unsigned char* ws = (unsigned char*)d_ws;
  u16*   pk     = (u16*)ws;
  float* shiftT = (float*)(ws + OFF_SHIFT);
  float* scaleT = (float*)(ws + OFF_SCALE);
  float* inSc   = (float*)(ws + OFF_INSC);
  float* inSh   = (float*)(ws + OFF_INSH);

  hipLaunchKernelGGL(prep_bn, dim3(14), dim3(256), 0, stream,
                     in_g, in_b, in_m, in_v, sh_g, sh_b, sh_m, sh_v,
                     dep_g, dep_b, dep_m, dep_v, at_g, at_b, at_m, at_v,
                     shiftT, scaleT, inSc, inSh);
  hipLaunchKernelGGL(prep_pack, dim3(204), dim3(256), 0, stream,
                     sh_W0, sh_W1, dep_W, at_W, Wout, scaleT, pk);
  hipLaunchKernelGGL(tabnet_main, dim3(4096), dim3(256), 0, stream,
                     inp, pk, shiftT, inSc, inSh, (float*)d_out);
}

// Round 15
// 440.949 us; speedup vs baseline: 2.0044x; 1.0082x over previous
//
#include <hip/hip_runtime.h>
#include <hip/hip_bf16.h>
#include <hip/hip_fp16.h>

typedef unsigned short u16;
typedef __attribute__((ext_vector_type(8))) short short8;
typedef __attribute__((ext_vector_type(4))) float f32x4;
typedef __attribute__((ext_vector_type(4))) int   i32x4;

#define BN_EPS    1e-3f
#define RELAX     1.3f
#define SQRT_HALF 0.7071067811865476f
#define ZSTRIDE   272

// packed-weight offsets (ushort units)
#define PK_G0_US     0
#define PK_G1_US     65536
#define PK_DEP_US    98304
#define PK_AT_US     360448
#define PK_WOUT_US   409600
#define PK_WOUTLO_US 413696
// ws byte offsets
#define OFF_SHIFT 835584
#define OFF_SCALE 848896
#define OFF_INSC  862208
#define OFF_INSH  863232

__device__ __forceinline__ u16 f2bf(float x){
  unsigned u = __float_as_uint(x);
  return (u16)((u + 0x7fffu + ((u >> 16) & 1u)) >> 16);
}
__device__ __forceinline__ float bf2f(u16 h){ return __uint_as_float(((unsigned)h) << 16); }
__device__ __forceinline__ float sigm(float x){ return __builtin_amdgcn_rcpf(1.0f + __expf(-x)); }
__device__ __forceinline__ f32x4 splat4(float x){ f32x4 v; v[0]=x; v[1]=x; v[2]=x; v[3]=x; return v; }

__device__ __forceinline__ unsigned pk2(float a, float b){
  float2 t; t.x = a; t.y = b;
  union { __hip_bfloat162 h; unsigned u; } v;
  v.h = __float22bfloat162_rn(t);
  return v.u;
}
__device__ __forceinline__ f32x4 unpk4(uint2 p){
  f32x4 r;
  r[0] = __uint_as_float(p.x << 16);
  r[1] = __uint_as_float(p.x & 0xffff0000u);
  r[2] = __uint_as_float(p.y << 16);
  r[3] = __uint_as_float(p.y & 0xffff0000u);
  return r;
}
__device__ __forceinline__ f32x4 unpkb4(ushort4 v){
  f32x4 r;
  r[0] = bf2f(v.x); r[1] = bf2f(v.y); r[2] = bf2f(v.z); r[3] = bf2f(v.w);
  return r;
}
__device__ __forceinline__ float2 h2f2(unsigned u){
  union { unsigned u; __half2 h; } v; v.u = u;
  return __half22float2(v.h);
}
__device__ __forceinline__ unsigned f22h2(float a, float b){
  union { __half2 h; unsigned u; } v; v.h = __floats2half2_rn(a, b);
  return v.u;
}

// ---------------- prep: BN scale/shift tables ----------------
__global__ void prep_bn(
  const float* in_g, const float* in_b, const float* in_m, const float* in_v,
  const float* sh_g, const float* sh_b, const float* sh_m, const float* sh_v,
  const float* dep_g, const float* dep_b, const float* dep_m, const float* dep_v,
  const float* at_g, const float* at_b, const float* at_m, const float* at_v,
  float* shiftT, float* scaleT, float* inSc, float* inSh)
{
  int r = blockIdx.x, f = threadIdx.x;
  if (r < 13) {
    const float *g, *bb, *mm, *vv;
    if (r < 2)       { g = sh_g + r*256;        bb = sh_b + r*256;        mm = sh_m + r*256;        vv = sh_v + r*256; }
    else if (r < 10) { int j = r-2;  g = dep_g + j*256; bb = dep_b + j*256; mm = dep_m + j*256; vv = dep_v + j*256; }
    else             { int j = r-10; g = at_g  + j*256; bb = at_b  + j*256; mm = at_m  + j*256; vv = at_v  + j*256; }
    float sc = g[f] * rsqrtf(vv[f] + BN_EPS);
    scaleT[r*256 + f] = sc;
    shiftT[r*256 + f] = bb[f] - mm[f]*sc;
  } else {
    float sc = in_g[f] * rsqrtf(in_v[f] + BN_EPS);
    inSc[f] = sc;
    inSh[f] = in_b[f] - in_m[f]*sc;
  }
}

// ---------------- prep: pack weights into MFMA A-fragment order (BN scale folded) ----------------
__global__ void prep_pack(
  const float* sh_W0, const float* sh_W1, const float* dep_W,
  const float* at_W, const float* Wout, const float* scaleT, u16* pk)
{
  int c = blockIdx.x*256 + threadIdx.x;   // 16B chunk id, 0..52223
  const float* W; int K, Nout, srow, base; bool lo = false;
  if (c < 8192)       { W = sh_W0; K = 256; Nout = 256; srow = 0;  base = 0; }
  else if (c < 12288) { W = sh_W1; K = 128; Nout = 256; srow = 1;  base = 8192; }
  else if (c < 45056) { int j = (c-12288) >> 12; W = dep_W + j*32768; K = 128; Nout = 256; srow = 2+j;  base = 12288 + j*4096; }
  else if (c < 51200) { int j = (c-45056) >> 11; W = at_W  + j*16384; K = 64;  Nout = 256; srow = 10+j; base = 45056 + j*2048; }
  else if (c < 51712) { W = Wout; K = 64; Nout = 64; srow = -1; base = 51200; }
  else                { W = Wout; K = 64; Nout = 64; srow = -1; base = 51712; lo = true; }
  int local = c - base;
  int lane  = local & 63;
  int t     = local >> 6;
  int KS    = K >> 5;
  int lsh   = (K == 256) ? 3 : (K == 128) ? 2 : 1;
  int ks    = t & (KS - 1);
  int mf    = t >> lsh;
  int feat  = mf*16 + (lane & 15);
  int k0    = ks*32 + ((lane >> 4) << 3);
  float scl = (srow < 0) ? 1.0f : scaleT[srow*256 + feat];
  u16 v[8];
  #pragma unroll
  for (int j = 0; j < 8; ++j) {
    float x = W[(size_t)(k0 + j)*Nout + feat] * scl;
    u16 h = f2bf(x);
    if (lo) h = f2bf(x - bf2f(h));
    v[j] = h;
  }
  ushort4* d4 = (ushort4*)(pk + (size_t)c*8);
  ushort4 p0; p0.x=v[0]; p0.y=v[1]; p0.z=v[2]; p0.w=v[3];
  ushort4 p1; p1.x=v[4]; p1.y=v[5]; p1.z=v[6]; p1.w=v[7];
  d4[0] = p0; d4[1] = p1;
}

// ---------------- gemm: 4 m-frags x 2 n-frags, manual even/odd double-buffer ----------------
template<int KS, int LDB, int KOFF>
__device__ __forceinline__ void gemm4(const u16* __restrict__ pk, const u16* bufB,
                                      int w, int l15, int lg, int swzv, f32x4 acc[4][2])
{
  const int lane = lg*16 + l15;
  short8 ae[4], be[2], ao[4], bo[2];
  #pragma unroll
  for (int nf = 0; nf < 2; ++nf) {
    int idx = (nf*16 + l15)*LDB + KOFF + lg*8;
    be[nf] = *(const short8*)(bufB + (idx ^ swzv));
  }
  #pragma unroll
  for (int mi = 0; mi < 4; ++mi)
    ae[mi] = *(const short8*)(pk + (size_t)(((w + 4*mi)*KS)*64 + lane)*8);

  #pragma unroll 1
  for (int ks = 0; ks < KS; ks += 2) {
    #pragma unroll
    for (int nf = 0; nf < 2; ++nf) {
      int idx = (nf*16 + l15)*LDB + KOFF + (ks+1)*32 + lg*8;
      bo[nf] = *(const short8*)(bufB + (idx ^ swzv));
    }
    #pragma unroll
    for (int mi = 0; mi < 4; ++mi)
      ao[mi] = *(const short8*)(pk + (size_t)(((w + 4*mi)*KS + ks + 1)*64 + lane)*8);
    #pragma unroll
    for (int mi = 0; mi < 4; ++mi) {
      acc[mi][0] = __builtin_amdgcn_mfma_f32_16x16x32_bf16(ae[mi], be[0], acc[mi][0], 0, 0, 0);
      acc[mi][1] = __builtin_amdgcn_mfma_f32_16x16x32_bf16(ae[mi], be[1], acc[mi][1], 0, 0, 0);
    }
    if (ks + 2 < KS) {
      #pragma unroll
      for (int nf = 0; nf < 2; ++nf) {
        int idx = (nf*16 + l15)*LDB + KOFF + (ks+2)*32 + lg*8;
        be[nf] = *(const short8*)(bufB + (idx ^ swzv));
      }
      #pragma unroll
      for (int mi = 0; mi < 4; ++mi)
        ae[mi] = *(const short8*)(pk + (size_t)(((w + 4*mi)*KS + ks + 2)*64 + lane)*8);
    }
    #pragma unroll
    for (int mi = 0; mi < 4; ++mi) {
      acc[mi][0] = __builtin_amdgcn_mfma_f32_16x16x32_bf16(ao[mi], bo[0], acc[mi][0], 0, 0, 0);
      acc[mi][1] = __builtin_amdgcn_mfma_f32_16x16x32_bf16(ao[mi], bo[1], acc[mi][1], 0, 0, 0);
    }
  }
}

// init acc with BN bias (C-in of first MFMA)
__device__ __forceinline__ void init4(f32x4 acc[4][2], const float* __restrict__ shrow,
                                      int w, int lg)
{
  #pragma unroll
  for (int mi = 0; mi < 4; ++mi) {
    const f32x4 bv = *(const f32x4*)(shrow + (w + 4*mi)*16 + lg*4);
    acc[mi][0] = bv;
    acc[mi][1] = bv;
  }
}

// GLU epilogue (bias pre-folded into acc): h = v * sigmoid(g)
__device__ __forceinline__ void glu_epi4(const f32x4 acc[4][2], f32x4 h[2][2])
{
  #pragma unroll
  for (int mi = 0; mi < 2; ++mi)
    #pragma unroll
    for (int nf = 0; nf < 2; ++nf)
      #pragma unroll
      for (int c = 0; c < 4; ++c)
        h[mi][nf][c] = acc[mi][nf][c] * sigm(acc[mi+2][nf][c]);
}

// write this wave's 32 features of a 128-wide activation [32][128] bf16 (swizzled)
__device__ __forceinline__ void write_half(u16* dst, const f32x4 v[2][2], int w, int l15, int lg, int swzv)
{
  #pragma unroll
  for (int mi = 0; mi < 2; ++mi) {
    const int f0 = (w + 4*mi)*16 + lg*4;
    #pragma unroll
    for (int nf = 0; nf < 2; ++nf) {
      const int s = nf*16 + l15;
      uint2 p;
      p.x = pk2(v[mi][nf][0], v[mi][nf][1]);
      p.y = pk2(v[mi][nf][2], v[mi][nf][3]);
      *(uint2*)(dst + ((s*128 + f0) ^ swzv)) = p;
    }
  }
}

// shared_block + dep_block. h in hbuf; x ping-pongs between big halves;
// x_final at big[0:4096]. DO_AGG: fuse out_agg += relu(x[:, :64]) into the
// dep-2 epilogue using the in-register f32 x (thread mapping of hd[0][nf][c]
// is identical to the old agg read: feature w*16+lg*4+c, sample nf*16+l15).
template<int DO_AGG>
__device__ __forceinline__ void shared_dep(const u16* __restrict__ pk, const float* __restrict__ shiftT,
                                           const u16* binput, u16* big, u16* hbuf, float* aggS, int inv,
                                           int tid, int w, int l15, int lg, int swzv)
{
  f32x4 acc[4][2];
  init4(acc, shiftT + 0, w, lg);
  gemm4<8, 256, 0>(pk + PK_G0_US, binput, w, l15, lg, swzv, acc);
  {
    f32x4 h[2][2];
    glu_epi4(acc, h);
    write_half(hbuf, h, w, l15, lg, swzv);   // hbuf disjoint from binput
  }
  __syncthreads();                           // B1: h visible; all G0 reads done

  init4(acc, shiftT + 256, w, lg);
  gemm4<4, 128, 0>(pk + PK_G1_US, hbuf, w, l15, lg, swzv, acc);
  {
    f32x4 h2[2][2];
    glu_epi4(acc, h2);
    f32x4 xv[2][2];
    #pragma unroll
    for (int mi = 0; mi < 2; ++mi) {
      const int f0 = (w + 4*mi)*16 + lg*4;
      #pragma unroll
      for (int nf = 0; nf < 2; ++nf) {
        const int s = nf*16 + l15;
        uint2 hp = *(const uint2*)(hbuf + ((s*128 + f0) ^ swzv));
        f32x4 hv = unpk4(hp);
        xv[mi][nf] = (hv + h2[mi][nf]) * SQRT_HALF;
      }
    }
    write_half(big, xv, w, l15, lg, swzv);   // x -> big[0:4096]
  }
  __syncthreads();                           // B2: x visible

  const u16* xin = big;
  u16* xout = big + 4096;
  #pragma unroll
  for (int i = 0; i < 2; ++i) {
    init4(acc, shiftT + (2 + inv*2 + i)*256, w, lg);
    gemm4<4, 128, 0>(pk + PK_DEP_US + (inv*2 + i)*32768, xin, w, l15, lg, swzv, acc);
    f32x4 hd[2][2];
    glu_epi4(acc, hd);
    #pragma unroll
    for (int mi = 0; mi < 2; ++mi) {
      const int f0 = (w + 4*mi)*16 + lg*4;
      #pragma unroll
      for (int nf = 0; nf < 2; ++nf) {
        const int s = nf*16 + l15;
        uint2 xp = *(const uint2*)(xin + ((s*128 + f0) ^ swzv));
        f32x4 xo = unpk4(xp);
        hd[mi][nf] = (xo + hd[mi][nf]) * SQRT_HALF;
      }
    }
    if (DO_AGG && i == 1) {
      const f32x4 zf = splat4(0.0f);
      #pragma unroll
      for (int nf = 0; nf < 2; ++nf) {
        f32x4 r = __builtin_elementwise_max(hd[0][nf], zf);
        #pragma unroll
        for (int c = 0; c < 4; ++c)
          aggS[(nf*4 + c)*256 + tid] += r[c];
      }
    }
    write_half(xout, hd, w, l15, lg, swzv);  // xout disjoint from xin
    __syncthreads();                         // B3/B4: x' visible
    const u16* t = xin; xin = xout; xout = (u16*)t;
  }
  // x_final at big[0:4096]
}

// ---------------- main fused kernel ----------------
// 32 samples/block, 4 waves. LDS 76,288 B -> 2 blocks/CU. 8 waves/CU is the
// hard ceiling at this register footprint (empirical pool = 256 VGPR/EU).
__global__ void __launch_bounds__(256, 2)
tabnet_main(const float* __restrict__ inp, const u16* __restrict__ pk,
            const float* __restrict__ shiftT, const float* __restrict__ inSc,
            const float* __restrict__ inSh, float* __restrict__ out)
{
  __shared__ __align__(16) u16 feat[32*256];     // 16 KB
  __shared__ __align__(16) u16 uni[17408];       // 34,816 B: zbuf f32[32][272] | big(16K)+hbuf(8K)
  __shared__ unsigned priorT[32*132];            // 16,896 B
  __shared__ float    aggS[8*256];               // 8 KB
  u16*   big  = uni;
  u16*   hbuf = uni + 8192;
  float* zbuf = (float*)uni;

  const int tid  = threadIdx.x;
  const int w    = tid >> 6;
  const int lane = tid & 63;
  const int l15  = lane & 15, lg = lane >> 4;
  const int swzv = (l15 & 7) << 3;
  const int a    = lane >> 3;
  const int b    = lane & 7;
  const int s_own = w*8 + a;
  const long long row0 = (long long)blockIdx.x * 32;

  // stage 0: features = BN(inputs) -> feat (bf16, swizzled [sample][256])
  {
    const int f = lane*4;
    const f32x4 sc = *(const f32x4*)(inSc + f);
    const f32x4 sh = *(const f32x4*)(inSh + f);
    #pragma unroll
    for (int j = 0; j < 8; ++j) {
      const int s = j*4 + w;
      f32x4 v = *(const f32x4*)(inp + (row0 + s)*256 + f);
      uint2 p;
      p.x = pk2(v[0]*sc[0] + sh[0], v[1]*sc[1] + sh[1]);
      p.y = pk2(v[2]*sc[2] + sh[2], v[3]*sc[3] + sh[3]);
      *(uint2*)(feat + ((s*256 + f) ^ ((s & 7) << 3))) = p;
    }
  }
  // init prior=1 (own transposed slots), agg=0 (own columns)
  {
    #pragma unroll
    for (int j = 0; j < 8; ++j) {
      const int c = (b ^ a) + 8*j;
      uint2 one; one.x = 0x3c003c00u; one.y = 0x3c003c00u;
      *(uint2*)(priorT + s_own*132 + 2*c) = one;
    }
    #pragma unroll
    for (int j = 0; j < 8; ++j) aggS[j*256 + tid] = 0.0f;
  }
  __syncthreads();

  shared_dep<0>(pk, shiftT, feat, big, hbuf, aggS, 0, tid, w, l15, lg, swzv);

  #pragma unroll 1
  for (int st = 0; st < 3; ++st) {
    // attention: z = a @ at_W[st] + bias (bias via acc init), a = x[:,64:128]
    f32x4 z[4][2];
    init4(z, shiftT + (10 + st)*256, w, lg);
    gemm4<2, 128, 64>(pk + PK_AT_US + st*16384, big, w, l15, lg, swzv, z);
    __syncthreads();   // B_a: all waves done reading big (x) before z-spill clobbers

    // spill z to zbuf f32[32][ZSTRIDE]
    #pragma unroll
    for (int mi = 0; mi < 4; ++mi) {
      const int F0 = (w + 4*mi)*16 + lg*4;
      #pragma unroll
      for (int nf = 0; nf < 2; ++nf) {
        const int s = nf*16 + l15;
        *(f32x4*)(zbuf + s*ZSTRIDE + F0) = z[mi][nf];
      }
    }
    __syncthreads();   // B_t: z visible

    // transposed assemble: zT = z * prior; rowmax via 3 shuffles
    f32x4 zT[8];
    float tau;
    {
      float mx = -1e30f;
      #pragma unroll
      for (int j = 0; j < 8; ++j) {
        const int c = (b ^ a) + 8*j;
        f32x4 zv = *(const f32x4*)(zbuf + s_own*ZSTRIDE + 4*c);
        uint2 pr = *(const uint2*)(priorT + s_own*132 + 2*c);
        float2 p0 = h2f2(pr.x), p1 = h2f2(pr.y);
        f32x4 pv; pv[0] = p0.x; pv[1] = p0.y; pv[2] = p1.x; pv[3] = p1.y;
        zv *= pv;
        zT[j] = zv;
        mx = fmaxf(mx, fmaxf(fmaxf(zv[0], zv[1]), fmaxf(zv[2], zv[3])));
      }
      mx = fmaxf(mx, __shfl_xor(mx, 1, 64));
      mx = fmaxf(mx, __shfl_xor(mx, 2, 64));
      mx = fmaxf(mx, __shfl_xor(mx, 4, 64));
      tau = mx - 1.0f;
    }

    // Newton: wave-local, vectorized scan, per-wave early exit (tol 1e-4)
    const f32x4 zf = splat4(0.0f);
    #pragma unroll 1
    for (int it = 0; it < 10; ++it) {
      f32x4 S4 = zf, C4 = zf;
      const f32x4 tau4 = splat4(tau);
      #pragma unroll
      for (int j = 0; j < 8; ++j) {
        f32x4 d = zT[j] - tau4;
        S4 += __builtin_elementwise_max(d, zf);
        i32x4 cm = d > zf;                       // -1 / 0 per lane-elem
        C4 -= __builtin_convertvector(cm, f32x4); // += 1 where positive
      }
      float S = (S4[0] + S4[1]) + (S4[2] + S4[3]);
      float C = (C4[0] + C4[1]) + (C4[2] + C4[3]);
      S += __shfl_xor(S, 1, 64); C += __shfl_xor(C, 1, 64);
      S += __shfl_xor(S, 2, 64); C += __shfl_xor(C, 2, 64);
      S += __shfl_xor(S, 4, 64); C += __shfl_xor(C, 4, 64);
      if (__all(fabsf(S - 1.0f) < 1e-4f)) break;
      tau += (S - 1.0f) * __builtin_amdgcn_rcpf(C);
    }

    __syncthreads();   // B_m: all waves done reading zbuf before mask overwrites big

    // mask + prior update + masked = mask * features -> big (vectorized)
    {
      const f32x4 tau4 = splat4(tau);
      const f32x4 rel4 = splat4(RELAX);
      #pragma unroll
      for (int j = 0; j < 8; ++j) {
        const int c = (b ^ a) + 8*j;
        f32x4 m4 = __builtin_elementwise_max(zT[j] - tau4, zf);
        uint2 pr = *(const uint2*)(priorT + s_own*132 + 2*c);
        float2 p0 = h2f2(pr.x), p1 = h2f2(pr.y);
        f32x4 pv; pv[0] = p0.x; pv[1] = p0.y; pv[2] = p1.x; pv[3] = p1.y;
        pv *= (rel4 - m4);
        pr.x = f22h2(pv[0], pv[1]);
        pr.y = f22h2(pv[2], pv[3]);
        *(uint2*)(priorT + s_own*132 + 2*c) = pr;
        const int idx = (s_own*256 + 4*c) ^ (a << 3);
        f32x4 fv = unpkb4(*(const ushort4*)(feat + idx));
        fv *= m4;
        uint2 o;
        o.x = pk2(fv[0], fv[1]);
        o.y = pk2(fv[2], fv[3]);
        *(uint2*)(big + idx) = o;
      }
    }
    __syncthreads();   // B_g0: masked visible before G0 reads

    shared_dep<1>(pk, shiftT, big, big, hbuf, aggS, st + 1, tid, w, l15, lg, swzv);
  }

  // final: out = out_agg @ Wout, split-bf16 (hi/lo) for precision.
  // No pre-barrier needed: last B4 already synced and agg is fused (no big reads).
  {
    #pragma unroll
    for (int nf = 0; nf < 2; ++nf) {
      const int si = nf*16 + l15;
      const int f0 = w*16 + lg*4;
      float a0 = aggS[(nf*4+0)*256 + tid];
      float a1 = aggS[(nf*4+1)*256 + tid];
      float a2 = aggS[(nf*4+2)*256 + tid];
      float a3 = aggS[(nf*4+3)*256 + tid];
      ushort4 hi, lo;
      u16 h0 = f2bf(a0); hi.x = h0; lo.x = f2bf(a0 - bf2f(h0));
      u16 h1 = f2bf(a1); hi.y = h1; lo.y = f2bf(a1 - bf2f(h1));
      u16 h2v = f2bf(a2); hi.z = h2v; lo.z = f2bf(a2 - bf2f(h2v));
      u16 h3 = f2bf(a3); hi.w = h3; lo.w = f2bf(a3 - bf2f(h3));
      *(ushort4*)(big + ((si*64 + f0) ^ swzv)) = hi;
      *(ushort4*)(big + 2048 + ((si*64 + f0) ^ swzv)) = lo;
    }
  }
  __syncthreads();

  // 64x64x(32 samples) GEMM: wave w -> out m-frag w, both sample n-frags
  {
    const int lane64 = lg*16 + l15;
    f32x4 facc[2];
    facc[0] = splat4(0.0f); facc[1] = splat4(0.0f);
    #pragma unroll
    for (int ks = 0; ks < 2; ++ks) {
      short8 aHi = *(const short8*)(pk + PK_WOUT_US   + (size_t)((w*2 + ks)*64 + lane64)*8);
      short8 aLo = *(const short8*)(pk + PK_WOUTLO_US + (size_t)((w*2 + ks)*64 + lane64)*8);
      #pragma unroll
      for (int j = 0; j < 2; ++j) {
        const int si = j*16 + l15;
        short8 bHi = *(const short8*)(big + ((si*64 + ks*32 + lg*8) ^ swzv));
        short8 bLo = *(const short8*)(big + 2048 + ((si*64 + ks*32 + lg*8) ^ swzv));
        facc[j] = __builtin_amdgcn_mfma_f32_16x16x32_bf16(aHi, bHi, facc[j], 0, 0, 0);
        facc[j] = __builtin_amdgcn_mfma_f32_16x16x32_bf16(aHi, bLo, facc[j], 0, 0, 0);
        facc[j] = __builtin_amdgcn_mfma_f32_16x16x32_bf16(aLo, bHi, facc[j], 0, 0, 0);
      }
    }
    #pragma unroll
    for (int j = 0; j < 2; ++j) {
      const int si = j*16 + l15;
      *(f32x4*)(out + (row0 + si)*64 + w*16 + lg*4) = facc[j];
    }
  }
}

// ---------------- launch ----------------
extern "C" void kernel_launch(void* const* d_in, const int* in_sizes, int n_in,
                              void* d_out, int out_size, void* d_ws, size_t ws_size,
                              hipStream_t stream)
{
  const float* inp   = (const float*)d_in[0];
  const float* in_g  = (const float*)d_in[1];
  const float* in_b  = (const float*)d_in[2];
  const float* in_m  = (const float*)d_in[3];
  const float* in_v  = (const float*)d_in[4];
  const float* sh_W0 = (const float*)d_in[5];
  const float* sh_W1 = (const float*)d_in[6];
  const float* sh_g  = (const float*)d_in[7];
  const float* sh_b  = (const float*)d_in[8];
  const float* sh_m  = (const float*)d_in[9];
  const float* sh_v  = (const float*)d_in[10];
  const float* dep_W = (const float*)d_in[11];
  const float* dep_g = (const float*)d_in[12];
  const float* dep_b = (const float*)d_in[13];
  const float* dep_m = (const float*)d_in[14];
  const float* dep_v = (const float*)d_in[15];
  const float* at_W  = (const float*)d_in[16];
  const float* at_g  = (const float*)d_in[17];
  const float* at_b  = (const float*)d_in[18];
  const float* at_m  = (const float*)d_in[19];
  const float* at_v  = (const float*)d_in[20];
  const float* Wout  = (const float*)d_in[21];

  unsigned char* ws = (unsigned char*)d_ws;
  u16*   pk     = (u16*)ws;
  float* shiftT = (float*)(ws + OFF_SHIFT);
  float* scaleT = (float*)(ws + OFF_SCALE);
  float* inSc   = (float*)(ws + OFF_INSC);
  float* inSh   = (float*)(ws + OFF_INSH);

  hipLaunchKernelGGL(prep_bn, dim3(14), dim3(256), 0, stream,
                     in_g, in_b, in_m, in_v, sh_g, sh_b, sh_m, sh_v,
                     dep_g, dep_b, dep_m, dep_v, at_g, at_b, at_m, at_v,
                     shiftT, scaleT, inSc, inSh);
  hipLaunchKernelGGL(prep_pack, dim3(204), dim3(256), 0, stream,
                     sh_W0, sh_W1, dep_W, at_W, Wout, scaleT, pk);
  hipLaunchKernelGGL(tabnet_main, dim3(4096), dim3(256), 0, stream,
                     inp, pk, shiftT, inSc, inSh, (float*)d_out);
}

// Round 16
// 432.792 us; speedup vs baseline: 2.0422x; 1.0188x over previous
//
#include <hip/hip_runtime.h>
#include <hip/hip_bf16.h>
#include <hip/hip_fp16.h>

typedef unsigned short u16;
typedef __attribute__((ext_vector_type(8))) short short8;
typedef __attribute__((ext_vector_type(4))) float f32x4;
typedef __attribute__((ext_vector_type(4))) int   i32x4;

#define BN_EPS    1e-3f
#define RELAX     1.3f
#define SQRT_HALF 0.7071067811865476f
#define ZSTRIDE   272

// packed-weight offsets (ushort units)
#define PK_G0_US     0
#define PK_G1_US     65536
#define PK_DEP_US    98304
#define PK_AT_US     360448
#define PK_WOUT_US   409600
#define PK_WOUTLO_US 413696
// ws byte offsets
#define OFF_SHIFT 835584
#define OFF_SCALE 848896
#define OFF_INSC  862208
#define OFF_INSH  863232

__device__ __forceinline__ u16 f2bf(float x){
  unsigned u = __float_as_uint(x);
  return (u16)((u + 0x7fffu + ((u >> 16) & 1u)) >> 16);
}
__device__ __forceinline__ float bf2f(u16 h){ return __uint_as_float(((unsigned)h) << 16); }
__device__ __forceinline__ float sigm(float x){ return __builtin_amdgcn_rcpf(1.0f + __expf(-x)); }
__device__ __forceinline__ f32x4 splat4(float x){ f32x4 v; v[0]=x; v[1]=x; v[2]=x; v[3]=x; return v; }

__device__ __forceinline__ unsigned pk2(float a, float b){
  float2 t; t.x = a; t.y = b;
  union { __hip_bfloat162 h; unsigned u; } v;
  v.h = __float22bfloat162_rn(t);
  return v.u;
}
__device__ __forceinline__ f32x4 unpk4(uint2 p){
  f32x4 r;
  r[0] = __uint_as_float(p.x << 16);
  r[1] = __uint_as_float(p.x & 0xffff0000u);
  r[2] = __uint_as_float(p.y << 16);
  r[3] = __uint_as_float(p.y & 0xffff0000u);
  return r;
}
__device__ __forceinline__ f32x4 unpkb4(ushort4 v){
  f32x4 r;
  r[0] = bf2f(v.x); r[1] = bf2f(v.y); r[2] = bf2f(v.z); r[3] = bf2f(v.w);
  return r;
}
__device__ __forceinline__ float2 h2f2(unsigned u){
  union { unsigned u; __half2 h; } v; v.u = u;
  return __half22float2(v.h);
}
__device__ __forceinline__ unsigned f22h2(float a, float b){
  union { __half2 h; unsigned u; } v; v.h = __floats2half2_rn(a, b);
  return v.u;
}

// ---------------- prep: BN scale/shift tables ----------------
__global__ void prep_bn(
  const float* in_g, const float* in_b, const float* in_m, const float* in_v,
  const float* sh_g, const float* sh_b, const float* sh_m, const float* sh_v,
  const float* dep_g, const float* dep_b, const float* dep_m, const float* dep_v,
  const float* at_g, const float* at_b, const float* at_m, const float* at_v,
  float* shiftT, float* scaleT, float* inSc, float* inSh)
{
  int r = blockIdx.x, f = threadIdx.x;
  if (r < 13) {
    const float *g, *bb, *mm, *vv;
    if (r < 2)       { g = sh_g + r*256;        bb = sh_b + r*256;        mm = sh_m + r*256;        vv = sh_v + r*256; }
    else if (r < 10) { int j = r-2;  g = dep_g + j*256; bb = dep_b + j*256; mm = dep_m + j*256; vv = dep_v + j*256; }
    else             { int j = r-10; g = at_g  + j*256; bb = at_b  + j*256; mm = at_m  + j*256; vv = at_v  + j*256; }
    float sc = g[f] * rsqrtf(vv[f] + BN_EPS);
    scaleT[r*256 + f] = sc;
    shiftT[r*256 + f] = bb[f] - mm[f]*sc;
  } else {
    float sc = in_g[f] * rsqrtf(in_v[f] + BN_EPS);
    inSc[f] = sc;
    inSh[f] = in_b[f] - in_m[f]*sc;
  }
}

// ---------------- prep: pack weights into MFMA A-fragment order (BN scale folded) ----------------
__global__ void prep_pack(
  const float* sh_W0, const float* sh_W1, const float* dep_W,
  const float* at_W, const float* Wout, const float* scaleT, u16* pk)
{
  int c = blockIdx.x*256 + threadIdx.x;   // 16B chunk id, 0..52223
  const float* W; int K, Nout, srow, base; bool lo = false;
  if (c < 8192)       { W = sh_W0; K = 256; Nout = 256; srow = 0;  base = 0; }
  else if (c < 12288) { W = sh_W1; K = 128; Nout = 256; srow = 1;  base = 8192; }
  else if (c < 45056) { int j = (c-12288) >> 12; W = dep_W + j*32768; K = 128; Nout = 256; srow = 2+j;  base = 12288 + j*4096; }
  else if (c < 51200) { int j = (c-45056) >> 11; W = at_W  + j*16384; K = 64;  Nout = 256; srow = 10+j; base = 45056 + j*2048; }
  else if (c < 51712) { W = Wout; K = 64; Nout = 64; srow = -1; base = 51200; }
  else                { W = Wout; K = 64; Nout = 64; srow = -1; base = 51712; lo = true; }
  int local = c - base;
  int lane  = local & 63;
  int t     = local >> 6;
  int KS    = K >> 5;
  int lsh   = (K == 256) ? 3 : (K == 128) ? 2 : 1;
  int ks    = t & (KS - 1);
  int mf    = t >> lsh;
  int feat  = mf*16 + (lane & 15);
  int k0    = ks*32 + ((lane >> 4) << 3);
  float scl = (srow < 0) ? 1.0f : scaleT[srow*256 + feat];
  u16 v[8];
  #pragma unroll
  for (int j = 0; j < 8; ++j) {
    float x = W[(size_t)(k0 + j)*Nout + feat] * scl;
    u16 h = f2bf(x);
    if (lo) h = f2bf(x - bf2f(h));
    v[j] = h;
  }
  ushort4* d4 = (ushort4*)(pk + (size_t)c*8);
  ushort4 p0; p0.x=v[0]; p0.y=v[1]; p0.z=v[2]; p0.w=v[3];
  ushort4 p1; p1.x=v[4]; p1.y=v[5]; p1.z=v[6]; p1.w=v[7];
  d4[0] = p0; d4[1] = p1;
}

// prefetch first A-tile (4 x 16B global loads) of a gemm; caller holds regs across barrier
template<int KS>
__device__ __forceinline__ void prefA(const u16* __restrict__ pk, int w, int lane, short8 ae[4]){
  #pragma unroll
  for (int mi = 0; mi < 4; ++mi)
    ae[mi] = *(const short8*)(pk + (size_t)(((w + 4*mi)*KS)*64 + lane)*8);
}

// ---------------- gemm: 4 m-frags x 2 n-frags, even/odd double-buffer ----------------
// PRE: first A-tile was prefetched (issued before the preceding barrier).
template<int KS, int LDB, int KOFF, bool PRE>
__device__ __forceinline__ void gemm4(const u16* __restrict__ pk, const u16* bufB,
                                      const short8* aePre,
                                      int w, int l15, int lg, int swzv, f32x4 acc[4][2])
{
  const int lane = lg*16 + l15;
  short8 ae[4], be[2], ao[4], bo[2];
  #pragma unroll
  for (int nf = 0; nf < 2; ++nf) {
    int idx = (nf*16 + l15)*LDB + KOFF + lg*8;
    be[nf] = *(const short8*)(bufB + (idx ^ swzv));
  }
  #pragma unroll
  for (int mi = 0; mi < 4; ++mi) {
    if (PRE) ae[mi] = aePre[mi];
    else     ae[mi] = *(const short8*)(pk + (size_t)(((w + 4*mi)*KS)*64 + lane)*8);
  }

  #pragma unroll 1
  for (int ks = 0; ks < KS; ks += 2) {
    #pragma unroll
    for (int nf = 0; nf < 2; ++nf) {
      int idx = (nf*16 + l15)*LDB + KOFF + (ks+1)*32 + lg*8;
      bo[nf] = *(const short8*)(bufB + (idx ^ swzv));
    }
    #pragma unroll
    for (int mi = 0; mi < 4; ++mi)
      ao[mi] = *(const short8*)(pk + (size_t)(((w + 4*mi)*KS + ks + 1)*64 + lane)*8);
    #pragma unroll
    for (int mi = 0; mi < 4; ++mi) {
      acc[mi][0] = __builtin_amdgcn_mfma_f32_16x16x32_bf16(ae[mi], be[0], acc[mi][0], 0, 0, 0);
      acc[mi][1] = __builtin_amdgcn_mfma_f32_16x16x32_bf16(ae[mi], be[1], acc[mi][1], 0, 0, 0);
    }
    if (ks + 2 < KS) {
      #pragma unroll
      for (int nf = 0; nf < 2; ++nf) {
        int idx = (nf*16 + l15)*LDB + KOFF + (ks+2)*32 + lg*8;
        be[nf] = *(const short8*)(bufB + (idx ^ swzv));
      }
      #pragma unroll
      for (int mi = 0; mi < 4; ++mi)
        ae[mi] = *(const short8*)(pk + (size_t)(((w + 4*mi)*KS + ks + 2)*64 + lane)*8);
    }
    #pragma unroll
    for (int mi = 0; mi < 4; ++mi) {
      acc[mi][0] = __builtin_amdgcn_mfma_f32_16x16x32_bf16(ao[mi], bo[0], acc[mi][0], 0, 0, 0);
      acc[mi][1] = __builtin_amdgcn_mfma_f32_16x16x32_bf16(ao[mi], bo[1], acc[mi][1], 0, 0, 0);
    }
  }
}

// init acc with BN bias (C-in of first MFMA)
__device__ __forceinline__ void init4(f32x4 acc[4][2], const float* __restrict__ shrow,
                                      int w, int lg)
{
  #pragma unroll
  for (int mi = 0; mi < 4; ++mi) {
    const f32x4 bv = *(const f32x4*)(shrow + (w + 4*mi)*16 + lg*4);
    acc[mi][0] = bv;
    acc[mi][1] = bv;
  }
}

// GLU epilogue (bias pre-folded into acc): h = v * sigmoid(g)
__device__ __forceinline__ void glu_epi4(const f32x4 acc[4][2], f32x4 h[2][2])
{
  #pragma unroll
  for (int mi = 0; mi < 2; ++mi)
    #pragma unroll
    for (int nf = 0; nf < 2; ++nf)
      #pragma unroll
      for (int c = 0; c < 4; ++c)
        h[mi][nf][c] = acc[mi][nf][c] * sigm(acc[mi+2][nf][c]);
}

// write this wave's 32 features of a 128-wide activation [32][128] bf16 (swizzled)
__device__ __forceinline__ void write_half(u16* dst, const f32x4 v[2][2], int w, int l15, int lg, int swzv)
{
  #pragma unroll
  for (int mi = 0; mi < 2; ++mi) {
    const int f0 = (w + 4*mi)*16 + lg*4;
    #pragma unroll
    for (int nf = 0; nf < 2; ++nf) {
      const int s = nf*16 + l15;
      uint2 p;
      p.x = pk2(v[mi][nf][0], v[mi][nf][1]);
      p.y = pk2(v[mi][nf][2], v[mi][nf][3]);
      *(uint2*)(dst + ((s*128 + f0) ^ swzv)) = p;
    }
  }
}

// shared_block + dep_block with A-tile prefetch across every internal barrier.
// h in hbuf; x ping-pongs between big halves; x_final at big[0:4096].
template<int DO_AGG>
__device__ __forceinline__ void shared_dep(const u16* __restrict__ pk, const float* __restrict__ shiftT,
                                           const u16* binput, u16* big, u16* hbuf, float* aggS,
                                           const short8 aeG0[4], int inv,
                                           int tid, int w, int lane, int l15, int lg, int swzv)
{
  f32x4 acc[4][2];
  init4(acc, shiftT + 0, w, lg);
  gemm4<8, 256, 0, true>(pk + PK_G0_US, binput, aeG0, w, l15, lg, swzv, acc);
  short8 aeN[4];
  prefA<4>(pk + PK_G1_US, w, lane, aeN);     // G1 A-tile issued before B1
  {
    f32x4 h[2][2];
    glu_epi4(acc, h);
    write_half(hbuf, h, w, l15, lg, swzv);   // hbuf disjoint from binput
  }
  __syncthreads();                           // B1: h visible; all G0 reads done

  init4(acc, shiftT + 256, w, lg);
  gemm4<4, 128, 0, true>(pk + PK_G1_US, hbuf, aeN, w, l15, lg, swzv, acc);
  prefA<4>(pk + PK_DEP_US + (inv*2 + 0)*32768, w, lane, aeN);  // dep0 A before B2
  {
    f32x4 h2[2][2];
    glu_epi4(acc, h2);
    f32x4 xv[2][2];
    #pragma unroll
    for (int mi = 0; mi < 2; ++mi) {
      const int f0 = (w + 4*mi)*16 + lg*4;
      #pragma unroll
      for (int nf = 0; nf < 2; ++nf) {
        const int s = nf*16 + l15;
        uint2 hp = *(const uint2*)(hbuf + ((s*128 + f0) ^ swzv));
        f32x4 hv = unpk4(hp);
        xv[mi][nf] = (hv + h2[mi][nf]) * SQRT_HALF;
      }
    }
    write_half(big, xv, w, l15, lg, swzv);   // x -> big[0:4096]
  }
  __syncthreads();                           // B2: x visible

  const u16* xin = big;
  u16* xout = big + 4096;
  #pragma unroll
  for (int i = 0; i < 2; ++i) {
    init4(acc, shiftT + (2 + inv*2 + i)*256, w, lg);
    gemm4<4, 128, 0, true>(pk + PK_DEP_US + (inv*2 + i)*32768, xin, aeN, w, l15, lg, swzv, acc);
    if (i == 0)
      prefA<4>(pk + PK_DEP_US + (inv*2 + 1)*32768, w, lane, aeN);  // dep1 A before B3
    f32x4 hd[2][2];
    glu_epi4(acc, hd);
    #pragma unroll
    for (int mi = 0; mi < 2; ++mi) {
      const int f0 = (w + 4*mi)*16 + lg*4;
      #pragma unroll
      for (int nf = 0; nf < 2; ++nf) {
        const int s = nf*16 + l15;
        uint2 xp = *(const uint2*)(xin + ((s*128 + f0) ^ swzv));
        f32x4 xo = unpk4(xp);
        hd[mi][nf] = (xo + hd[mi][nf]) * SQRT_HALF;
      }
    }
    if (DO_AGG && i == 1) {
      const f32x4 zf = splat4(0.0f);
      #pragma unroll
      for (int nf = 0; nf < 2; ++nf) {
        f32x4 r = __builtin_elementwise_max(hd[0][nf], zf);
        #pragma unroll
        for (int c = 0; c < 4; ++c)
          aggS[(nf*4 + c)*256 + tid] += r[c];
      }
    }
    write_half(xout, hd, w, l15, lg, swzv);  // xout disjoint from xin
    __syncthreads();                         // B3/B4: x' visible
    const u16* t = xin; xin = xout; xout = (u16*)t;
  }
  // x_final at big[0:4096]
}

// ---------------- main fused kernel ----------------
// 32 samples/block, 4 waves. LDS 76,288 B -> 2 blocks/CU (8 waves = hard cap at
// this register footprint). A-tile prefetch hides gemm-prologue L2 latency.
__global__ void __launch_bounds__(256, 2)
tabnet_main(const float* __restrict__ inp, const u16* __restrict__ pk,
            const float* __restrict__ shiftT, const float* __restrict__ inSc,
            const float* __restrict__ inSh, float* __restrict__ out)
{
  __shared__ __align__(16) u16 feat[32*256];     // 16 KB
  __shared__ __align__(16) u16 uni[17408];       // 34,816 B: zbuf f32[32][272] | big(16K)+hbuf(8K)
  __shared__ unsigned priorT[32*132];            // 16,896 B
  __shared__ float    aggS[8*256];               // 8 KB
  u16*   big  = uni;
  u16*   hbuf = uni + 8192;
  float* zbuf = (float*)uni;

  const int tid  = threadIdx.x;
  const int w    = tid >> 6;
  const int lane = tid & 63;
  const int l15  = lane & 15, lg = lane >> 4;
  const int swzv = (l15 & 7) << 3;
  const int a    = lane >> 3;
  const int b    = lane & 7;
  const int s_own = w*8 + a;
  const long long row0 = (long long)blockIdx.x * 32;

  // stage 0: features = BN(inputs) -> feat (bf16, swizzled [sample][256])
  {
    const int f = lane*4;
    const f32x4 sc = *(const f32x4*)(inSc + f);
    const f32x4 sh = *(const f32x4*)(inSh + f);
    #pragma unroll
    for (int j = 0; j < 8; ++j) {
      const int s = j*4 + w;
      f32x4 v = *(const f32x4*)(inp + (row0 + s)*256 + f);
      uint2 p;
      p.x = pk2(v[0]*sc[0] + sh[0], v[1]*sc[1] + sh[1]);
      p.y = pk2(v[2]*sc[2] + sh[2], v[3]*sc[3] + sh[3]);
      *(uint2*)(feat + ((s*256 + f) ^ ((s & 7) << 3))) = p;
    }
  }
  // init prior=1 (own transposed slots), agg=0 (own columns)
  {
    #pragma unroll
    for (int j = 0; j < 8; ++j) {
      const int c = (b ^ a) + 8*j;
      uint2 one; one.x = 0x3c003c00u; one.y = 0x3c003c00u;
      *(uint2*)(priorT + s_own*132 + 2*c) = one;
    }
    #pragma unroll
    for (int j = 0; j < 8; ++j) aggS[j*256 + tid] = 0.0f;
  }
  short8 aeG0[4];
  prefA<8>(pk + PK_G0_US, w, lane, aeG0);   // G0 A-tile before the staging barrier
  __syncthreads();

  shared_dep<0>(pk, shiftT, feat, big, hbuf, aggS, aeG0, 0, tid, w, lane, l15, lg, swzv);

  #pragma unroll 1
  for (int st = 0; st < 3; ++st) {
    // attention: z = a @ at_W[st] + bias (bias via acc init), a = x[:,64:128]
    f32x4 z[4][2];
    init4(z, shiftT + (10 + st)*256, w, lg);
    gemm4<2, 128, 64, false>(pk + PK_AT_US + st*16384, big, nullptr, w, l15, lg, swzv, z);
    __syncthreads();   // B_a: all waves done reading big (x) before z-spill clobbers

    // spill z to zbuf f32[32][ZSTRIDE]
    #pragma unroll
    for (int mi = 0; mi < 4; ++mi) {
      const int F0 = (w + 4*mi)*16 + lg*4;
      #pragma unroll
      for (int nf = 0; nf < 2; ++nf) {
        const int s = nf*16 + l15;
        *(f32x4*)(zbuf + s*ZSTRIDE + F0) = z[mi][nf];
      }
    }
    __syncthreads();   // B_t: z visible

    // transposed assemble: zT = z * prior; rowmax via 3 shuffles
    f32x4 zT[8];
    float tau;
    {
      float mx = -1e30f;
      #pragma unroll
      for (int j = 0; j < 8; ++j) {
        const int c = (b ^ a) + 8*j;
        f32x4 zv = *(const f32x4*)(zbuf + s_own*ZSTRIDE + 4*c);
        uint2 pr = *(const uint2*)(priorT + s_own*132 + 2*c);
        float2 p0 = h2f2(pr.x), p1 = h2f2(pr.y);
        f32x4 pv; pv[0] = p0.x; pv[1] = p0.y; pv[2] = p1.x; pv[3] = p1.y;
        zv *= pv;
        zT[j] = zv;
        mx = fmaxf(mx, fmaxf(fmaxf(zv[0], zv[1]), fmaxf(zv[2], zv[3])));
      }
      mx = fmaxf(mx, __shfl_xor(mx, 1, 64));
      mx = fmaxf(mx, __shfl_xor(mx, 2, 64));
      mx = fmaxf(mx, __shfl_xor(mx, 4, 64));
      tau = mx - 1.0f;
    }

    // Newton: wave-local, vectorized scan, per-wave early exit (tol 1e-4)
    const f32x4 zf = splat4(0.0f);
    #pragma unroll 1
    for (int it = 0; it < 10; ++it) {
      f32x4 S4 = zf, C4 = zf;
      const f32x4 tau4 = splat4(tau);
      #pragma unroll
      for (int j = 0; j < 8; ++j) {
        f32x4 d = zT[j] - tau4;
        S4 += __builtin_elementwise_max(d, zf);
        i32x4 cm = d > zf;
        C4 -= __builtin_convertvector(cm, f32x4);
      }
      float S = (S4[0] + S4[1]) + (S4[2] + S4[3]);
      float C = (C4[0] + C4[1]) + (C4[2] + C4[3]);
      S += __shfl_xor(S, 1, 64); C += __shfl_xor(C, 1, 64);
      S += __shfl_xor(S, 2, 64); C += __shfl_xor(C, 2, 64);
      S += __shfl_xor(S, 4, 64); C += __shfl_xor(C, 4, 64);
      if (__all(fabsf(S - 1.0f) < 1e-4f)) break;
      tau += (S - 1.0f) * __builtin_amdgcn_rcpf(C);
    }

    __syncthreads();   // B_m: all waves done reading zbuf before mask overwrites big

    // mask + prior update + masked = mask * features -> big (vectorized)
    {
      const f32x4 tau4 = splat4(tau);
      const f32x4 rel4 = splat4(RELAX);
      #pragma unroll
      for (int j = 0; j < 8; ++j) {
        const int c = (b ^ a) + 8*j;
        f32x4 m4 = __builtin_elementwise_max(zT[j] - tau4, zf);
        uint2 pr = *(const uint2*)(priorT + s_own*132 + 2*c);
        float2 p0 = h2f2(pr.x), p1 = h2f2(pr.y);
        f32x4 pv; pv[0] = p0.x; pv[1] = p0.y; pv[2] = p1.x; pv[3] = p1.y;
        pv *= (rel4 - m4);
        pr.x = f22h2(pv[0], pv[1]);
        pr.y = f22h2(pv[2], pv[3]);
        *(uint2*)(priorT + s_own*132 + 2*c) = pr;
        const int idx = (s_own*256 + 4*c) ^ (a << 3);
        f32x4 fv = unpkb4(*(const ushort4*)(feat + idx));
        fv *= m4;
        uint2 o;
        o.x = pk2(fv[0], fv[1]);
        o.y = pk2(fv[2], fv[3]);
        *(uint2*)(big + idx) = o;
      }
    }
    prefA<8>(pk + PK_G0_US, w, lane, aeG0);  // next G0 A-tile before B_g0
    __syncthreads();   // B_g0: masked visible before G0 reads

    shared_dep<1>(pk, shiftT, big, big, hbuf, aggS, aeG0, st + 1, tid, w, lane, l15, lg, swzv);
  }

  // final: out = out_agg @ Wout, split-bf16 (hi/lo) for precision.
  {
    #pragma unroll
    for (int nf = 0; nf < 2; ++nf) {
      const int si = nf*16 + l15;
      const int f0 = w*16 + lg*4;
      float a0 = aggS[(nf*4+0)*256 + tid];
      float a1 = aggS[(nf*4+1)*256 + tid];
      float a2 = aggS[(nf*4+2)*256 + tid];
      float a3 = aggS[(nf*4+3)*256 + tid];
      ushort4 hi, lo;
      u16 h0 = f2bf(a0); hi.x = h0; lo.x = f2bf(a0 - bf2f(h0));
      u16 h1 = f2bf(a1); hi.y = h1; lo.y = f2bf(a1 - bf2f(h1));
      u16 h2v = f2bf(a2); hi.z = h2v; lo.z = f2bf(a2 - bf2f(h2v));
      u16 h3 = f2bf(a3); hi.w = h3; lo.w = f2bf(a3 - bf2f(h3));
      *(ushort4*)(big + ((si*64 + f0) ^ swzv)) = hi;
      *(ushort4*)(big + 2048 + ((si*64 + f0) ^ swzv)) = lo;
    }
  }
  __syncthreads();

  // 64x64x(32 samples) GEMM: wave w -> out m-frag w, both sample n-frags
  {
    const int lane64 = lg*16 + l15;
    f32x4 facc[2];
    facc[0] = splat4(0.0f); facc[1] = splat4(0.0f);
    #pragma unroll
    for (int ks = 0; ks < 2; ++ks) {
      short8 aHi = *(const short8*)(pk + PK_WOUT_US   + (size_t)((w*2 + ks)*64 + lane64)*8);
      short8 aLo = *(const short8*)(pk + PK_WOUTLO_US + (size_t)((w*2 + ks)*64 + lane64)*8);
      #pragma unroll
      for (int j = 0; j < 2; ++j) {
        const int si = j*16 + l15;
        short8 bHi = *(const short8*)(big + ((si*64 + ks*32 + lg*8) ^ swzv));
        short8 bLo = *(const short8*)(big + 2048 + ((si*64 + ks*32 + lg*8) ^ swzv));
        facc[j] = __builtin_amdgcn_mfma_f32_16x16x32_bf16(aHi, bHi, facc[j], 0, 0, 0);
        facc[j] = __builtin_amdgcn_mfma_f32_16x16x32_bf16(aHi, bLo, facc[j], 0, 0, 0);
        facc[j] = __builtin_amdgcn_mfma_f32_16x16x32_bf16(aLo, bHi, facc[j], 0, 0, 0);
      }
    }
    #pragma unroll
    for (int j = 0; j < 2; ++j) {
      const int si = j*16 + l15;
      *(f32x4*)(out + (row0 + si)*64 + w*16 + lg*4) = facc[j];
    }
  }
}

// ---------------- launch ----------------
extern "C" void kernel_launch(void* const* d_in, const int* in_sizes, int n_in,
                              void* d_out, int out_size, void* d_ws, size_t ws_size,
                              hipStream_t stream)
{
  const float* inp   = (const float*)d_in[0];
  const float* in_g  = (const float*)d_in[1];
  const float* in_b  = (const float*)d_in[2];
  const float* in_m  = (const float*)d_in[3];
  const float* in_v  = (const float*)d_in[4];
  const float* sh_W0 = (const float*)d_in[5];
  const float* sh_W1 = (const float*)d_in[6];
  const float* sh_g  = (const float*)d_in[7];
  const float* sh_b  = (const float*)d_in[8];
  const float* sh_m  = (const float*)d_in[9];
  const float* sh_v  = (const float*)d_in[10];
  const float* dep_W = (const float*)d_in[11];
  const float* dep_g = (const float*)d_in[12];
  const float* dep_b = (const float*)d_in[13];
  const float* dep_m = (const float*)d_in[14];
  const float* dep_v = (const float*)d_in[15];
  const float* at_W  = (const float*)d_in[16];
  const float* at_g  = (const float*)d_in[17];
  const float* at_b  = (const float*)d_in[18];
  const float* at_m  = (const float*)d_in[19];
  const float* at_v  = (const float*)d_in[20];
  const float* Wout  = (const float*)d_in[21];

  unsigned char* ws = (unsigned char*)d_ws;
  u16*   pk     = (u16*)ws;
  float* shiftT = (float*)(ws + OFF_SHIFT);
  float* scaleT = (float*)(ws + OFF_SCALE);
  float* inSc   = (float*)(ws + OFF_INSC);
  float* inSh   = (float*)(ws + OFF_INSH);

  hipLaunchKernelGGL(prep_bn, dim3(14), dim3(256), 0, stream,
                     in_g, in_b, in_m, in_v, sh_g, sh_b, sh_m, sh_v,
                     dep_g, dep_b, dep_m, dep_v, at_g, at_b, at_m, at_v,
                     shiftT, scaleT, inSc, inSh);
  hipLaunchKernelGGL(prep_pack, dim3(204), dim3(256), 0, stream,
                     sh_W0, sh_W1, dep_W, at_W, Wout, scaleT, pk);
  hipLaunchKernelGGL(tabnet_main, dim3(4096), dim3(256), 0, stream,
                     inp, pk, shiftT, inSc, inSh, (float*)d_out);
}

// Round 17
// 431.557 us; speedup vs baseline: 2.0480x; 1.0029x over previous
//
#include <hip/hip_runtime.h>
#include <hip/hip_bf16.h>
#include <hip/hip_fp16.h>

typedef unsigned short u16;
typedef __attribute__((ext_vector_type(8))) short short8;
typedef __attribute__((ext_vector_type(4))) float f32x4;
typedef __attribute__((ext_vector_type(4))) int   i32x4;

#define BN_EPS    1e-3f
#define RELAX     1.3f
#define SQRT_HALF 0.7071067811865476f
#define ZSTRIDE   272

// packed-weight offsets (ushort units)
#define PK_G0_US     0
#define PK_G1_US     65536
#define PK_DEP_US    98304
#define PK_AT_US     360448
#define PK_WOUT_US   409600
#define PK_WOUTLO_US 413696
// ws byte offsets
#define OFF_SHIFT 835584
#define OFF_SCALE 848896
#define OFF_INSC  862208
#define OFF_INSH  863232

__device__ __forceinline__ u16 f2bf(float x){
  unsigned u = __float_as_uint(x);
  return (u16)((u + 0x7fffu + ((u >> 16) & 1u)) >> 16);
}
__device__ __forceinline__ float bf2f(u16 h){ return __uint_as_float(((unsigned)h) << 16); }
__device__ __forceinline__ float sigm(float x){ return __builtin_amdgcn_rcpf(1.0f + __expf(-x)); }
__device__ __forceinline__ f32x4 splat4(float x){ f32x4 v; v[0]=x; v[1]=x; v[2]=x; v[3]=x; return v; }

__device__ __forceinline__ unsigned pk2(float a, float b){
  float2 t; t.x = a; t.y = b;
  union { __hip_bfloat162 h; unsigned u; } v;
  v.h = __float22bfloat162_rn(t);
  return v.u;
}
__device__ __forceinline__ f32x4 unpk4(uint2 p){
  f32x4 r;
  r[0] = __uint_as_float(p.x << 16);
  r[1] = __uint_as_float(p.x & 0xffff0000u);
  r[2] = __uint_as_float(p.y << 16);
  r[3] = __uint_as_float(p.y & 0xffff0000u);
  return r;
}
__device__ __forceinline__ f32x4 unpkb4(ushort4 v){
  f32x4 r;
  r[0] = bf2f(v.x); r[1] = bf2f(v.y); r[2] = bf2f(v.z); r[3] = bf2f(v.w);
  return r;
}
__device__ __forceinline__ float2 h2f2(unsigned u){
  union { unsigned u; __half2 h; } v; v.u = u;
  return __half22float2(v.h);
}
__device__ __forceinline__ unsigned f22h2(float a, float b){
  union { __half2 h; unsigned u; } v; v.h = __floats2half2_rn(a, b);
  return v.u;
}

// ---------------- prep: BN scale/shift tables ----------------
__global__ void prep_bn(
  const float* in_g, const float* in_b, const float* in_m, const float* in_v,
  const float* sh_g, const float* sh_b, const float* sh_m, const float* sh_v,
  const float* dep_g, const float* dep_b, const float* dep_m, const float* dep_v,
  const float* at_g, const float* at_b, const float* at_m, const float* at_v,
  float* shiftT, float* scaleT, float* inSc, float* inSh)
{
  int r = blockIdx.x, f = threadIdx.x;
  if (r < 13) {
    const float *g, *bb, *mm, *vv;
    if (r < 2)       { g = sh_g + r*256;        bb = sh_b + r*256;        mm = sh_m + r*256;        vv = sh_v + r*256; }
    else if (r < 10) { int j = r-2;  g = dep_g + j*256; bb = dep_b + j*256; mm = dep_m + j*256; vv = dep_v + j*256; }
    else             { int j = r-10; g = at_g  + j*256; bb = at_b  + j*256; mm = at_m  + j*256; vv = at_v  + j*256; }
    float sc = g[f] * rsqrtf(vv[f] + BN_EPS);
    scaleT[r*256 + f] = sc;
    shiftT[r*256 + f] = bb[f] - mm[f]*sc;
  } else {
    float sc = in_g[f] * rsqrtf(in_v[f] + BN_EPS);
    inSc[f] = sc;
    inSh[f] = in_b[f] - in_m[f]*sc;
  }
}

// ---------------- prep: pack weights into MFMA A-fragment order (BN scale folded) ----------------
__global__ void prep_pack(
  const float* sh_W0, const float* sh_W1, const float* dep_W,
  const float* at_W, const float* Wout, const float* scaleT, u16* pk)
{
  int c = blockIdx.x*256 + threadIdx.x;   // 16B chunk id, 0..52223
  const float* W; int K, Nout, srow, base; bool lo = false;
  if (c < 8192)       { W = sh_W0; K = 256; Nout = 256; srow = 0;  base = 0; }
  else if (c < 12288) { W = sh_W1; K = 128; Nout = 256; srow = 1;  base = 8192; }
  else if (c < 45056) { int j = (c-12288) >> 12; W = dep_W + j*32768; K = 128; Nout = 256; srow = 2+j;  base = 12288 + j*4096; }
  else if (c < 51200) { int j = (c-45056) >> 11; W = at_W  + j*16384; K = 64;  Nout = 256; srow = 10+j; base = 45056 + j*2048; }
  else if (c < 51712) { W = Wout; K = 64; Nout = 64; srow = -1; base = 51200; }
  else                { W = Wout; K = 64; Nout = 64; srow = -1; base = 51712; lo = true; }
  int local = c - base;
  int lane  = local & 63;
  int t     = local >> 6;
  int KS    = K >> 5;
  int lsh   = (K == 256) ? 3 : (K == 128) ? 2 : 1;
  int ks    = t & (KS - 1);
  int mf    = t >> lsh;
  int feat  = mf*16 + (lane & 15);
  int k0    = ks*32 + ((lane >> 4) << 3);
  float scl = (srow < 0) ? 1.0f : scaleT[srow*256 + feat];
  u16 v[8];
  #pragma unroll
  for (int j = 0; j < 8; ++j) {
    float x = W[(size_t)(k0 + j)*Nout + feat] * scl;
    u16 h = f2bf(x);
    if (lo) h = f2bf(x - bf2f(h));
    v[j] = h;
  }
  ushort4* d4 = (ushort4*)(pk + (size_t)c*8);
  ushort4 p0; p0.x=v[0]; p0.y=v[1]; p0.z=v[2]; p0.w=v[3];
  ushort4 p1; p1.x=v[4]; p1.y=v[5]; p1.z=v[6]; p1.w=v[7];
  d4[0] = p0; d4[1] = p1;
}

// prefetch first A-tile of a gemm (4 x 16B global loads)
template<int KS>
__device__ __forceinline__ void prefA(const u16* __restrict__ pk, int w, int lane, short8 ae[4]){
  #pragma unroll
  for (int mi = 0; mi < 4; ++mi)
    ae[mi] = *(const short8*)(pk + (size_t)(((w + 4*mi)*KS)*64 + lane)*8);
}
// prefetch gemm bias (C-init) rows
__device__ __forceinline__ void prefB4(const float* __restrict__ shrow, int w, int lg, f32x4 bv[4]){
  #pragma unroll
  for (int mi = 0; mi < 4; ++mi)
    bv[mi] = *(const f32x4*)(shrow + (w + 4*mi)*16 + lg*4);
}
// init acc from prefetched bias
__device__ __forceinline__ void initP(f32x4 acc[4][2], const f32x4 bv[4]){
  #pragma unroll
  for (int mi = 0; mi < 4; ++mi) { acc[mi][0] = bv[mi]; acc[mi][1] = bv[mi]; }
}

// ---------------- gemm: 4 m-frags x 2 n-frags, even/odd double-buffer ----------------
// First A-tile comes prefetched (issued before the preceding barrier).
template<int KS, int LDB, int KOFF>
__device__ __forceinline__ void gemm4(const u16* __restrict__ pk, const u16* bufB,
                                      const short8 aePre[4],
                                      int w, int l15, int lg, int swzv, f32x4 acc[4][2])
{
  const int lane = lg*16 + l15;
  short8 ae[4], be[2], ao[4], bo[2];
  #pragma unroll
  for (int nf = 0; nf < 2; ++nf) {
    int idx = (nf*16 + l15)*LDB + KOFF + lg*8;
    be[nf] = *(const short8*)(bufB + (idx ^ swzv));
  }
  #pragma unroll
  for (int mi = 0; mi < 4; ++mi) ae[mi] = aePre[mi];

  #pragma unroll 1
  for (int ks = 0; ks < KS; ks += 2) {
    #pragma unroll
    for (int nf = 0; nf < 2; ++nf) {
      int idx = (nf*16 + l15)*LDB + KOFF + (ks+1)*32 + lg*8;
      bo[nf] = *(const short8*)(bufB + (idx ^ swzv));
    }
    #pragma unroll
    for (int mi = 0; mi < 4; ++mi)
      ao[mi] = *(const short8*)(pk + (size_t)(((w + 4*mi)*KS + ks + 1)*64 + lane)*8);
    #pragma unroll
    for (int mi = 0; mi < 4; ++mi) {
      acc[mi][0] = __builtin_amdgcn_mfma_f32_16x16x32_bf16(ae[mi], be[0], acc[mi][0], 0, 0, 0);
      acc[mi][1] = __builtin_amdgcn_mfma_f32_16x16x32_bf16(ae[mi], be[1], acc[mi][1], 0, 0, 0);
    }
    if (ks + 2 < KS) {
      #pragma unroll
      for (int nf = 0; nf < 2; ++nf) {
        int idx = (nf*16 + l15)*LDB + KOFF + (ks+2)*32 + lg*8;
        be[nf] = *(const short8*)(bufB + (idx ^ swzv));
      }
      #pragma unroll
      for (int mi = 0; mi < 4; ++mi)
        ae[mi] = *(const short8*)(pk + (size_t)(((w + 4*mi)*KS + ks + 2)*64 + lane)*8);
    }
    #pragma unroll
    for (int mi = 0; mi < 4; ++mi) {
      acc[mi][0] = __builtin_amdgcn_mfma_f32_16x16x32_bf16(ao[mi], bo[0], acc[mi][0], 0, 0, 0);
      acc[mi][1] = __builtin_amdgcn_mfma_f32_16x16x32_bf16(ao[mi], bo[1], acc[mi][1], 0, 0, 0);
    }
  }
}

// GLU epilogue (bias pre-folded into acc): h = v * sigmoid(g)
__device__ __forceinline__ void glu_epi4(const f32x4 acc[4][2], f32x4 h[2][2])
{
  #pragma unroll
  for (int mi = 0; mi < 2; ++mi)
    #pragma unroll
    for (int nf = 0; nf < 2; ++nf)
      #pragma unroll
      for (int c = 0; c < 4; ++c)
        h[mi][nf][c] = acc[mi][nf][c] * sigm(acc[mi+2][nf][c]);
}

// write this wave's 32 features of a 128-wide activation [32][128] bf16 (swizzled)
__device__ __forceinline__ void write_half(u16* dst, const f32x4 v[2][2], int w, int l15, int lg, int swzv)
{
  #pragma unroll
  for (int mi = 0; mi < 2; ++mi) {
    const int f0 = (w + 4*mi)*16 + lg*4;
    #pragma unroll
    for (int nf = 0; nf < 2; ++nf) {
      const int s = nf*16 + l15;
      uint2 p;
      p.x = pk2(v[mi][nf][0], v[mi][nf][1]);
      p.y = pk2(v[mi][nf][2], v[mi][nf][3]);
      *(uint2*)(dst + ((s*128 + f0) ^ swzv)) = p;
    }
  }
}

// shared_block + dep_block with (A-tile, bias) prefetch across every barrier.
// Also prefetches the NEXT phase's attn tiles (nextA/nextBias -> aeNext/bNext)
// during the dep1 epilogue so the attn gemm prologue is warm.
template<int DO_AGG>
__device__ __forceinline__ void shared_dep(const u16* __restrict__ pk, const float* __restrict__ shiftT,
                                           const u16* binput, u16* big, u16* hbuf, float* aggS,
                                           const short8 aeG0[4], const f32x4 bG0[4],
                                           const u16* __restrict__ nextA, const float* __restrict__ nextBias,
                                           short8 aeNext[4], f32x4 bNext[4], int inv,
                                           int tid, int w, int lane, int l15, int lg, int swzv)
{
  f32x4 acc[4][2];
  initP(acc, bG0);
  gemm4<8, 256, 0>(pk + PK_G0_US, binput, aeG0, w, l15, lg, swzv, acc);
  short8 aeN[4];
  f32x4  bN[4];
  prefA<4>(pk + PK_G1_US, w, lane, aeN);          // G1 A + bias before B1
  prefB4(shiftT + 256, w, lg, bN);
  {
    f32x4 h[2][2];
    glu_epi4(acc, h);
    write_half(hbuf, h, w, l15, lg, swzv);   // hbuf disjoint from binput
  }
  __syncthreads();                           // B1: h visible; all G0 reads done

  initP(acc, bN);
  gemm4<4, 128, 0>(pk + PK_G1_US, hbuf, aeN, w, l15, lg, swzv, acc);
  prefA<4>(pk + PK_DEP_US + (inv*2 + 0)*32768, w, lane, aeN);  // dep0 A + bias before B2
  prefB4(shiftT + (2 + inv*2 + 0)*256, w, lg, bN);
  {
    f32x4 h2[2][2];
    glu_epi4(acc, h2);
    f32x4 xv[2][2];
    #pragma unroll
    for (int mi = 0; mi < 2; ++mi) {
      const int f0 = (w + 4*mi)*16 + lg*4;
      #pragma unroll
      for (int nf = 0; nf < 2; ++nf) {
        const int s = nf*16 + l15;
        uint2 hp = *(const uint2*)(hbuf + ((s*128 + f0) ^ swzv));
        f32x4 hv = unpk4(hp);
        xv[mi][nf] = (hv + h2[mi][nf]) * SQRT_HALF;
      }
    }
    write_half(big, xv, w, l15, lg, swzv);   // x -> big[0:4096]
  }
  __syncthreads();                           // B2: x visible

  const u16* xin = big;
  u16* xout = big + 4096;
  #pragma unroll
  for (int i = 0; i < 2; ++i) {
    initP(acc, bN);
    gemm4<4, 128, 0>(pk + PK_DEP_US + (inv*2 + i)*32768, xin, aeN, w, l15, lg, swzv, acc);
    if (i == 0) {
      prefA<4>(pk + PK_DEP_US + (inv*2 + 1)*32768, w, lane, aeN);  // dep1 A + bias before B3
      prefB4(shiftT + (2 + inv*2 + 1)*256, w, lg, bN);
    } else {
      prefA<2>(nextA, w, lane, aeNext);       // next attn A + bias before B4
      prefB4(nextBias, w, lg, bNext);
    }
    f32x4 hd[2][2];
    glu_epi4(acc, hd);
    #pragma unroll
    for (int mi = 0; mi < 2; ++mi) {
      const int f0 = (w + 4*mi)*16 + lg*4;
      #pragma unroll
      for (int nf = 0; nf < 2; ++nf) {
        const int s = nf*16 + l15;
        uint2 xp = *(const uint2*)(xin + ((s*128 + f0) ^ swzv));
        f32x4 xo = unpk4(xp);
        hd[mi][nf] = (xo + hd[mi][nf]) * SQRT_HALF;
      }
    }
    if (DO_AGG && i == 1) {
      const f32x4 zf = splat4(0.0f);
      #pragma unroll
      for (int nf = 0; nf < 2; ++nf) {
        f32x4 r = __builtin_elementwise_max(hd[0][nf], zf);
        #pragma unroll
        for (int c = 0; c < 4; ++c)
          aggS[(nf*4 + c)*256 + tid] += r[c];
      }
    }
    write_half(xout, hd, w, l15, lg, swzv);  // xout disjoint from xin
    __syncthreads();                         // B3/B4: x' visible
    const u16* t = xin; xin = xout; xout = (u16*)t;
  }
  // x_final at big[0:4096]
}

// ---------------- main fused kernel ----------------
// 32 samples/block, 4 waves. LDS 76,288 B -> 2 blocks/CU (8 waves = hard cap at
// this register footprint). Full (A-tile + bias) prefetch across all barriers.
__global__ void __launch_bounds__(256, 2)
tabnet_main(const float* __restrict__ inp, const u16* __restrict__ pk,
            const float* __restrict__ shiftT, const float* __restrict__ inSc,
            const float* __restrict__ inSh, float* __restrict__ out)
{
  __shared__ __align__(16) u16 feat[32*256];     // 16 KB
  __shared__ __align__(16) u16 uni[17408];       // 34,816 B: zbuf f32[32][272] | big(16K)+hbuf(8K)
  __shared__ unsigned priorT[32*132];            // 16,896 B
  __shared__ float    aggS[8*256];               // 8 KB
  u16*   big  = uni;
  u16*   hbuf = uni + 8192;
  float* zbuf = (float*)uni;

  const int tid  = threadIdx.x;
  const int w    = tid >> 6;
  const int lane = tid & 63;
  const int l15  = lane & 15, lg = lane >> 4;
  const int swzv = (l15 & 7) << 3;
  const int a    = lane >> 3;
  const int b    = lane & 7;
  const int s_own = w*8 + a;
  const long long row0 = (long long)blockIdx.x * 32;

  // stage 0: features = BN(inputs) -> feat (bf16, swizzled [sample][256])
  {
    const int f = lane*4;
    const f32x4 sc = *(const f32x4*)(inSc + f);
    const f32x4 sh = *(const f32x4*)(inSh + f);
    #pragma unroll
    for (int j = 0; j < 8; ++j) {
      const int s = j*4 + w;
      f32x4 v = *(const f32x4*)(inp + (row0 + s)*256 + f);
      uint2 p;
      p.x = pk2(v[0]*sc[0] + sh[0], v[1]*sc[1] + sh[1]);
      p.y = pk2(v[2]*sc[2] + sh[2], v[3]*sc[3] + sh[3]);
      *(uint2*)(feat + ((s*256 + f) ^ ((s & 7) << 3))) = p;
    }
  }
  // init prior=1 (own transposed slots), agg=0 (own columns)
  {
    #pragma unroll
    for (int j = 0; j < 8; ++j) {
      const int c = (b ^ a) + 8*j;
      uint2 one; one.x = 0x3c003c00u; one.y = 0x3c003c00u;
      *(uint2*)(priorT + s_own*132 + 2*c) = one;
    }
    #pragma unroll
    for (int j = 0; j < 8; ++j) aggS[j*256 + tid] = 0.0f;
  }
  short8 aeG0[4], aeAT[4];
  f32x4  bG0[4], bAT[4];
  prefA<8>(pk + PK_G0_US, w, lane, aeG0);   // G0 A + bias before the staging barrier
  prefB4(shiftT + 0, w, lg, bG0);
  __syncthreads();

  shared_dep<0>(pk, shiftT, feat, big, hbuf, aggS, aeG0, bG0,
                pk + PK_AT_US, shiftT + 10*256, aeAT, bAT,
                0, tid, w, lane, l15, lg, swzv);

  #pragma unroll 1
  for (int st = 0; st < 3; ++st) {
    // attention: z = a @ at_W[st] + bias (A + bias prefetched), a = x[:,64:128]
    f32x4 z[4][2];
    initP(z, bAT);
    gemm4<2, 128, 64>(pk + PK_AT_US + st*16384, big, aeAT, w, l15, lg, swzv, z);
    __syncthreads();   // B_a: all waves done reading big (x) before z-spill clobbers

    // spill z to zbuf f32[32][ZSTRIDE]
    #pragma unroll
    for (int mi = 0; mi < 4; ++mi) {
      const int F0 = (w + 4*mi)*16 + lg*4;
      #pragma unroll
      for (int nf = 0; nf < 2; ++nf) {
        const int s = nf*16 + l15;
        *(f32x4*)(zbuf + s*ZSTRIDE + F0) = z[mi][nf];
      }
    }
    __syncthreads();   // B_t: z visible

    // transposed assemble: zT = z * prior; rowmax via 3 shuffles
    f32x4 zT[8];
    float tau;
    {
      float mx = -1e30f;
      #pragma unroll
      for (int j = 0; j < 8; ++j) {
        const int c = (b ^ a) + 8*j;
        f32x4 zv = *(const f32x4*)(zbuf + s_own*ZSTRIDE + 4*c);
        uint2 pr = *(const uint2*)(priorT + s_own*132 + 2*c);
        float2 p0 = h2f2(pr.x), p1 = h2f2(pr.y);
        f32x4 pv; pv[0] = p0.x; pv[1] = p0.y; pv[2] = p1.x; pv[3] = p1.y;
        zv *= pv;
        zT[j] = zv;
        mx = fmaxf(mx, fmaxf(fmaxf(zv[0], zv[1]), fmaxf(zv[2], zv[3])));
      }
      mx = fmaxf(mx, __shfl_xor(mx, 1, 64));
      mx = fmaxf(mx, __shfl_xor(mx, 2, 64));
      mx = fmaxf(mx, __shfl_xor(mx, 4, 64));
      tau = mx - 1.0f;
    }

    // Newton: wave-local, vectorized scan, per-wave early exit (tol 1e-4)
    const f32x4 zf = splat4(0.0f);
    #pragma unroll 1
    for (int it = 0; it < 10; ++it) {
      f32x4 S4 = zf, C4 = zf;
      const f32x4 tau4 = splat4(tau);
      #pragma unroll
      for (int j = 0; j < 8; ++j) {
        f32x4 d = zT[j] - tau4;
        S4 += __builtin_elementwise_max(d, zf);
        i32x4 cm = d > zf;
        C4 -= __builtin_convertvector(cm, f32x4);
      }
      float S = (S4[0] + S4[1]) + (S4[2] + S4[3]);
      float C = (C4[0] + C4[1]) + (C4[2] + C4[3]);
      S += __shfl_xor(S, 1, 64); C += __shfl_xor(C, 1, 64);
      S += __shfl_xor(S, 2, 64); C += __shfl_xor(C, 2, 64);
      S += __shfl_xor(S, 4, 64); C += __shfl_xor(C, 4, 64);
      if (__all(fabsf(S - 1.0f) < 1e-4f)) break;
      tau += (S - 1.0f) * __builtin_amdgcn_rcpf(C);
    }

    __syncthreads();   // B_m: all waves done reading zbuf before mask overwrites big

    // mask + prior update + masked = mask * features -> big (vectorized)
    {
      const f32x4 tau4 = splat4(tau);
      const f32x4 rel4 = splat4(RELAX);
      #pragma unroll
      for (int j = 0; j < 8; ++j) {
        const int c = (b ^ a) + 8*j;
        f32x4 m4 = __builtin_elementwise_max(zT[j] - tau4, zf);
        uint2 pr = *(const uint2*)(priorT + s_own*132 + 2*c);
        float2 p0 = h2f2(pr.x), p1 = h2f2(pr.y);
        f32x4 pv; pv[0] = p0.x; pv[1] = p0.y; pv[2] = p1.x; pv[3] = p1.y;
        pv *= (rel4 - m4);
        pr.x = f22h2(pv[0], pv[1]);
        pr.y = f22h2(pv[2], pv[3]);
        *(uint2*)(priorT + s_own*132 + 2*c) = pr;
        const int idx = (s_own*256 + 4*c) ^ (a << 3);
        f32x4 fv = unpkb4(*(const ushort4*)(feat + idx));
        fv *= m4;
        uint2 o;
        o.x = pk2(fv[0], fv[1]);
        o.y = pk2(fv[2], fv[3]);
        *(uint2*)(big + idx) = o;
      }
    }
    prefA<8>(pk + PK_G0_US, w, lane, aeG0);  // next G0 A + bias before B_g0
    prefB4(shiftT + 0, w, lg, bG0);
    __syncthreads();   // B_g0: masked visible before G0 reads

    const int stn = (st + 1 < 3) ? st + 1 : 0;   // dummy prefetch on last stage
    shared_dep<1>(pk, shiftT, big, big, hbuf, aggS, aeG0, bG0,
                  pk + PK_AT_US + stn*16384, shiftT + (10 + stn)*256, aeAT, bAT,
                  st + 1, tid, w, lane, l15, lg, swzv);
  }

  // final: out = out_agg @ Wout, split-bf16 (hi/lo) for precision.
  {
    #pragma unroll
    for (int nf = 0; nf < 2; ++nf) {
      const int si = nf*16 + l15;
      const int f0 = w*16 + lg*4;
      float a0 = aggS[(nf*4+0)*256 + tid];
      float a1 = aggS[(nf*4+1)*256 + tid];
      float a2 = aggS[(nf*4+2)*256 + tid];
      float a3 = aggS[(nf*4+3)*256 + tid];
      ushort4 hi, lo;
      u16 h0 = f2bf(a0); hi.x = h0; lo.x = f2bf(a0 - bf2f(h0));
      u16 h1 = f2bf(a1); hi.y = h1; lo.y = f2bf(a1 - bf2f(h1));
      u16 h2v = f2bf(a2); hi.z = h2v; lo.z = f2bf(a2 - bf2f(h2v));
      u16 h3 = f2bf(a3); hi.w = h3; lo.w = f2bf(a3 - bf2f(h3));
      *(ushort4*)(big + ((si*64 + f0) ^ swzv)) = hi;
      *(ushort4*)(big + 2048 + ((si*64 + f0) ^ swzv)) = lo;
    }
  }
  __syncthreads();

  // 64x64x(32 samples) GEMM: wave w -> out m-frag w, both sample n-frags
  {
    const int lane64 = lg*16 + l15;
    f32x4 facc[2];
    facc[0] = splat4(0.0f); facc[1] = splat4(0.0f);
    #pragma unroll
    for (int ks = 0; ks < 2; ++ks) {
      short8 aHi = *(const short8*)(pk + PK_WOUT_US   + (size_t)((w*2 + ks)*64 + lane64)*8);
      short8 aLo = *(const short8*)(pk + PK_WOUTLO_US + (size_t)((w*2 + ks)*64 + lane64)*8);
      #pragma unroll
      for (int j = 0; j < 2; ++j) {
        const int si = j*16 + l15;
        short8 bHi = *(const short8*)(big + ((si*64 + ks*32 + lg*8) ^ swzv));
        short8 bLo = *(const short8*)(big + 2048 + ((si*64 + ks*32 + lg*8) ^ swzv));
        facc[j] = __builtin_amdgcn_mfma_f32_16x16x32_bf16(aHi, bHi, facc[j], 0, 0, 0);
        facc[j] = __builtin_amdgcn_mfma_f32_16x16x32_bf16(aHi, bLo, facc[j], 0, 0, 0);
        facc[j] = __builtin_amdgcn_mfma_f32_16x16x32_bf16(aLo, bHi, facc[j], 0, 0, 0);
      }
    }
    #pragma unroll
    for (int j = 0; j < 2; ++j) {
      const int si = j*16 + l15;
      *(f32x4*)(out + (row0 + si)*64 + w*16 + lg*4) = facc[j];
    }
  }
}

// ---------------- launch ----------------
extern "C" void kernel_launch(void* const* d_in, const int* in_sizes, int n_in,
                              void* d_out, int out_size, void* d_ws, size_t ws_size,
                              hipStream_t stream)
{
  const float* inp   = (const float*)d_in[0];
  const float* in_g  = (const float*)d_in[1];
  const float* in_b  = (const float*)d_in[2];
  const float* in_m  = (const float*)d_in[3];
  const float* in_v  = (const float*)d_in[4];
  const float* sh_W0 = (const float*)d_in[5];
  const float* sh_W1 = (const float*)d_in[6];
  const float* sh_g  = (const float*)d_in[7];
  const float* sh_b  = (const float*)d_in[8];
  const float* sh_m  = (const float*)d_in[9];
  const float* sh_v  = (const float*)d_in[10];
  const float* dep_W = (const float*)d_in[11];
  const float* dep_g = (const float*)d_in[12];
  const float* dep_b = (const float*)d_in[13];
  const float* dep_m = (const float*)d_in[14];
  const float* dep_v = (const float*)d_in[15];
  const float* at_W  = (const float*)d_in[16];
  const float* at_g  = (const float*)d_in[17];
  const float* at_b  = (const float*)d_in[18];
  const float* at_m  = (const float*)d_in[19];
  const float* at_v  = (const float*)d_in[20];
  const float* Wout  = (const float*)d_in[21];

  unsigned char* ws = (unsigned char*)d_ws;
  u16*   pk     = (u16*)ws;
  float* shiftT = (float*)(ws + OFF_SHIFT);
  float* scaleT = (float*)(ws + OFF_SCALE);
  float* inSc   = (float*)(ws + OFF_INSC);
  float* inSh   = (float*)(ws + OFF_INSH);

  hipLaunchKernelGGL(prep_bn, dim3(14), dim3(256), 0, stream,
                     in_g, in_b, in_m, in_v, sh_g, sh_b, sh_m, sh_v,
                     dep_g, dep_b, dep_m, dep_v, at_g, at_b, at_m, at_v,
                     shiftT, scaleT, inSc, inSh);
  hipLaunchKernelGGL(prep_pack, dim3(204), dim3(256), 0, stream,
                     sh_W0, sh_W1, dep_W, at_W, Wout, scaleT, pk);
  hipLaunchKernelGGL(tabnet_main, dim3(4096), dim3(256), 0, stream,
                     inp, pk, shiftT, inSc, inSh, (float*)d_out);
}